// Round 1
// baseline (1591.846 us; speedup 1.0000x reference)
//
#include <hip/hip_runtime.h>
#include <hip/hip_bf16.h>

#define S_LEN 4096
#define DMODEL 512
#define NHEADS 8
#define DK 64
#define BATCH 2
#define MROWS (BATCH * S_LEN)  // 8192

// ---------------------------------------------------------------------------
// Fused GEMM + bias: out = A[M,512] @ W[512,512] + b
// BM=BN=64, BK=16, 256 threads, 4x4 micro-tile per thread.
// SPLIT=true writes head-split layout [B, H, S, DK] for Q/K/V.
// ---------------------------------------------------------------------------
template <bool SPLIT>
__global__ __launch_bounds__(256) void gemm_bias_k(
    const float* __restrict__ A, const float* __restrict__ W,
    const float* __restrict__ bias, float* __restrict__ out) {
  __shared__ __align__(16) float As[16][64];  // As[k][m]  (k-major)
  __shared__ __align__(16) float Bs[16][64];  // Bs[k][n]
  const int tid = threadIdx.x;
  const int tx = tid & 15;   // n dim
  const int ty = tid >> 4;   // m dim
  const int m0 = blockIdx.x * 64;
  const int n0 = blockIdx.y * 64;

  float4 acc[4];
#pragma unroll
  for (int i = 0; i < 4; ++i) acc[i] = make_float4(0.f, 0.f, 0.f, 0.f);

  const int ar = tid >> 2;         // 0..63 : A tile row
  const int ak = (tid & 3) * 4;    // k chunk
  const int bk = tid >> 4;         // 0..15 : B tile row (k)
  const int bn = (tid & 15) * 4;   // n chunk

  for (int k0 = 0; k0 < 512; k0 += 16) {
    __syncthreads();
    float4 av = *reinterpret_cast<const float4*>(A + (size_t)(m0 + ar) * 512 + k0 + ak);
    As[ak + 0][ar] = av.x;
    As[ak + 1][ar] = av.y;
    As[ak + 2][ar] = av.z;
    As[ak + 3][ar] = av.w;
    *reinterpret_cast<float4*>(&Bs[bk][bn]) =
        *reinterpret_cast<const float4*>(W + (size_t)(k0 + bk) * 512 + n0 + bn);
    __syncthreads();
#pragma unroll
    for (int kk = 0; kk < 16; ++kk) {
      float4 a = *reinterpret_cast<const float4*>(&As[kk][ty * 4]);
      float4 b = *reinterpret_cast<const float4*>(&Bs[kk][tx * 4]);
      float am[4] = {a.x, a.y, a.z, a.w};
#pragma unroll
      for (int mi = 0; mi < 4; ++mi) {
        acc[mi].x = fmaf(am[mi], b.x, acc[mi].x);
        acc[mi].y = fmaf(am[mi], b.y, acc[mi].y);
        acc[mi].z = fmaf(am[mi], b.z, acc[mi].z);
        acc[mi].w = fmaf(am[mi], b.w, acc[mi].w);
      }
    }
  }

  float4 bv = *reinterpret_cast<const float4*>(bias + n0 + tx * 4);
#pragma unroll
  for (int mi = 0; mi < 4; ++mi) {
    int row = m0 + ty * 4 + mi;
    float4 o;
    o.x = acc[mi].x + bv.x;
    o.y = acc[mi].y + bv.y;
    o.z = acc[mi].z + bv.z;
    o.w = acc[mi].w + bv.w;
    if (SPLIT) {
      int b = row >> 12;           // row / 4096
      int srow = row & 4095;
      int col = n0 + tx * 4;
      int h = col >> 6;
      int d = col & 63;
      *reinterpret_cast<float4*>(out + (((size_t)b * NHEADS + h) * S_LEN + srow) * DK + d) = o;
    } else {
      *reinterpret_cast<float4*>(out + (size_t)row * 512 + n0 + tx * 4) = o;
    }
  }
}

// ---------------------------------------------------------------------------
// Flash-style attention, fp32. Grid (S/64, B*H), 256 threads.
// 64 queries / block; 4 threads per query (g = tid&3 owns dims g*16..g*16+15
// and keys g*16..g*16+15 of each 64-key tile). Q row lives in registers.
// K staged transposed (Kt[d][j]); V staged row-major with per-row chunk
// swizzle so reads resolve to compile-time acc indices.
// ---------------------------------------------------------------------------
__global__ __launch_bounds__(256) void attn_fp32(
    const float* __restrict__ Q, const float* __restrict__ K,
    const float* __restrict__ V, float* __restrict__ AO) {
  __shared__ __align__(16) float Kt[64][64];  // Kt[d][j]
  __shared__ __align__(16) float Vs[64][64];  // Vs[j][d], chunk-swizzled
  const int tid = threadIdx.x;
  const int g = tid & 3;
  const int ql = tid >> 2;  // 0..63
  const int qt = blockIdx.x;
  const int bh = blockIdx.y;
  const int sq = qt * 64 + ql;

  const float* Qb = Q + (size_t)bh * S_LEN * DK;
  const float* Kb = K + (size_t)bh * S_LEN * DK;
  const float* Vb = V + (size_t)bh * S_LEN * DK;

  // Q row -> 16 float4 registers (all indexing compile-time)
  float4 qv[16];
#pragma unroll
  for (int c = 0; c < 16; ++c)
    qv[c] = *reinterpret_cast<const float4*>(Qb + (size_t)sq * DK + c * 4);

  float m = -INFINITY, l = 0.f;
  float4 acc[4];
#pragma unroll
  for (int c = 0; c < 4; ++c) acc[c] = make_float4(0.f, 0.f, 0.f, 0.f);

  for (int kt = 0; kt < S_LEN / 64; ++kt) {
    __syncthreads();  // previous tile fully consumed before overwrite
    {
      const int r = ql;
      const float* krow = Kb + ((size_t)kt * 64 + r) * DK + g * 16;
#pragma unroll
      for (int c = 0; c < 4; ++c) {
        float4 kv = *reinterpret_cast<const float4*>(krow + c * 4);
        int d0 = g * 16 + c * 4;
        Kt[d0 + 0][r] = kv.x;
        Kt[d0 + 1][r] = kv.y;
        Kt[d0 + 2][r] = kv.z;
        Kt[d0 + 3][r] = kv.w;
      }
      const float* vrow = Vb + ((size_t)kt * 64 + r) * DK + g * 16;
#pragma unroll
      for (int c = 0; c < 4; ++c) {
        float4 vv = *reinterpret_cast<const float4*>(vrow + c * 4);
        int cc = (c + r) & 3;  // swizzle chunk within the 16-float block
        *reinterpret_cast<float4*>(&Vs[r][g * 16 + cc * 4]) = vv;
      }
    }
    __syncthreads();

    // ---- scores: s[jj] = q . K[j],  j = g*16 + jj ----
    float s[16];
#pragma unroll
    for (int jj = 0; jj < 16; ++jj) s[jj] = 0.f;
#pragma unroll
    for (int dc = 0; dc < 16; ++dc) {
      float4 q4 = qv[dc];
      float qs_[4] = {q4.x, q4.y, q4.z, q4.w};
#pragma unroll
      for (int i = 0; i < 4; ++i) {
        int d = dc * 4 + i;
        const float4* krow4 = reinterpret_cast<const float4*>(&Kt[d][g * 16]);
#pragma unroll
        for (int c = 0; c < 4; ++c) {
          float4 kv = krow4[c];
          s[c * 4 + 0] = fmaf(qs_[i], kv.x, s[c * 4 + 0]);
          s[c * 4 + 1] = fmaf(qs_[i], kv.y, s[c * 4 + 1]);
          s[c * 4 + 2] = fmaf(qs_[i], kv.z, s[c * 4 + 2]);
          s[c * 4 + 3] = fmaf(qs_[i], kv.w, s[c * 4 + 3]);
        }
      }
    }

    // ---- online softmax over the 4-lane group (one query row) ----
    float tmax = -INFINITY;
#pragma unroll
    for (int jj = 0; jj < 16; ++jj) {
      s[jj] *= 0.125f;  // 1/sqrt(64)
      tmax = fmaxf(tmax, s[jj]);
    }
    tmax = fmaxf(tmax, __shfl_xor(tmax, 1));
    tmax = fmaxf(tmax, __shfl_xor(tmax, 2));
    float mnew = fmaxf(m, tmax);
    float alpha = __expf(m - mnew);  // exp(-inf)=0 on first tile
    float p[16];
    float tsum = 0.f;
#pragma unroll
    for (int jj = 0; jj < 16; ++jj) {
      p[jj] = __expf(s[jj] - mnew);
      tsum += p[jj];
    }
    tsum += __shfl_xor(tsum, 1);
    tsum += __shfl_xor(tsum, 2);
    l = l * alpha + tsum;
    m = mnew;
#pragma unroll
    for (int c = 0; c < 4; ++c) {
      acc[c].x *= alpha; acc[c].y *= alpha;
      acc[c].z *= alpha; acc[c].w *= alpha;
    }

    // ---- PV: acc[d] += sum_j p_j * V[j][d], d in [g*16, g*16+16) ----
    for (int jg = 0; jg < 4; ++jg) {
#pragma unroll
      for (int jj = 0; jj < 16; ++jj) {
        float pj = __shfl(p[jj], jg, 4);  // p for key j = jg*16+jj of this query
        const float4* vrow4 = reinterpret_cast<const float4*>(&Vs[jg * 16 + jj][g * 16]);
#pragma unroll
        for (int cp = 0; cp < 4; ++cp) {
          float4 vv = vrow4[cp];
          int c = (cp - jj) & 3;  // undo swizzle; compile-time
          acc[c].x = fmaf(pj, vv.x, acc[c].x);
          acc[c].y = fmaf(pj, vv.y, acc[c].y);
          acc[c].z = fmaf(pj, vv.z, acc[c].z);
          acc[c].w = fmaf(pj, vv.w, acc[c].w);
        }
      }
    }
  }

  const int b = bh >> 3;
  const int h = bh & 7;
  float inv = 1.f / l;
  float* obase = AO + ((size_t)b * S_LEN + sq) * DMODEL + h * DK + g * 16;
#pragma unroll
  for (int c = 0; c < 4; ++c) {
    float4 o;
    o.x = acc[c].x * inv;
    o.y = acc[c].y * inv;
    o.z = acc[c].z * inv;
    o.w = acc[c].w * inv;
    *reinterpret_cast<float4*>(obase + c * 4) = o;
  }
}

extern "C" void kernel_launch(void* const* d_in, const int* in_sizes, int n_in,
                              void* d_out, int out_size, void* d_ws, size_t ws_size,
                              hipStream_t stream) {
  const float* x  = (const float*)d_in[0];
  const float* Wq = (const float*)d_in[1];
  const float* bq = (const float*)d_in[2];
  const float* Wk = (const float*)d_in[3];
  const float* bk = (const float*)d_in[4];
  const float* Wv = (const float*)d_in[5];
  const float* bv = (const float*)d_in[6];
  const float* Wo = (const float*)d_in[7];
  const float* bo = (const float*)d_in[8];
  float* out = (float*)d_out;

  float* ws = (float*)d_ws;
  const size_t SZ = (size_t)MROWS * DMODEL;  // 4 Mi floats = 16 MB
  float* Qw  = ws;            // [B,H,S,DK]
  float* Kw  = ws + SZ;       // [B,H,S,DK]
  float* Vw  = ws + 2 * SZ;   // [B,H,S,DK]
  float* AOw = ws + 3 * SZ;   // [B,S,DMODEL]

  dim3 gg(MROWS / 64, DMODEL / 64);  // (128, 8)
  gemm_bias_k<true><<<gg, 256, 0, stream>>>(x, Wq, bq, Qw);
  gemm_bias_k<true><<<gg, 256, 0, stream>>>(x, Wk, bk, Kw);
  gemm_bias_k<true><<<gg, 256, 0, stream>>>(x, Wv, bv, Vw);

  dim3 ga(S_LEN / 64, BATCH * NHEADS);  // (64, 16)
  attn_fp32<<<ga, 256, 0, stream>>>(Qw, Kw, Vw, AOw);

  gemm_bias_k<false><<<gg, 256, 0, stream>>>(AOw, Wo, bo, out);
}

// Round 2
// 404.704 us; speedup vs baseline: 3.9334x; 3.9334x over previous
//
#include <hip/hip_runtime.h>
#include <hip/hip_bf16.h>

#define S_LEN 4096
#define DMODEL 512
#define NHEADS 8
#define DK 64
#define BATCH 2
#define MROWS (BATCH * S_LEN)  // 8192

typedef __attribute__((ext_vector_type(8))) short bf16x8;
typedef __attribute__((ext_vector_type(4))) float f32x4;

__device__ __forceinline__ unsigned packbf(float a, float b) {
  union { __hip_bfloat16 h; unsigned short s; } ua, ub;
  ua.h = __float2bfloat16(a);
  ub.h = __float2bfloat16(b);
  return (unsigned)ua.s | ((unsigned)ub.s << 16);
}

__device__ __forceinline__ uint2 pack4bf(float a, float b, float c, float d) {
  uint2 r;
  r.x = packbf(a, b);
  r.y = packbf(c, d);
  return r;
}

__device__ __forceinline__ void gll16(const void* g, void* l) {
  __builtin_amdgcn_global_load_lds(
      (const __attribute__((address_space(1))) unsigned*)g,
      (__attribute__((address_space(3))) unsigned*)l, 16, 0, 0);
}

// ---------------------------------------------------------------------------
// GEMM + bias: out = A[M,512] @ W[512,512] + b      (fp32 compute)
// MODE 0: fp32 out [M,512]
// MODE 1: bf16 out head-split [B,H,S,DK]
// MODE 2: bf16 out transposed  [B,H,DK,S]   (for V^T)
// ---------------------------------------------------------------------------
template <int MODE>
__global__ __launch_bounds__(256) void gemm_bias_k(
    const float* __restrict__ A, const float* __restrict__ W,
    const float* __restrict__ bias, void* __restrict__ outp) {
  __shared__ __align__(16) float As[16][64];  // As[k][m]
  __shared__ __align__(16) float Bs[16][64];  // Bs[k][n]
  const int tid = threadIdx.x;
  const int tx = tid & 15;   // n dim
  const int ty = tid >> 4;   // m dim
  const int m0 = blockIdx.x * 64;
  const int n0 = blockIdx.y * 64;

  float4 acc[4];
#pragma unroll
  for (int i = 0; i < 4; ++i) acc[i] = make_float4(0.f, 0.f, 0.f, 0.f);

  const int ar = tid >> 2;
  const int ak = (tid & 3) * 4;
  const int bk = tid >> 4;
  const int bn = (tid & 15) * 4;

  for (int k0 = 0; k0 < 512; k0 += 16) {
    __syncthreads();
    float4 av = *reinterpret_cast<const float4*>(A + (size_t)(m0 + ar) * 512 + k0 + ak);
    As[ak + 0][ar] = av.x;
    As[ak + 1][ar] = av.y;
    As[ak + 2][ar] = av.z;
    As[ak + 3][ar] = av.w;
    *reinterpret_cast<float4*>(&Bs[bk][bn]) =
        *reinterpret_cast<const float4*>(W + (size_t)(k0 + bk) * 512 + n0 + bn);
    __syncthreads();
#pragma unroll
    for (int kk = 0; kk < 16; ++kk) {
      float4 a = *reinterpret_cast<const float4*>(&As[kk][ty * 4]);
      float4 b = *reinterpret_cast<const float4*>(&Bs[kk][tx * 4]);
      float am[4] = {a.x, a.y, a.z, a.w};
#pragma unroll
      for (int mi = 0; mi < 4; ++mi) {
        acc[mi].x = fmaf(am[mi], b.x, acc[mi].x);
        acc[mi].y = fmaf(am[mi], b.y, acc[mi].y);
        acc[mi].z = fmaf(am[mi], b.z, acc[mi].z);
        acc[mi].w = fmaf(am[mi], b.w, acc[mi].w);
      }
    }
  }

  float4 bv = *reinterpret_cast<const float4*>(bias + n0 + tx * 4);
  float av2[4][4];
#pragma unroll
  for (int mi = 0; mi < 4; ++mi) {
    av2[mi][0] = acc[mi].x + bv.x;
    av2[mi][1] = acc[mi].y + bv.y;
    av2[mi][2] = acc[mi].z + bv.z;
    av2[mi][3] = acc[mi].w + bv.w;
  }

  if (MODE == 0) {
    float* out = (float*)outp;
#pragma unroll
    for (int mi = 0; mi < 4; ++mi) {
      int row = m0 + ty * 4 + mi;
      float4 o = make_float4(av2[mi][0], av2[mi][1], av2[mi][2], av2[mi][3]);
      *reinterpret_cast<float4*>(out + (size_t)row * 512 + n0 + tx * 4) = o;
    }
  } else if (MODE == 1) {
    unsigned short* out = (unsigned short*)outp;
    int col = n0 + tx * 4;
    int h = col >> 6, d = col & 63;
#pragma unroll
    for (int mi = 0; mi < 4; ++mi) {
      int row = m0 + ty * 4 + mi;
      int b = row >> 12, s = row & 4095;
      uint2 pv = pack4bf(av2[mi][0], av2[mi][1], av2[mi][2], av2[mi][3]);
      *reinterpret_cast<uint2*>(out + (((size_t)(b * NHEADS + h) * S_LEN + s) * DK + d)) = pv;
    }
  } else {
    // MODE 2: Vt[b,h,d,s]
    unsigned short* out = (unsigned short*)outp;
    int b = m0 >> 12;
    int s = (m0 & 4095) + ty * 4;
#pragma unroll
    for (int c = 0; c < 4; ++c) {
      int col = n0 + tx * 4 + c;
      int h = col >> 6, d = col & 63;
      uint2 pv = pack4bf(av2[0][c], av2[1][c], av2[2][c], av2[3][c]);
      *reinterpret_cast<uint2*>(out + (((size_t)(b * NHEADS + h) * DK + d) * S_LEN + s)) = pv;
    }
  }
}

// ---------------------------------------------------------------------------
// MFMA flash attention. Grid (S/128, B*H), 256 threads = 4 waves.
// Wave owns 32 query rows. KVBLK=64. S^T = mfma(K, Q); PV via free
// k-permutation (B operand = own packed P values, zero shuffles).
// K_lds row-major [key][64], Vt_lds [d][64keys]; both XOR-swizzled
// (16B chunk ^ (row&7)) with linear-dest global_load_lds staging.
// ---------------------------------------------------------------------------
__global__ __launch_bounds__(256, 2) void attn_mfma(
    const unsigned short* __restrict__ Q, const unsigned short* __restrict__ K,
    const unsigned short* __restrict__ Vt, float* __restrict__ AO) {
  __shared__ unsigned short KL[2][64 * 64];
  __shared__ unsigned short VL[2][64 * 64];

  const int tid = threadIdx.x;
  const int wid = tid >> 6;
  const int lane = tid & 63;
  const int g = lane >> 4;     // 16-lane group
  const int ql = lane & 15;
  const int bh = blockIdx.y;

  const unsigned short* Qb = Q + (size_t)bh * S_LEN * DK;
  const unsigned short* Kb = K + (size_t)bh * S_LEN * DK;
  const unsigned short* Vb = Vt + (size_t)bh * DK * S_LEN;

  const int qbase = blockIdx.x * 128 + wid * 32;

  // Q B-fragments: qf[c][t] : col q = qbase+16c+ql, k = 32t + 8g + j
  bf16x8 qf[2][2];
#pragma unroll
  for (int c = 0; c < 2; ++c) {
    int q = qbase + c * 16 + ql;
#pragma unroll
    for (int t = 0; t < 2; ++t)
      qf[c][t] = *reinterpret_cast<const bf16x8*>(Qb + (size_t)q * DK + t * 32 + g * 8);
  }

  f32x4 ot[4][2];
#pragma unroll
  for (int db = 0; db < 4; ++db)
#pragma unroll
    for (int c = 0; c < 2; ++c) ot[db][c] = (f32x4){0.f, 0.f, 0.f, 0.f};
  float m_[2] = {-INFINITY, -INFINITY};
  float l_[2] = {0.f, 0.f};

  // --- staging: wave w stages K rows [16w,16w+16) and Vt rows [16w,16w+16)
  const int srow = lane >> 3;  // 0..7
  const int schk = lane & 7;   // 16B chunk

  auto stage = [&](int kt, int buf) {
#pragma unroll
    for (int i = 0; i < 2; ++i) {
      int r = wid * 16 + i * 8 + srow;
      int sc = (schk ^ (r & 7)) << 4;
      const char* gk = (const char*)Kb + ((size_t)(kt * 64 + r)) * 128 + sc;
      char* lk = (char*)&KL[buf][0] + (wid * 16 + i * 8) * 128 + lane * 16;
      gll16(gk, lk);
      const char* gv = (const char*)Vb + (size_t)r * (S_LEN * 2) + (size_t)kt * 128 + sc;
      char* lv = (char*)&VL[buf][0] + (wid * 16 + i * 8) * 128 + lane * 16;
      gll16(gv, lv);
    }
  };

  stage(0, 0);
  __syncthreads();
  int buf = 0;

  for (int kt = 0; kt < S_LEN / 64; ++kt) {
    if (kt < S_LEN / 64 - 1) stage(kt + 1, buf ^ 1);

    const char* KB = (const char*)&KL[buf][0];
    const char* VB = (const char*)&VL[buf][0];

    // ---- S^T = K . Q^T : st[kb][c], rows=keys 16kb+4g+r, cols q=16c+ql ----
    f32x4 st[4][2];
#pragma unroll
    for (int kb = 0; kb < 4; ++kb) {
      int r = kb * 16 + ql;
      bf16x8 k0 = *reinterpret_cast<const bf16x8*>(KB + r * 128 + (((g) ^ (r & 7)) << 4));
      bf16x8 k1 = *reinterpret_cast<const bf16x8*>(KB + r * 128 + (((g + 4) ^ (r & 7)) << 4));
#pragma unroll
      for (int c = 0; c < 2; ++c) {
        f32x4 z = (f32x4){0.f, 0.f, 0.f, 0.f};
        z = __builtin_amdgcn_mfma_f32_16x16x32_bf16(k0, qf[c][0], z, 0, 0, 0);
        z = __builtin_amdgcn_mfma_f32_16x16x32_bf16(k1, qf[c][1], z, 0, 0, 0);
        st[kb][c] = z;
      }
    }

    // ---- online softmax (keys per lane: 16kb + 4g + r) ----
    unsigned pk[2][4][2];
#pragma unroll
    for (int c = 0; c < 2; ++c) {
      float sv[4][4];
      float tmax = -INFINITY;
#pragma unroll
      for (int kb = 0; kb < 4; ++kb)
#pragma unroll
        for (int rr = 0; rr < 4; ++rr) {
          sv[kb][rr] = st[kb][c][rr] * 0.125f;
          tmax = fmaxf(tmax, sv[kb][rr]);
        }
      tmax = fmaxf(tmax, __shfl_xor(tmax, 16));
      tmax = fmaxf(tmax, __shfl_xor(tmax, 32));
      float mnew = fmaxf(m_[c], tmax);
      float alpha = __expf(m_[c] - mnew);
      m_[c] = mnew;
      float ts = 0.f;
#pragma unroll
      for (int kb = 0; kb < 4; ++kb)
#pragma unroll
        for (int r2 = 0; r2 < 2; ++r2) {
          float pa = __expf(sv[kb][2 * r2] - mnew);
          float pb = __expf(sv[kb][2 * r2 + 1] - mnew);
          ts += pa + pb;
          pk[c][kb][r2] = packbf(pa, pb);
        }
      ts += __shfl_xor(ts, 16);
      ts += __shfl_xor(ts, 32);
      l_[c] = l_[c] * alpha + ts;
#pragma unroll
      for (int db = 0; db < 4; ++db) ot[db][c] *= alpha;
    }

    // ---- PV: O^T[d][q] += V^T . P^T  (k-permutation kappa(g,j)) ----
#pragma unroll
    for (int t = 0; t < 2; ++t) {
      union { unsigned u[4]; bf16x8 v; } pb0, pb1;
      pb0.u[0] = pk[0][2 * t][0];     pb0.u[1] = pk[0][2 * t][1];
      pb0.u[2] = pk[0][2 * t + 1][0]; pb0.u[3] = pk[0][2 * t + 1][1];
      pb1.u[0] = pk[1][2 * t][0];     pb1.u[1] = pk[1][2 * t][1];
      pb1.u[2] = pk[1][2 * t + 1][0]; pb1.u[3] = pk[1][2 * t + 1][1];
#pragma unroll
      for (int db = 0; db < 4; ++db) {
        int rd = db * 16 + ql;
        int c1 = t * 4 + (g >> 1);
        int intra = (g & 1) << 3;
        uint2 lo = *reinterpret_cast<const uint2*>(VB + rd * 128 + ((c1 ^ (rd & 7)) << 4) + intra);
        uint2 hi = *reinterpret_cast<const uint2*>(VB + rd * 128 + (((c1 + 2) ^ (rd & 7)) << 4) + intra);
        union { unsigned u[4]; bf16x8 v; } af;
        af.u[0] = lo.x; af.u[1] = lo.y; af.u[2] = hi.x; af.u[3] = hi.y;
        ot[db][0] = __builtin_amdgcn_mfma_f32_16x16x32_bf16(af.v, pb0.v, ot[db][0], 0, 0, 0);
        ot[db][1] = __builtin_amdgcn_mfma_f32_16x16x32_bf16(af.v, pb1.v, ot[db][1], 0, 0, 0);
      }
    }

    __syncthreads();
    buf ^= 1;
  }

  // ---- epilogue: O = (O^T)^T / l, write fp32 AO[b,s,h*64+d] ----
  const int b = bh >> 3, h = bh & 7;
#pragma unroll
  for (int c = 0; c < 2; ++c) {
    float inv = 1.f / l_[c];
    int q = qbase + c * 16 + ql;
#pragma unroll
    for (int db = 0; db < 4; ++db) {
      float4 o = make_float4(ot[db][c][0] * inv, ot[db][c][1] * inv,
                             ot[db][c][2] * inv, ot[db][c][3] * inv);
      *reinterpret_cast<float4*>(AO + ((size_t)b * S_LEN + q) * DMODEL + h * DK + db * 16 + g * 4) = o;
    }
  }
}

extern "C" void kernel_launch(void* const* d_in, const int* in_sizes, int n_in,
                              void* d_out, int out_size, void* d_ws, size_t ws_size,
                              hipStream_t stream) {
  const float* x  = (const float*)d_in[0];
  const float* Wq = (const float*)d_in[1];
  const float* bq = (const float*)d_in[2];
  const float* Wk = (const float*)d_in[3];
  const float* bk = (const float*)d_in[4];
  const float* Wv = (const float*)d_in[5];
  const float* bv = (const float*)d_in[6];
  const float* Wo = (const float*)d_in[7];
  const float* bo = (const float*)d_in[8];
  float* out = (float*)d_out;

  char* ws = (char*)d_ws;
  const size_t NBF = (size_t)MROWS * DMODEL;  // 4 Mi elements
  unsigned short* Qbf = (unsigned short*)ws;                  // 8 MB [B,H,S,DK]
  unsigned short* Kbf = (unsigned short*)(ws + NBF * 2);      // 8 MB [B,H,S,DK]
  unsigned short* Vtb = (unsigned short*)(ws + NBF * 4);      // 8 MB [B,H,DK,S]
  float* AOw = (float*)(ws + NBF * 6);                        // 16 MB [B,S,DMODEL]

  dim3 gg(MROWS / 64, DMODEL / 64);  // (128, 8)
  gemm_bias_k<1><<<gg, 256, 0, stream>>>(x, Wq, bq, Qbf);
  gemm_bias_k<1><<<gg, 256, 0, stream>>>(x, Wk, bk, Kbf);
  gemm_bias_k<2><<<gg, 256, 0, stream>>>(x, Wv, bv, Vtb);

  dim3 ga(S_LEN / 128, BATCH * NHEADS);  // (32, 16)
  attn_mfma<<<ga, 256, 0, stream>>>(Qbf, Kbf, Vtb, AOw);

  gemm_bias_k<0><<<gg, 256, 0, stream>>>(AOw, Wo, bo, out);
}

// Round 3
// 209.777 us; speedup vs baseline: 7.5883x; 1.9292x over previous
//
#include <hip/hip_runtime.h>
#include <hip/hip_bf16.h>

#define S_LEN 4096
#define DMODEL 512
#define NHEADS 8
#define DK 64
#define BATCH 2
#define MROWS (BATCH * S_LEN)  // 8192

typedef __attribute__((ext_vector_type(8))) short bf16x8;
typedef __attribute__((ext_vector_type(4))) float f32x4;
typedef unsigned short ushort_t;

__device__ __forceinline__ unsigned packbf(float a, float b) {
  union { __hip_bfloat16 h; unsigned short s; } ua, ub;
  ua.h = __float2bfloat16(a);
  ub.h = __float2bfloat16(b);
  return (unsigned)ua.s | ((unsigned)ub.s << 16);
}

__device__ __forceinline__ unsigned short bf1(float a) {
  union { __hip_bfloat16 h; unsigned short s; } u;
  u.h = __float2bfloat16(a);
  return u.s;
}

__device__ __forceinline__ void gll16(const void* g, void* l) {
  __builtin_amdgcn_global_load_lds(
      (const __attribute__((address_space(1))) unsigned*)g,
      (__attribute__((address_space(3))) unsigned*)l, 16, 0, 0);
}

// ---------------------------------------------------------------------------
// x fp32 -> bf16, 8 elems/thread, exact grid (n divisible by 2048)
// ---------------------------------------------------------------------------
__global__ __launch_bounds__(256) void cvt_bf16(const float* __restrict__ in,
                                                ushort_t* __restrict__ out) {
  size_t i = ((size_t)blockIdx.x * 256 + threadIdx.x) * 8;
  float4 a = *reinterpret_cast<const float4*>(in + i);
  float4 b = *reinterpret_cast<const float4*>(in + i + 4);
  uint4 o;
  o.x = packbf(a.x, a.y);
  o.y = packbf(a.z, a.w);
  o.z = packbf(b.x, b.y);
  o.w = packbf(b.z, b.w);
  *reinterpret_cast<uint4*>(out + i) = o;
}

// ---------------------------------------------------------------------------
// W[512,512] fp32 (k,n) -> Wt[512,512] bf16 (n,k). 32x32 tiles, 256 thr.
// ---------------------------------------------------------------------------
__global__ __launch_bounds__(256) void transp_w(const float* __restrict__ W,
                                                ushort_t* __restrict__ Wt) {
  __shared__ float T[32][33];
  const int tid = threadIdx.x;
  const int k0 = blockIdx.x * 32, n0 = blockIdx.y * 32;
  const int r = tid >> 3, c4 = (tid & 7) * 4;
  float4 v = *reinterpret_cast<const float4*>(W + (size_t)(k0 + r) * 512 + n0 + c4);
  T[r][c4 + 0] = v.x; T[r][c4 + 1] = v.y; T[r][c4 + 2] = v.z; T[r][c4 + 3] = v.w;
  __syncthreads();
  uint2 o;
  o.x = packbf(T[c4 + 0][r], T[c4 + 1][r]);
  o.y = packbf(T[c4 + 2][r], T[c4 + 3][r]);
  *reinterpret_cast<uint2*>(Wt + (size_t)(n0 + r) * 512 + k0 + c4) = o;
}

// ---------------------------------------------------------------------------
// MFMA GEMM: C = A[M,512](bf16) @ Wt[N=512,K=512]^T(bf16) + bias
// 128x128 tile, BK=32, 256 threads = 4 waves (2x2 of 64x64).
// MODE 0: fp32 out [M,512]; MODE 1: bf16 head-split [B,H,S,DK];
// MODE 2: bf16 transposed [B,H,DK,S] (V^T).
// ---------------------------------------------------------------------------
template <int MODE>
__global__ __launch_bounds__(256) void gemm_mfma(
    const ushort_t* __restrict__ A, const ushort_t* __restrict__ Wt,
    const float* __restrict__ bias, void* __restrict__ outp) {
  __shared__ ushort_t AL[2][128 * 32];
  __shared__ ushort_t BL[2][128 * 32];
  const int tid = threadIdx.x;
  const int wid = tid >> 6;
  const int lane = tid & 63;
  const int ql = lane & 15;
  const int g = lane >> 4;
  const int wr = wid >> 1, wc = wid & 1;
  const int m0 = blockIdx.x * 128, n0 = blockIdx.y * 128;

  f32x4 acc[4][4];
#pragma unroll
  for (int i = 0; i < 4; ++i)
#pragma unroll
    for (int j = 0; j < 4; ++j) acc[i][j] = (f32x4){0.f, 0.f, 0.f, 0.f};

  const int sr = tid >> 2;       // 0..63 within 2-iter staging (row/2)
  const int sc = (tid & 3) * 8;  // k-element chunk (8 bf16 = 16B)

  auto stage = [&](int k0, int buf) {
#pragma unroll
    for (int i = 0; i < 2; ++i) {
      int idx = i * 256 + tid;
      int r = idx >> 2;
      int c = (idx & 3) * 8;
      gll16(A + (size_t)(m0 + r) * 512 + k0 + c, &AL[buf][idx * 8]);
      gll16(Wt + (size_t)(n0 + r) * 512 + k0 + c, &BL[buf][idx * 8]);
    }
  };

  stage(0, 0);
  __syncthreads();
  int buf = 0;

  for (int t = 0; t < 16; ++t) {
    if (t < 15) stage((t + 1) * 32, buf ^ 1);
    const ushort_t* ALb = &AL[buf][0];
    const ushort_t* BLb = &BL[buf][0];
    bf16x8 af[4], bfr[4];
#pragma unroll
    for (int mi = 0; mi < 4; ++mi)
      af[mi] = *reinterpret_cast<const bf16x8*>(ALb + (wr * 64 + mi * 16 + ql) * 32 + g * 8);
#pragma unroll
    for (int ni = 0; ni < 4; ++ni)
      bfr[ni] = *reinterpret_cast<const bf16x8*>(BLb + (wc * 64 + ni * 16 + ql) * 32 + g * 8);
#pragma unroll
    for (int mi = 0; mi < 4; ++mi)
#pragma unroll
      for (int ni = 0; ni < 4; ++ni)
        acc[mi][ni] = __builtin_amdgcn_mfma_f32_16x16x32_bf16(af[mi], bfr[ni], acc[mi][ni], 0, 0, 0);
    __syncthreads();
    buf ^= 1;
  }

  float bv[4];
#pragma unroll
  for (int ni = 0; ni < 4; ++ni) bv[ni] = bias[n0 + wc * 64 + ni * 16 + ql];

#pragma unroll
  for (int mi = 0; mi < 4; ++mi) {
#pragma unroll
    for (int ni = 0; ni < 4; ++ni) {
      int n = n0 + wc * 64 + ni * 16 + ql;
#pragma unroll
      for (int reg = 0; reg < 4; ++reg) {
        float val = acc[mi][ni][reg] + bv[ni];
        int m = m0 + wr * 64 + mi * 16 + 4 * g + reg;
        if (MODE == 0) {
          ((float*)outp)[(size_t)m * 512 + n] = val;
        } else if (MODE == 1) {
          int b = m >> 12, s = m & 4095;
          int h = n >> 6, d = n & 63;
          ((ushort_t*)outp)[(((size_t)(b * NHEADS + h) * S_LEN + s) * DK) + d] = bf1(val);
        } else {
          int b = m >> 12, s = m & 4095;
          int h = n >> 6, d = n & 63;
          ((ushort_t*)outp)[(((size_t)(b * NHEADS + h) * DK + d) * S_LEN) + s] = bf1(val);
        }
      }
    }
  }
}

// ---------------------------------------------------------------------------
// MFMA flash attention (unchanged from round 2 except bf16 AO epilogue).
// Grid (S/128, B*H), 256 threads = 4 waves; wave owns 32 query rows.
// ---------------------------------------------------------------------------
__global__ __launch_bounds__(256, 2) void attn_mfma(
    const ushort_t* __restrict__ Q, const ushort_t* __restrict__ K,
    const ushort_t* __restrict__ Vt, ushort_t* __restrict__ AO) {
  __shared__ ushort_t KL[2][64 * 64];
  __shared__ ushort_t VL[2][64 * 64];

  const int tid = threadIdx.x;
  const int wid = tid >> 6;
  const int lane = tid & 63;
  const int g = lane >> 4;
  const int ql = lane & 15;
  const int bh = blockIdx.y;

  const ushort_t* Qb = Q + (size_t)bh * S_LEN * DK;
  const ushort_t* Kb = K + (size_t)bh * S_LEN * DK;
  const ushort_t* Vb = Vt + (size_t)bh * DK * S_LEN;

  const int qbase = blockIdx.x * 128 + wid * 32;

  bf16x8 qf[2][2];
#pragma unroll
  for (int c = 0; c < 2; ++c) {
    int q = qbase + c * 16 + ql;
#pragma unroll
    for (int t = 0; t < 2; ++t)
      qf[c][t] = *reinterpret_cast<const bf16x8*>(Qb + (size_t)q * DK + t * 32 + g * 8);
  }

  f32x4 ot[4][2];
#pragma unroll
  for (int db = 0; db < 4; ++db)
#pragma unroll
    for (int c = 0; c < 2; ++c) ot[db][c] = (f32x4){0.f, 0.f, 0.f, 0.f};
  float m_[2] = {-INFINITY, -INFINITY};
  float l_[2] = {0.f, 0.f};

  const int srow = lane >> 3;
  const int schk = lane & 7;

  auto stage = [&](int kt, int buf) {
#pragma unroll
    for (int i = 0; i < 2; ++i) {
      int r = wid * 16 + i * 8 + srow;
      int sc = (schk ^ (r & 7)) << 4;
      const char* gk = (const char*)Kb + ((size_t)(kt * 64 + r)) * 128 + sc;
      char* lk = (char*)&KL[buf][0] + (wid * 16 + i * 8) * 128 + lane * 16;
      gll16(gk, lk);
      const char* gv = (const char*)Vb + (size_t)r * (S_LEN * 2) + (size_t)kt * 128 + sc;
      char* lv = (char*)&VL[buf][0] + (wid * 16 + i * 8) * 128 + lane * 16;
      gll16(gv, lv);
    }
  };

  stage(0, 0);
  __syncthreads();
  int buf = 0;

  for (int kt = 0; kt < S_LEN / 64; ++kt) {
    if (kt < S_LEN / 64 - 1) stage(kt + 1, buf ^ 1);

    const char* KB = (const char*)&KL[buf][0];
    const char* VB = (const char*)&VL[buf][0];

    f32x4 st[4][2];
#pragma unroll
    for (int kb = 0; kb < 4; ++kb) {
      int r = kb * 16 + ql;
      bf16x8 k0 = *reinterpret_cast<const bf16x8*>(KB + r * 128 + (((g) ^ (r & 7)) << 4));
      bf16x8 k1 = *reinterpret_cast<const bf16x8*>(KB + r * 128 + (((g + 4) ^ (r & 7)) << 4));
#pragma unroll
      for (int c = 0; c < 2; ++c) {
        f32x4 z = (f32x4){0.f, 0.f, 0.f, 0.f};
        z = __builtin_amdgcn_mfma_f32_16x16x32_bf16(k0, qf[c][0], z, 0, 0, 0);
        z = __builtin_amdgcn_mfma_f32_16x16x32_bf16(k1, qf[c][1], z, 0, 0, 0);
        st[kb][c] = z;
      }
    }

    unsigned pk[2][4][2];
#pragma unroll
    for (int c = 0; c < 2; ++c) {
      float sv[4][4];
      float tmax = -INFINITY;
#pragma unroll
      for (int kb = 0; kb < 4; ++kb)
#pragma unroll
        for (int rr = 0; rr < 4; ++rr) {
          sv[kb][rr] = st[kb][c][rr] * 0.125f;
          tmax = fmaxf(tmax, sv[kb][rr]);
        }
      tmax = fmaxf(tmax, __shfl_xor(tmax, 16));
      tmax = fmaxf(tmax, __shfl_xor(tmax, 32));
      float mnew = fmaxf(m_[c], tmax);
      float alpha = __expf(m_[c] - mnew);
      m_[c] = mnew;
      float ts = 0.f;
#pragma unroll
      for (int kb = 0; kb < 4; ++kb)
#pragma unroll
        for (int r2 = 0; r2 < 2; ++r2) {
          float pa = __expf(sv[kb][2 * r2] - mnew);
          float pb = __expf(sv[kb][2 * r2 + 1] - mnew);
          ts += pa + pb;
          pk[c][kb][r2] = packbf(pa, pb);
        }
      ts += __shfl_xor(ts, 16);
      ts += __shfl_xor(ts, 32);
      l_[c] = l_[c] * alpha + ts;
#pragma unroll
      for (int db = 0; db < 4; ++db) ot[db][c] *= alpha;
    }

#pragma unroll
    for (int t = 0; t < 2; ++t) {
      union { unsigned u[4]; bf16x8 v; } pb0, pb1;
      pb0.u[0] = pk[0][2 * t][0];     pb0.u[1] = pk[0][2 * t][1];
      pb0.u[2] = pk[0][2 * t + 1][0]; pb0.u[3] = pk[0][2 * t + 1][1];
      pb1.u[0] = pk[1][2 * t][0];     pb1.u[1] = pk[1][2 * t][1];
      pb1.u[2] = pk[1][2 * t + 1][0]; pb1.u[3] = pk[1][2 * t + 1][1];
#pragma unroll
      for (int db = 0; db < 4; ++db) {
        int rd = db * 16 + ql;
        int c1 = t * 4 + (g >> 1);
        int intra = (g & 1) << 3;
        uint2 lo = *reinterpret_cast<const uint2*>(VB + rd * 128 + ((c1 ^ (rd & 7)) << 4) + intra);
        uint2 hi = *reinterpret_cast<const uint2*>(VB + rd * 128 + (((c1 + 2) ^ (rd & 7)) << 4) + intra);
        union { unsigned u[4]; bf16x8 v; } af;
        af.u[0] = lo.x; af.u[1] = lo.y; af.u[2] = hi.x; af.u[3] = hi.y;
        ot[db][0] = __builtin_amdgcn_mfma_f32_16x16x32_bf16(af.v, pb0.v, ot[db][0], 0, 0, 0);
        ot[db][1] = __builtin_amdgcn_mfma_f32_16x16x32_bf16(af.v, pb1.v, ot[db][1], 0, 0, 0);
      }
    }

    __syncthreads();
    buf ^= 1;
  }

  const int b = bh >> 3, h = bh & 7;
#pragma unroll
  for (int c = 0; c < 2; ++c) {
    float inv = 1.f / l_[c];
    int q = qbase + c * 16 + ql;
#pragma unroll
    for (int db = 0; db < 4; ++db) {
      uint2 o;
      o.x = packbf(ot[db][c][0] * inv, ot[db][c][1] * inv);
      o.y = packbf(ot[db][c][2] * inv, ot[db][c][3] * inv);
      *reinterpret_cast<uint2*>(AO + ((size_t)b * S_LEN + q) * DMODEL + h * DK + db * 16 + g * 4) = o;
    }
  }
}

extern "C" void kernel_launch(void* const* d_in, const int* in_sizes, int n_in,
                              void* d_out, int out_size, void* d_ws, size_t ws_size,
                              hipStream_t stream) {
  const float* x  = (const float*)d_in[0];
  const float* Wq = (const float*)d_in[1];
  const float* bq = (const float*)d_in[2];
  const float* Wk = (const float*)d_in[3];
  const float* bk = (const float*)d_in[4];
  const float* Wv = (const float*)d_in[5];
  const float* bv = (const float*)d_in[6];
  const float* Wo = (const float*)d_in[7];
  const float* bo = (const float*)d_in[8];
  float* out = (float*)d_out;

  char* ws = (char*)d_ws;
  const size_t NBF = (size_t)MROWS * DMODEL;  // 4 Mi elements
  ushort_t* xbf = (ushort_t*)ws;                   // 8 MB
  ushort_t* Qbf = (ushort_t*)(ws + NBF * 2);       // 8 MB [B,H,S,DK]
  ushort_t* Kbf = (ushort_t*)(ws + NBF * 4);       // 8 MB [B,H,S,DK]
  ushort_t* Vtb = (ushort_t*)(ws + NBF * 6);       // 8 MB [B,H,DK,S]
  ushort_t* AOb = (ushort_t*)(ws + NBF * 8);       // 8 MB [B,S,DMODEL]
  ushort_t* Wqt = (ushort_t*)(ws + NBF * 10);                 // 512 KB each
  ushort_t* Wkt = Wqt + 512 * 512;
  ushort_t* Wvt = Wkt + 512 * 512;
  ushort_t* Wot = Wvt + 512 * 512;

  cvt_bf16<<<MROWS * DMODEL / 2048, 256, 0, stream>>>(x, xbf);
  dim3 gt(16, 16);
  transp_w<<<gt, 256, 0, stream>>>(Wq, Wqt);
  transp_w<<<gt, 256, 0, stream>>>(Wk, Wkt);
  transp_w<<<gt, 256, 0, stream>>>(Wv, Wvt);
  transp_w<<<gt, 256, 0, stream>>>(Wo, Wot);

  dim3 gg(MROWS / 128, DMODEL / 128);  // (64, 4)
  gemm_mfma<1><<<gg, 256, 0, stream>>>(xbf, Wqt, bq, Qbf);
  gemm_mfma<1><<<gg, 256, 0, stream>>>(xbf, Wkt, bk, Kbf);
  gemm_mfma<2><<<gg, 256, 0, stream>>>(xbf, Wvt, bv, Vtb);

  dim3 ga(S_LEN / 128, BATCH * NHEADS);  // (32, 16)
  attn_mfma<<<ga, 256, 0, stream>>>(Qbf, Kbf, Vtb, AOb);

  gemm_mfma<0><<<gg, 256, 0, stream>>>(AOb, Wot, bo, out);
}

// Round 4
// 176.703 us; speedup vs baseline: 9.0086x; 1.1872x over previous
//
#include <hip/hip_runtime.h>
#include <hip/hip_bf16.h>

#define S_LEN 4096
#define DMODEL 512
#define NHEADS 8
#define DK 64
#define BATCH 2
#define MROWS (BATCH * S_LEN)  // 8192

typedef __attribute__((ext_vector_type(8))) short bf16x8;
typedef __attribute__((ext_vector_type(4))) float f32x4;
typedef unsigned short ushort_t;

__device__ __forceinline__ unsigned packbf(float a, float b) {
  union { __hip_bfloat16 h; unsigned short s; } ua, ub;
  ua.h = __float2bfloat16(a);
  ub.h = __float2bfloat16(b);
  return (unsigned)ua.s | ((unsigned)ub.s << 16);
}

__device__ __forceinline__ unsigned short bf1(float a) {
  union { __hip_bfloat16 h; unsigned short s; } u;
  u.h = __float2bfloat16(a);
  return u.s;
}

__device__ __forceinline__ void gll16(const void* g, void* l) {
  __builtin_amdgcn_global_load_lds(
      (const __attribute__((address_space(1))) unsigned*)g,
      (__attribute__((address_space(3))) unsigned*)l, 16, 0, 0);
}

// ---------------------------------------------------------------------------
// x fp32 -> bf16, 8 elems/thread
// ---------------------------------------------------------------------------
__global__ __launch_bounds__(256) void cvt_bf16(const float* __restrict__ in,
                                                ushort_t* __restrict__ out) {
  size_t i = ((size_t)blockIdx.x * 256 + threadIdx.x) * 8;
  float4 a = *reinterpret_cast<const float4*>(in + i);
  float4 b = *reinterpret_cast<const float4*>(in + i + 4);
  uint4 o;
  o.x = packbf(a.x, a.y);
  o.y = packbf(a.z, a.w);
  o.z = packbf(b.x, b.y);
  o.w = packbf(b.z, b.w);
  *reinterpret_cast<uint4*>(out + i) = o;
}

// ---------------------------------------------------------------------------
// W[512,512] fp32 (k,n) -> Wt[512,512] bf16 (n,k). 32x32 tiles, 256 thr.
// ---------------------------------------------------------------------------
__global__ __launch_bounds__(256) void transp_w(const float* __restrict__ W,
                                                ushort_t* __restrict__ Wt) {
  __shared__ float T[32][33];
  const int tid = threadIdx.x;
  const int k0 = blockIdx.x * 32, n0 = blockIdx.y * 32;
  const int r = tid >> 3, c4 = (tid & 7) * 4;
  float4 v = *reinterpret_cast<const float4*>(W + (size_t)(k0 + r) * 512 + n0 + c4);
  T[r][c4 + 0] = v.x; T[r][c4 + 1] = v.y; T[r][c4 + 2] = v.z; T[r][c4 + 3] = v.w;
  __syncthreads();
  uint2 o;
  o.x = packbf(T[c4 + 0][r], T[c4 + 1][r]);
  o.y = packbf(T[c4 + 2][r], T[c4 + 3][r]);
  *reinterpret_cast<uint2*>(Wt + (size_t)(n0 + r) * 512 + k0 + c4) = o;
}

// ---------------------------------------------------------------------------
// MFMA GEMM: C = A[M,512](bf16) @ Wt[N=512,K=512]^T(bf16) + bias
// 128x128 tile, BK=32, 256 threads = 4 waves (2x2 of 64x64).
// ---------------------------------------------------------------------------
template <int MODE>
__global__ __launch_bounds__(256) void gemm_mfma(
    const ushort_t* __restrict__ A, const ushort_t* __restrict__ Wt,
    const float* __restrict__ bias, void* __restrict__ outp) {
  __shared__ ushort_t AL[2][128 * 32];
  __shared__ ushort_t BL[2][128 * 32];
  const int tid = threadIdx.x;
  const int wid = tid >> 6;
  const int lane = tid & 63;
  const int ql = lane & 15;
  const int g = lane >> 4;
  const int wr = wid >> 1, wc = wid & 1;
  const int m0 = blockIdx.x * 128, n0 = blockIdx.y * 128;

  f32x4 acc[4][4];
#pragma unroll
  for (int i = 0; i < 4; ++i)
#pragma unroll
    for (int j = 0; j < 4; ++j) acc[i][j] = (f32x4){0.f, 0.f, 0.f, 0.f};

  auto stage = [&](int k0, int buf) {
#pragma unroll
    for (int i = 0; i < 2; ++i) {
      int idx = i * 256 + tid;
      int r = idx >> 2;
      int c = (idx & 3) * 8;
      gll16(A + (size_t)(m0 + r) * 512 + k0 + c, &AL[buf][idx * 8]);
      gll16(Wt + (size_t)(n0 + r) * 512 + k0 + c, &BL[buf][idx * 8]);
    }
  };

  stage(0, 0);
  __syncthreads();
  int buf = 0;

  for (int t = 0; t < 16; ++t) {
    if (t < 15) stage((t + 1) * 32, buf ^ 1);
    const ushort_t* ALb = &AL[buf][0];
    const ushort_t* BLb = &BL[buf][0];
    bf16x8 af[4], bfr[4];
#pragma unroll
    for (int mi = 0; mi < 4; ++mi)
      af[mi] = *reinterpret_cast<const bf16x8*>(ALb + (wr * 64 + mi * 16 + ql) * 32 + g * 8);
#pragma unroll
    for (int ni = 0; ni < 4; ++ni)
      bfr[ni] = *reinterpret_cast<const bf16x8*>(BLb + (wc * 64 + ni * 16 + ql) * 32 + g * 8);
#pragma unroll
    for (int mi = 0; mi < 4; ++mi)
#pragma unroll
      for (int ni = 0; ni < 4; ++ni)
        acc[mi][ni] = __builtin_amdgcn_mfma_f32_16x16x32_bf16(af[mi], bfr[ni], acc[mi][ni], 0, 0, 0);
    __syncthreads();
    buf ^= 1;
  }

  float bv[4];
#pragma unroll
  for (int ni = 0; ni < 4; ++ni) bv[ni] = bias[n0 + wc * 64 + ni * 16 + ql];

#pragma unroll
  for (int mi = 0; mi < 4; ++mi) {
#pragma unroll
    for (int ni = 0; ni < 4; ++ni) {
      int n = n0 + wc * 64 + ni * 16 + ql;
#pragma unroll
      for (int reg = 0; reg < 4; ++reg) {
        float val = acc[mi][ni][reg] + bv[ni];
        int m = m0 + wr * 64 + mi * 16 + 4 * g + reg;
        if (MODE == 0) {
          ((float*)outp)[(size_t)m * 512 + n] = val;
        } else if (MODE == 1) {
          int b = m >> 12, s = m & 4095;
          int h = n >> 6, d = n & 63;
          ((ushort_t*)outp)[(((size_t)(b * NHEADS + h) * S_LEN + s) * DK) + d] = bf1(val);
        } else {
          int b = m >> 12, s = m & 4095;
          int h = n >> 6, d = n & 63;
          ((ushort_t*)outp)[(((size_t)(b * NHEADS + h) * DK + d) * S_LEN) + s] = bf1(val);
        }
      }
    }
  }
}

// ---------------------------------------------------------------------------
// MFMA flash attention, no-max softmax (scores bounded ~|2|: exp never
// overflows; softmax identical after final 1/l). Grid (S/64, B*H), 4 waves,
// wave owns 16 q rows. Zero in-loop shuffles; l reduced in epilogue.
// ---------------------------------------------------------------------------
__global__ __launch_bounds__(256, 4) void attn_mfma(
    const ushort_t* __restrict__ Q, const ushort_t* __restrict__ K,
    const ushort_t* __restrict__ Vt, ushort_t* __restrict__ AO) {
  __shared__ ushort_t KL[2][64 * 64];
  __shared__ ushort_t VL[2][64 * 64];

  const int tid = threadIdx.x;
  const int wid = tid >> 6;
  const int lane = tid & 63;
  const int g = lane >> 4;
  const int ql = lane & 15;
  const int bh = blockIdx.y;

  const ushort_t* Qb = Q + (size_t)bh * S_LEN * DK;
  const ushort_t* Kb = K + (size_t)bh * S_LEN * DK;
  const ushort_t* Vb = Vt + (size_t)bh * DK * S_LEN;

  const int qbase = blockIdx.x * 64 + wid * 16;

  // Q B-fragment: col q = qbase+ql, k = 32t + 8g + j
  bf16x8 qf[2];
#pragma unroll
  for (int t = 0; t < 2; ++t)
    qf[t] = *reinterpret_cast<const bf16x8*>(Qb + (size_t)(qbase + ql) * DK + t * 32 + g * 8);

  f32x4 ot[4];
#pragma unroll
  for (int db = 0; db < 4; ++db) ot[db] = (f32x4){0.f, 0.f, 0.f, 0.f};
  float l_loc = 0.f;

  const int srow = lane >> 3;
  const int schk = lane & 7;

  auto stage = [&](int kt, int buf) {
#pragma unroll
    for (int i = 0; i < 2; ++i) {
      int r = wid * 16 + i * 8 + srow;
      int sc = (schk ^ (r & 7)) << 4;
      const char* gk = (const char*)Kb + ((size_t)(kt * 64 + r)) * 128 + sc;
      char* lk = (char*)&KL[buf][0] + (wid * 16 + i * 8) * 128 + lane * 16;
      gll16(gk, lk);
      const char* gv = (const char*)Vb + (size_t)r * (S_LEN * 2) + (size_t)kt * 128 + sc;
      char* lv = (char*)&VL[buf][0] + (wid * 16 + i * 8) * 128 + lane * 16;
      gll16(gv, lv);
    }
  };

  stage(0, 0);
  __syncthreads();
  int buf = 0;

  const float C = 0.18033688f;  // 0.125 * log2(e)

  for (int kt = 0; kt < S_LEN / 64; ++kt) {
    if (kt < S_LEN / 64 - 1) stage(kt + 1, buf ^ 1);

    const char* KB = (const char*)&KL[buf][0];
    const char* VB = (const char*)&VL[buf][0];

    // ---- S^T = K . Q^T : keys 16kb+4g+reg, col q = qbase+ql ----
    f32x4 st[4];
#pragma unroll
    for (int kb = 0; kb < 4; ++kb) {
      int r = kb * 16 + ql;
      bf16x8 k0 = *reinterpret_cast<const bf16x8*>(KB + r * 128 + (((g) ^ (r & 7)) << 4));
      bf16x8 k1 = *reinterpret_cast<const bf16x8*>(KB + r * 128 + (((g + 4) ^ (r & 7)) << 4));
      f32x4 z = (f32x4){0.f, 0.f, 0.f, 0.f};
      z = __builtin_amdgcn_mfma_f32_16x16x32_bf16(k0, qf[0], z, 0, 0, 0);
      z = __builtin_amdgcn_mfma_f32_16x16x32_bf16(k1, qf[1], z, 0, 0, 0);
      st[kb] = z;
    }

    // ---- no-max softmax numerator: p = exp2(s * 0.125*log2e) ----
    unsigned pk[4][2];
#pragma unroll
    for (int kb = 0; kb < 4; ++kb) {
#pragma unroll
      for (int r2 = 0; r2 < 2; ++r2) {
        float pa = __builtin_amdgcn_exp2f(st[kb][2 * r2] * C);
        float pb_ = __builtin_amdgcn_exp2f(st[kb][2 * r2 + 1] * C);
        l_loc += pa + pb_;
        pk[kb][r2] = packbf(pa, pb_);
      }
    }

    // ---- PV: O^T[d][q] += V^T . P^T  (k-permutation kappa(g,j)) ----
#pragma unroll
    for (int t = 0; t < 2; ++t) {
      union { unsigned u[4]; bf16x8 v; } pb;
      pb.u[0] = pk[2 * t][0];     pb.u[1] = pk[2 * t][1];
      pb.u[2] = pk[2 * t + 1][0]; pb.u[3] = pk[2 * t + 1][1];
#pragma unroll
      for (int db = 0; db < 4; ++db) {
        int rd = db * 16 + ql;
        int c1 = t * 4 + (g >> 1);
        int intra = (g & 1) << 3;
        uint2 lo = *reinterpret_cast<const uint2*>(VB + rd * 128 + ((c1 ^ (rd & 7)) << 4) + intra);
        uint2 hi = *reinterpret_cast<const uint2*>(VB + rd * 128 + (((c1 + 2) ^ (rd & 7)) << 4) + intra);
        union { unsigned u[4]; bf16x8 v; } af;
        af.u[0] = lo.x; af.u[1] = lo.y; af.u[2] = hi.x; af.u[3] = hi.y;
        ot[db] = __builtin_amdgcn_mfma_f32_16x16x32_bf16(af.v, pb.v, ot[db], 0, 0, 0);
      }
    }

    __syncthreads();
    buf ^= 1;
  }

  // ---- epilogue: reduce l across g-groups, write bf16 AO ----
  float l = l_loc;
  l += __shfl_xor(l, 16);
  l += __shfl_xor(l, 32);
  float inv = 1.f / l;
  const int b = bh >> 3, h = bh & 7;
  const int q = qbase + ql;
#pragma unroll
  for (int db = 0; db < 4; ++db) {
    uint2 o;
    o.x = packbf(ot[db][0] * inv, ot[db][1] * inv);
    o.y = packbf(ot[db][2] * inv, ot[db][3] * inv);
    *reinterpret_cast<uint2*>(AO + ((size_t)b * S_LEN + q) * DMODEL + h * DK + db * 16 + g * 4) = o;
  }
}

extern "C" void kernel_launch(void* const* d_in, const int* in_sizes, int n_in,
                              void* d_out, int out_size, void* d_ws, size_t ws_size,
                              hipStream_t stream) {
  const float* x  = (const float*)d_in[0];
  const float* Wq = (const float*)d_in[1];
  const float* bq = (const float*)d_in[2];
  const float* Wk = (const float*)d_in[3];
  const float* bk = (const float*)d_in[4];
  const float* Wv = (const float*)d_in[5];
  const float* bv = (const float*)d_in[6];
  const float* Wo = (const float*)d_in[7];
  const float* bo = (const float*)d_in[8];
  float* out = (float*)d_out;

  char* ws = (char*)d_ws;
  const size_t NBF = (size_t)MROWS * DMODEL;  // 4 Mi elements
  ushort_t* xbf = (ushort_t*)ws;
  ushort_t* Qbf = (ushort_t*)(ws + NBF * 2);
  ushort_t* Kbf = (ushort_t*)(ws + NBF * 4);
  ushort_t* Vtb = (ushort_t*)(ws + NBF * 6);
  ushort_t* AOb = (ushort_t*)(ws + NBF * 8);
  ushort_t* Wqt = (ushort_t*)(ws + NBF * 10);
  ushort_t* Wkt = Wqt + 512 * 512;
  ushort_t* Wvt = Wkt + 512 * 512;
  ushort_t* Wot = Wvt + 512 * 512;

  cvt_bf16<<<MROWS * DMODEL / 2048, 256, 0, stream>>>(x, xbf);
  dim3 gt(16, 16);
  transp_w<<<gt, 256, 0, stream>>>(Wq, Wqt);
  transp_w<<<gt, 256, 0, stream>>>(Wk, Wkt);
  transp_w<<<gt, 256, 0, stream>>>(Wv, Wvt);
  transp_w<<<gt, 256, 0, stream>>>(Wo, Wot);

  dim3 gg(MROWS / 128, DMODEL / 128);  // (64, 4)
  gemm_mfma<1><<<gg, 256, 0, stream>>>(xbf, Wqt, bq, Qbf);
  gemm_mfma<1><<<gg, 256, 0, stream>>>(xbf, Wkt, bk, Kbf);
  gemm_mfma<2><<<gg, 256, 0, stream>>>(xbf, Wvt, bv, Vtb);

  dim3 ga(S_LEN / 64, BATCH * NHEADS);  // (64, 16)
  attn_mfma<<<ga, 256, 0, stream>>>(Qbf, Kbf, Vtb, AOb);

  gemm_mfma<0><<<gg, 256, 0, stream>>>(AOb, Wot, bo, out);
}

// Round 6
// 172.909 us; speedup vs baseline: 9.2063x; 1.0219x over previous
//
#include <hip/hip_runtime.h>
#include <hip/hip_bf16.h>

#define S_LEN 4096
#define DMODEL 512
#define NHEADS 8
#define DK 64
#define BATCH 2
#define MROWS (BATCH * S_LEN)  // 8192

typedef __attribute__((ext_vector_type(8))) short bf16x8;
typedef __attribute__((ext_vector_type(4))) float f32x4;
typedef unsigned short ushort_t;

__device__ __forceinline__ unsigned packbf(float a, float b) {
  union { __hip_bfloat16 h; unsigned short s; } ua, ub;
  ua.h = __float2bfloat16(a);
  ub.h = __float2bfloat16(b);
  return (unsigned)ua.s | ((unsigned)ub.s << 16);
}

__device__ __forceinline__ unsigned short bf1(float a) {
  union { __hip_bfloat16 h; unsigned short s; } u;
  u.h = __float2bfloat16(a);
  return u.s;
}

__device__ __forceinline__ void gll16(const void* g, void* l) {
  __builtin_amdgcn_global_load_lds(
      (const __attribute__((address_space(1))) unsigned*)g,
      (__attribute__((address_space(3))) unsigned*)l, 16, 0, 0);
}

// ---------------------------------------------------------------------------
// x fp32 -> bf16, 8 elems/thread
// ---------------------------------------------------------------------------
__global__ __launch_bounds__(256) void cvt_bf16(const float* __restrict__ in,
                                                ushort_t* __restrict__ out) {
  size_t i = ((size_t)blockIdx.x * 256 + threadIdx.x) * 8;
  float4 a = *reinterpret_cast<const float4*>(in + i);
  float4 b = *reinterpret_cast<const float4*>(in + i + 4);
  uint4 o;
  o.x = packbf(a.x, a.y);
  o.y = packbf(a.z, a.w);
  o.z = packbf(b.x, b.y);
  o.w = packbf(b.z, b.w);
  *reinterpret_cast<uint4*>(out + i) = o;
}

// ---------------------------------------------------------------------------
// W[512,512] fp32 (k,n) -> Wt[512,512] bf16 (n,k). 32x32 tiles, 256 thr.
// ---------------------------------------------------------------------------
__global__ __launch_bounds__(256) void transp_w(const float* __restrict__ W,
                                                ushort_t* __restrict__ Wt) {
  __shared__ float T[32][33];
  const int tid = threadIdx.x;
  const int k0 = blockIdx.x * 32, n0 = blockIdx.y * 32;
  const int r = tid >> 3, c4 = (tid & 7) * 4;
  float4 v = *reinterpret_cast<const float4*>(W + (size_t)(k0 + r) * 512 + n0 + c4);
  T[r][c4 + 0] = v.x; T[r][c4 + 1] = v.y; T[r][c4 + 2] = v.z; T[r][c4 + 3] = v.w;
  __syncthreads();
  uint2 o;
  o.x = packbf(T[c4 + 0][r], T[c4 + 1][r]);
  o.y = packbf(T[c4 + 2][r], T[c4 + 3][r]);
  *reinterpret_cast<uint2*>(Wt + (size_t)(n0 + r) * 512 + k0 + c4) = o;
}

// ---------------------------------------------------------------------------
// MFMA GEMM: C = (A[M,512](bf16) @ Wt[N,K]^T(bf16) + bias) * scale
// 128x128 tile, BK=32, 256 threads = 4 waves (2x2 of 64x64).
// MODE 0: fp32 [M,512]; MODE 1: bf16 head-split [B,H,S,DK]; MODE 2: bf16 V^T.
// ---------------------------------------------------------------------------
template <int MODE>
__global__ __launch_bounds__(256) void gemm_mfma(
    const ushort_t* __restrict__ A, const ushort_t* __restrict__ Wt,
    const float* __restrict__ bias, void* __restrict__ outp, float scale) {
  __shared__ ushort_t AL[2][128 * 32];
  __shared__ ushort_t BL[2][128 * 32];
  const int tid = threadIdx.x;
  const int wid = tid >> 6;
  const int lane = tid & 63;
  const int ql = lane & 15;
  const int g = lane >> 4;
  const int wr = wid >> 1, wc = wid & 1;
  const int m0 = blockIdx.x * 128, n0 = blockIdx.y * 128;

  f32x4 acc[4][4];
#pragma unroll
  for (int i = 0; i < 4; ++i)
#pragma unroll
    for (int j = 0; j < 4; ++j) acc[i][j] = (f32x4){0.f, 0.f, 0.f, 0.f};

  auto stage = [&](int k0, int buf) {
#pragma unroll
    for (int i = 0; i < 2; ++i) {
      int idx = i * 256 + tid;
      int r = idx >> 2;
      int c = (idx & 3) * 8;
      gll16(A + (size_t)(m0 + r) * 512 + k0 + c, &AL[buf][idx * 8]);
      gll16(Wt + (size_t)(n0 + r) * 512 + k0 + c, &BL[buf][idx * 8]);
    }
  };

  stage(0, 0);
  __syncthreads();
  int buf = 0;

  for (int t = 0; t < 16; ++t) {
    if (t < 15) stage((t + 1) * 32, buf ^ 1);
    const ushort_t* ALb = &AL[buf][0];
    const ushort_t* BLb = &BL[buf][0];
    bf16x8 af[4], bfr[4];
#pragma unroll
    for (int mi = 0; mi < 4; ++mi)
      af[mi] = *reinterpret_cast<const bf16x8*>(ALb + (wr * 64 + mi * 16 + ql) * 32 + g * 8);
#pragma unroll
    for (int ni = 0; ni < 4; ++ni)
      bfr[ni] = *reinterpret_cast<const bf16x8*>(BLb + (wc * 64 + ni * 16 + ql) * 32 + g * 8);
#pragma unroll
    for (int mi = 0; mi < 4; ++mi)
#pragma unroll
      for (int ni = 0; ni < 4; ++ni)
        acc[mi][ni] = __builtin_amdgcn_mfma_f32_16x16x32_bf16(af[mi], bfr[ni], acc[mi][ni], 0, 0, 0);
    __syncthreads();
    buf ^= 1;
  }

  float bv[4];
#pragma unroll
  for (int ni = 0; ni < 4; ++ni) bv[ni] = bias[n0 + wc * 64 + ni * 16 + ql];

#pragma unroll
  for (int mi = 0; mi < 4; ++mi) {
#pragma unroll
    for (int ni = 0; ni < 4; ++ni) {
      int n = n0 + wc * 64 + ni * 16 + ql;
#pragma unroll
      for (int reg = 0; reg < 4; ++reg) {
        float val = (acc[mi][ni][reg] + bv[ni]) * scale;
        int m = m0 + wr * 64 + mi * 16 + 4 * g + reg;
        if (MODE == 0) {
          ((float*)outp)[(size_t)m * 512 + n] = val;
        } else if (MODE == 1) {
          int b = m >> 12, s = m & 4095;
          int h = n >> 6, d = n & 63;
          ((ushort_t*)outp)[(((size_t)(b * NHEADS + h) * S_LEN + s) * DK) + d] = bf1(val);
        } else {
          int b = m >> 12, s = m & 4095;
          int h = n >> 6, d = n & 63;
          ((ushort_t*)outp)[(((size_t)(b * NHEADS + h) * DK + d) * S_LEN) + s] = bf1(val);
        }
      }
    }
  }
}

// ---------------------------------------------------------------------------
// MFMA flash attention, no-max softmax. Q pre-scaled by 0.125*log2e, so
// p = exp2(s) directly. l computed via ones-row MFMA (no VALU adds, no
// epilogue shuffles). SPLIT2: blockIdx.z halves the key range; partial
// fp32 O + l written for a combine pass.
// ---------------------------------------------------------------------------
template <bool SPLIT2>
__global__ __launch_bounds__(256, 5) void attn_mfma(
    const ushort_t* __restrict__ Q, const ushort_t* __restrict__ K,
    const ushort_t* __restrict__ Vt, ushort_t* __restrict__ AO,
    float* __restrict__ Opart, float* __restrict__ Lpart) {
  __shared__ ushort_t KL[2][64 * 64];
  __shared__ ushort_t VL[2][64 * 64];

  const int tid = threadIdx.x;
  const int wid = tid >> 6;
  const int lane = tid & 63;
  const int g = lane >> 4;
  const int ql = lane & 15;
  const int bh = blockIdx.y;
  const int sp = SPLIT2 ? blockIdx.z : 0;
  const int NT = SPLIT2 ? 32 : 64;
  const int t0 = sp * NT;

  const ushort_t* Qb = Q + (size_t)bh * S_LEN * DK;
  const ushort_t* Kb = K + (size_t)bh * S_LEN * DK;
  const ushort_t* Vb = Vt + (size_t)bh * DK * S_LEN;

  const int qbase = blockIdx.x * 64 + wid * 16;

  bf16x8 qf[2];
#pragma unroll
  for (int t = 0; t < 2; ++t)
    qf[t] = *reinterpret_cast<const bf16x8*>(Qb + (size_t)(qbase + ql) * DK + t * 32 + g * 8);

  bf16x8 ones;
#pragma unroll
  for (int j = 0; j < 8; ++j) ones[j] = (short)0x3F80;  // bf16 1.0

  f32x4 ot[4];
#pragma unroll
  for (int db = 0; db < 4; ++db) ot[db] = (f32x4){0.f, 0.f, 0.f, 0.f};
  f32x4 lacc = (f32x4){0.f, 0.f, 0.f, 0.f};

  const int srow = lane >> 3;
  const int schk = lane & 7;

  auto stage = [&](int kt, int buf) {
#pragma unroll
    for (int i = 0; i < 2; ++i) {
      int r = wid * 16 + i * 8 + srow;
      int sc = (schk ^ (r & 7)) << 4;
      const char* gk = (const char*)Kb + ((size_t)(kt * 64 + r)) * 128 + sc;
      char* lk = (char*)&KL[buf][0] + (wid * 16 + i * 8) * 128 + lane * 16;
      gll16(gk, lk);
      const char* gv = (const char*)Vb + (size_t)r * (S_LEN * 2) + (size_t)kt * 128 + sc;
      char* lv = (char*)&VL[buf][0] + (wid * 16 + i * 8) * 128 + lane * 16;
      gll16(gv, lv);
    }
  };

  stage(t0, 0);
  __syncthreads();
  int buf = 0;

  for (int it = 0; it < NT; ++it) {
    const int kt = t0 + it;
    if (it < NT - 1) stage(kt + 1, buf ^ 1);

    const char* KB = (const char*)&KL[buf][0];
    const char* VB = (const char*)&VL[buf][0];

    // ---- S^T = K . Q^T (Q pre-scaled) : keys 16kb+4g+reg, col q=qbase+ql --
    f32x4 st[4];
    __builtin_amdgcn_s_setprio(1);
#pragma unroll
    for (int kb = 0; kb < 4; ++kb) {
      int r = kb * 16 + ql;
      bf16x8 k0 = *reinterpret_cast<const bf16x8*>(KB + r * 128 + (((g) ^ (r & 7)) << 4));
      bf16x8 k1 = *reinterpret_cast<const bf16x8*>(KB + r * 128 + (((g + 4) ^ (r & 7)) << 4));
      f32x4 z = (f32x4){0.f, 0.f, 0.f, 0.f};
      z = __builtin_amdgcn_mfma_f32_16x16x32_bf16(k0, qf[0], z, 0, 0, 0);
      z = __builtin_amdgcn_mfma_f32_16x16x32_bf16(k1, qf[1], z, 0, 0, 0);
      st[kb] = z;
    }
    __builtin_amdgcn_s_setprio(0);

    // ---- p = exp2(s) ----
    unsigned pk[4][2];
#pragma unroll
    for (int kb = 0; kb < 4; ++kb) {
#pragma unroll
      for (int r2 = 0; r2 < 2; ++r2) {
        float pa = __builtin_amdgcn_exp2f(st[kb][2 * r2]);
        float pb_ = __builtin_amdgcn_exp2f(st[kb][2 * r2 + 1]);
        pk[kb][r2] = packbf(pa, pb_);
      }
    }

    // ---- PV + l: O^T += V^T . P^T ; l = ones . P^T ----
    __builtin_amdgcn_s_setprio(1);
#pragma unroll
    for (int t = 0; t < 2; ++t) {
      union { unsigned u[4]; bf16x8 v; } pb;
      pb.u[0] = pk[2 * t][0];     pb.u[1] = pk[2 * t][1];
      pb.u[2] = pk[2 * t + 1][0]; pb.u[3] = pk[2 * t + 1][1];
#pragma unroll
      for (int db = 0; db < 4; ++db) {
        int rd = db * 16 + ql;
        int c1 = t * 4 + (g >> 1);
        int intra = (g & 1) << 3;
        uint2 lo = *reinterpret_cast<const uint2*>(VB + rd * 128 + ((c1 ^ (rd & 7)) << 4) + intra);
        uint2 hi = *reinterpret_cast<const uint2*>(VB + rd * 128 + (((c1 + 2) ^ (rd & 7)) << 4) + intra);
        union { unsigned u[4]; bf16x8 v; } af;
        af.u[0] = lo.x; af.u[1] = lo.y; af.u[2] = hi.x; af.u[3] = hi.y;
        ot[db] = __builtin_amdgcn_mfma_f32_16x16x32_bf16(af.v, pb.v, ot[db], 0, 0, 0);
      }
      lacc = __builtin_amdgcn_mfma_f32_16x16x32_bf16(ones, pb.v, lacc, 0, 0, 0);
    }
    __builtin_amdgcn_s_setprio(0);

    __syncthreads();
    buf ^= 1;
  }

  const float l = lacc[0];  // full key-sum of this split, same in all lanes/regs
  const int q = qbase + ql;

  if (SPLIT2) {
    float* Ob = Opart + (((size_t)sp * 16 + bh) * S_LEN) * 64;
#pragma unroll
    for (int db = 0; db < 4; ++db) {
      float4 o = make_float4(ot[db][0], ot[db][1], ot[db][2], ot[db][3]);
      *reinterpret_cast<float4*>(Ob + (size_t)q * 64 + db * 16 + 4 * g) = o;
    }
    if (g == 0) Lpart[((size_t)sp * 16 + bh) * S_LEN + q] = l;
  } else {
    float inv = 1.f / l;
    const int b = bh >> 3, h = bh & 7;
#pragma unroll
    for (int db = 0; db < 4; ++db) {
      uint2 o;
      o.x = packbf(ot[db][0] * inv, ot[db][1] * inv);
      o.y = packbf(ot[db][2] * inv, ot[db][3] * inv);
      *reinterpret_cast<uint2*>(AO + ((size_t)b * S_LEN + q) * DMODEL + h * DK + db * 16 + g * 4) = o;
    }
  }
}

// ---------------------------------------------------------------------------
// Combine the 2 KV-split partials: AO = (O0+O1)/(l0+l1), bf16.
// 8 d-elems per thread; grid 2048 x 256.
// ---------------------------------------------------------------------------
__global__ __launch_bounds__(256) void combine_o(
    const float* __restrict__ Opart, const float* __restrict__ Lpart,
    ushort_t* __restrict__ AO) {
  int idx = blockIdx.x * 256 + threadIdx.x;  // 524288 total
  int dblk = idx & 7;
  int q = (idx >> 3) & 4095;
  int bh = idx >> 15;
  size_t o0 = ((size_t)bh * S_LEN + q) * 64 + dblk * 8;
  size_t o1 = o0 + (size_t)16 * S_LEN * 64;
  float4 a0 = *reinterpret_cast<const float4*>(Opart + o0);
  float4 b0 = *reinterpret_cast<const float4*>(Opart + o0 + 4);
  float4 a1 = *reinterpret_cast<const float4*>(Opart + o1);
  float4 b1 = *reinterpret_cast<const float4*>(Opart + o1 + 4);
  float l = Lpart[(size_t)bh * S_LEN + q] + Lpart[(size_t)(16 + bh) * S_LEN + q];
  float inv = 1.0f / l;
  int b = bh >> 3, h = bh & 7;
  uint4 o;
  o.x = packbf((a0.x + a1.x) * inv, (a0.y + a1.y) * inv);
  o.y = packbf((a0.z + a1.z) * inv, (a0.w + a1.w) * inv);
  o.z = packbf((b0.x + b1.x) * inv, (b0.y + b1.y) * inv);
  o.w = packbf((b0.z + b1.z) * inv, (b0.w + b1.w) * inv);
  *reinterpret_cast<uint4*>(AO + ((size_t)b * S_LEN + q) * DMODEL + h * 64 + dblk * 8) = o;
}

extern "C" void kernel_launch(void* const* d_in, const int* in_sizes, int n_in,
                              void* d_out, int out_size, void* d_ws, size_t ws_size,
                              hipStream_t stream) {
  const float* x  = (const float*)d_in[0];
  const float* Wq = (const float*)d_in[1];
  const float* bq = (const float*)d_in[2];
  const float* Wk = (const float*)d_in[3];
  const float* bk = (const float*)d_in[4];
  const float* Wv = (const float*)d_in[5];
  const float* bv = (const float*)d_in[6];
  const float* Wo = (const float*)d_in[7];
  const float* bo = (const float*)d_in[8];
  float* out = (float*)d_out;

  const float CQ = 0.18033688f;  // 0.125 * log2(e)

  char* ws = (char*)d_ws;
  const size_t NBF = (size_t)MROWS * DMODEL;  // 4 Mi elements
  // Shared prefix layout (both paths):
  //  [0]        xbf   8MB   (reused as AOb in split path after attn)
  //  [NBF*2]    Qbf   8MB
  //  [NBF*4]    Kbf   8MB
  //  [NBF*6]    Vtb   8MB
  ushort_t* xbf = (ushort_t*)ws;
  ushort_t* Qbf = (ushort_t*)(ws + NBF * 2);
  ushort_t* Kbf = (ushort_t*)(ws + NBF * 4);
  ushort_t* Vtb = (ushort_t*)(ws + NBF * 6);

  // split path extras
  const size_t OFF_WT    = NBF * 8;                       // 32MB: 4 x 512KB Wt
  const size_t OFF_LPART = OFF_WT + 4 * 512 * 512 * 2;    // 34MB: 512KB Lpart
  const size_t OFF_OPART = OFF_LPART + 512 * 1024;        // 34.5MB: 32MB Opart
  const size_t NEED_SPLIT = OFF_OPART + (size_t)2 * 16 * S_LEN * 64 * 4;  // 66.5MB
  const bool use_split = ws_size >= NEED_SPLIT;

  ushort_t* Wqt;
  ushort_t* AOb;
  if (use_split) {
    Wqt = (ushort_t*)(ws + OFF_WT);
    AOb = xbf;  // xbf dead after V GEMM; combine writes here
  } else {
    AOb = (ushort_t*)(ws + NBF * 8);
    Wqt = (ushort_t*)(ws + NBF * 10);
  }
  ushort_t* Wkt = Wqt + 512 * 512;
  ushort_t* Wvt = Wkt + 512 * 512;
  ushort_t* Wot = Wvt + 512 * 512;
  float* Lpart = (float*)(ws + OFF_LPART);
  float* Opart = (float*)(ws + OFF_OPART);

  cvt_bf16<<<MROWS * DMODEL / 2048, 256, 0, stream>>>(x, xbf);
  dim3 gt(16, 16);
  transp_w<<<gt, 256, 0, stream>>>(Wq, Wqt);
  transp_w<<<gt, 256, 0, stream>>>(Wk, Wkt);
  transp_w<<<gt, 256, 0, stream>>>(Wv, Wvt);
  transp_w<<<gt, 256, 0, stream>>>(Wo, Wot);

  dim3 gg(MROWS / 128, DMODEL / 128);  // (64, 4)
  gemm_mfma<1><<<gg, 256, 0, stream>>>(xbf, Wqt, bq, Qbf, CQ);
  gemm_mfma<1><<<gg, 256, 0, stream>>>(xbf, Wkt, bk, Kbf, 1.0f);
  gemm_mfma<2><<<gg, 256, 0, stream>>>(xbf, Wvt, bv, Vtb, 1.0f);

  if (use_split) {
    dim3 ga(S_LEN / 64, BATCH * NHEADS, 2);  // (64, 16, 2)
    attn_mfma<true><<<ga, 256, 0, stream>>>(Qbf, Kbf, Vtb, AOb, Opart, Lpart);
    combine_o<<<2048, 256, 0, stream>>>(Opart, Lpart, AOb);
  } else {
    dim3 ga(S_LEN / 64, BATCH * NHEADS, 1);
    attn_mfma<false><<<ga, 256, 0, stream>>>(Qbf, Kbf, Vtb, AOb, Opart, Lpart);
  }

  gemm_mfma<0><<<gg, 256, 0, stream>>>(AOb, Wot, bo, out, 1.0f);
}

// Round 7
// 142.440 us; speedup vs baseline: 11.1756x; 1.2139x over previous
//
#include <hip/hip_runtime.h>
#include <hip/hip_bf16.h>

#define S_LEN 4096
#define DMODEL 512
#define NHEADS 8
#define DK 64
#define BATCH 2
#define MROWS (BATCH * S_LEN)  // 8192

typedef __attribute__((ext_vector_type(8))) short bf16x8;
typedef __attribute__((ext_vector_type(4))) float f32x4;
typedef unsigned short ushort_t;

__device__ __forceinline__ unsigned packbf(float a, float b) {
  union { __hip_bfloat16 h; unsigned short s; } ua, ub;
  ua.h = __float2bfloat16(a);
  ub.h = __float2bfloat16(b);
  return (unsigned)ua.s | ((unsigned)ub.s << 16);
}

__device__ __forceinline__ unsigned short bf1(float a) {
  union { __hip_bfloat16 h; unsigned short s; } u;
  u.h = __float2bfloat16(a);
  return u.s;
}

__device__ __forceinline__ void gll16(const void* g, void* l) {
  __builtin_amdgcn_global_load_lds(
      (const __attribute__((address_space(1))) unsigned*)g,
      (__attribute__((address_space(3))) unsigned*)l, 16, 0, 0);
}

// ---------------------------------------------------------------------------
// x fp32 -> bf16, 8 elems/thread
// ---------------------------------------------------------------------------
__global__ __launch_bounds__(256) void cvt_bf16(const float* __restrict__ in,
                                                ushort_t* __restrict__ out) {
  size_t i = ((size_t)blockIdx.x * 256 + threadIdx.x) * 8;
  float4 a = *reinterpret_cast<const float4*>(in + i);
  float4 b = *reinterpret_cast<const float4*>(in + i + 4);
  uint4 o;
  o.x = packbf(a.x, a.y);
  o.y = packbf(a.z, a.w);
  o.z = packbf(b.x, b.y);
  o.w = packbf(b.z, b.w);
  *reinterpret_cast<uint4*>(out + i) = o;
}

// ---------------------------------------------------------------------------
// W[512,512] fp32 (k,n) -> Wt[512,512] bf16 (n,k). 32x32 tiles, 256 thr.
// ---------------------------------------------------------------------------
__global__ __launch_bounds__(256) void transp_w(const float* __restrict__ W,
                                                ushort_t* __restrict__ Wt) {
  __shared__ float T[32][33];
  const int tid = threadIdx.x;
  const int k0 = blockIdx.x * 32, n0 = blockIdx.y * 32;
  const int r = tid >> 3, c4 = (tid & 7) * 4;
  float4 v = *reinterpret_cast<const float4*>(W + (size_t)(k0 + r) * 512 + n0 + c4);
  T[r][c4 + 0] = v.x; T[r][c4 + 1] = v.y; T[r][c4 + 2] = v.z; T[r][c4 + 3] = v.w;
  __syncthreads();
  uint2 o;
  o.x = packbf(T[c4 + 0][r], T[c4 + 1][r]);
  o.y = packbf(T[c4 + 2][r], T[c4 + 3][r]);
  *reinterpret_cast<uint2*>(Wt + (size_t)(n0 + r) * 512 + k0 + c4) = o;
}

// ---------------------------------------------------------------------------
// Fused QKV GEMM: [Q|K|V] = x[8192,512] @ Wcat[1536,512]^T + b{q,k,v}
// 128x128 tile, BK=32, 256 threads = 4 waves. Q region scaled by CQ.
// Q,K -> bf16 head-split [B,H,S,DK]; V -> bf16 transposed [B,H,DK,S].
// ---------------------------------------------------------------------------
__global__ __launch_bounds__(256) void gemm_qkv(
    const ushort_t* __restrict__ A, const ushort_t* __restrict__ Wcat,
    const float* __restrict__ bq, const float* __restrict__ bk,
    const float* __restrict__ bv, ushort_t* __restrict__ Qo,
    ushort_t* __restrict__ Ko, ushort_t* __restrict__ Vo, float CQ) {
  __shared__ ushort_t AL[2][128 * 32];
  __shared__ ushort_t BL[2][128 * 32];
  const int tid = threadIdx.x;
  const int wid = tid >> 6;
  const int lane = tid & 63;
  const int ql = lane & 15;
  const int g = lane >> 4;
  const int wr = wid >> 1, wc = wid & 1;
  const int m0 = blockIdx.x * 128, n0 = blockIdx.y * 128;
  const int region = n0 >> 9;  // 0=Q 1=K 2=V

  f32x4 acc[4][4];
#pragma unroll
  for (int i = 0; i < 4; ++i)
#pragma unroll
    for (int j = 0; j < 4; ++j) acc[i][j] = (f32x4){0.f, 0.f, 0.f, 0.f};

  auto stage = [&](int k0, int buf) {
#pragma unroll
    for (int i = 0; i < 2; ++i) {
      int idx = i * 256 + tid;
      int r = idx >> 2;
      int c = (idx & 3) * 8;
      gll16(A + (size_t)(m0 + r) * 512 + k0 + c, &AL[buf][idx * 8]);
      gll16(Wcat + (size_t)(n0 + r) * 512 + k0 + c, &BL[buf][idx * 8]);
    }
  };

  stage(0, 0);
  __syncthreads();
  int buf = 0;

  for (int t = 0; t < 16; ++t) {
    if (t < 15) stage((t + 1) * 32, buf ^ 1);
    const ushort_t* ALb = &AL[buf][0];
    const ushort_t* BLb = &BL[buf][0];
    bf16x8 af[4], bfr[4];
#pragma unroll
    for (int mi = 0; mi < 4; ++mi)
      af[mi] = *reinterpret_cast<const bf16x8*>(ALb + (wr * 64 + mi * 16 + ql) * 32 + g * 8);
#pragma unroll
    for (int ni = 0; ni < 4; ++ni)
      bfr[ni] = *reinterpret_cast<const bf16x8*>(BLb + (wc * 64 + ni * 16 + ql) * 32 + g * 8);
#pragma unroll
    for (int mi = 0; mi < 4; ++mi)
#pragma unroll
      for (int ni = 0; ni < 4; ++ni)
        acc[mi][ni] = __builtin_amdgcn_mfma_f32_16x16x32_bf16(af[mi], bfr[ni], acc[mi][ni], 0, 0, 0);
    __syncthreads();
    buf ^= 1;
  }

  const float* bias = region == 0 ? bq : (region == 1 ? bk : bv);
  const float scale = region == 0 ? CQ : 1.0f;
  const int nl0 = n0 - (region << 9);
  ushort_t* outT = region == 0 ? Qo : Ko;

  float bvv[4];
#pragma unroll
  for (int ni = 0; ni < 4; ++ni) bvv[ni] = bias[nl0 + wc * 64 + ni * 16 + ql];

#pragma unroll
  for (int mi = 0; mi < 4; ++mi) {
#pragma unroll
    for (int ni = 0; ni < 4; ++ni) {
      int nl = nl0 + wc * 64 + ni * 16 + ql;
      int h = nl >> 6, d = nl & 63;
#pragma unroll
      for (int reg = 0; reg < 4; ++reg) {
        float val = (acc[mi][ni][reg] + bvv[ni]) * scale;
        int m = m0 + wr * 64 + mi * 16 + 4 * g + reg;
        int b = m >> 12, s = m & 4095;
        if (region <= 1) {
          outT[(((size_t)(b * NHEADS + h) * S_LEN + s) * DK) + d] = bf1(val);
        } else {
          Vo[(((size_t)(b * NHEADS + h) * DK + d) * S_LEN) + s] = bf1(val);
        }
      }
    }
  }
}

// ---------------------------------------------------------------------------
// MFMA GEMM (Wo): out = A[M,512](bf16) @ Wt[512,512]^T + bias, fp32 out.
// ---------------------------------------------------------------------------
__global__ __launch_bounds__(256) void gemm_wo(
    const ushort_t* __restrict__ A, const ushort_t* __restrict__ Wt,
    const float* __restrict__ bias, float* __restrict__ out) {
  __shared__ ushort_t AL[2][128 * 32];
  __shared__ ushort_t BL[2][128 * 32];
  const int tid = threadIdx.x;
  const int wid = tid >> 6;
  const int lane = tid & 63;
  const int ql = lane & 15;
  const int g = lane >> 4;
  const int wr = wid >> 1, wc = wid & 1;
  const int m0 = blockIdx.x * 128, n0 = blockIdx.y * 128;

  f32x4 acc[4][4];
#pragma unroll
  for (int i = 0; i < 4; ++i)
#pragma unroll
    for (int j = 0; j < 4; ++j) acc[i][j] = (f32x4){0.f, 0.f, 0.f, 0.f};

  auto stage = [&](int k0, int buf) {
#pragma unroll
    for (int i = 0; i < 2; ++i) {
      int idx = i * 256 + tid;
      int r = idx >> 2;
      int c = (idx & 3) * 8;
      gll16(A + (size_t)(m0 + r) * 512 + k0 + c, &AL[buf][idx * 8]);
      gll16(Wt + (size_t)(n0 + r) * 512 + k0 + c, &BL[buf][idx * 8]);
    }
  };

  stage(0, 0);
  __syncthreads();
  int buf = 0;

  for (int t = 0; t < 16; ++t) {
    if (t < 15) stage((t + 1) * 32, buf ^ 1);
    const ushort_t* ALb = &AL[buf][0];
    const ushort_t* BLb = &BL[buf][0];
    bf16x8 af[4], bfr[4];
#pragma unroll
    for (int mi = 0; mi < 4; ++mi)
      af[mi] = *reinterpret_cast<const bf16x8*>(ALb + (wr * 64 + mi * 16 + ql) * 32 + g * 8);
#pragma unroll
    for (int ni = 0; ni < 4; ++ni)
      bfr[ni] = *reinterpret_cast<const bf16x8*>(BLb + (wc * 64 + ni * 16 + ql) * 32 + g * 8);
#pragma unroll
    for (int mi = 0; mi < 4; ++mi)
#pragma unroll
      for (int ni = 0; ni < 4; ++ni)
        acc[mi][ni] = __builtin_amdgcn_mfma_f32_16x16x32_bf16(af[mi], bfr[ni], acc[mi][ni], 0, 0, 0);
    __syncthreads();
    buf ^= 1;
  }

  float bv[4];
#pragma unroll
  for (int ni = 0; ni < 4; ++ni) bv[ni] = bias[n0 + wc * 64 + ni * 16 + ql];

#pragma unroll
  for (int mi = 0; mi < 4; ++mi) {
#pragma unroll
    for (int ni = 0; ni < 4; ++ni) {
      int n = n0 + wc * 64 + ni * 16 + ql;
#pragma unroll
      for (int reg = 0; reg < 4; ++reg) {
        int m = m0 + wr * 64 + mi * 16 + 4 * g + reg;
        out[(size_t)m * 512 + n] = acc[mi][ni][reg] + bv[ni];
      }
    }
  }
}

// ---------------------------------------------------------------------------
// MFMA flash attention, no-max softmax, 32 q/wave (128 q/block).
// Flat grid, XCD-swizzled so each XCD owns contiguous (bh,sp) groups
// (K/V working set 2MB -> L2-resident). l via ones-row MFMA.
// SPLIT2: blockIdx halves the key range; partial fp32 O + l written.
// ---------------------------------------------------------------------------
template <bool SPLIT2>
__global__ __launch_bounds__(256, 4) void attn_mfma(
    const ushort_t* __restrict__ Q, const ushort_t* __restrict__ K,
    const ushort_t* __restrict__ Vt, ushort_t* __restrict__ AO,
    float* __restrict__ Opart, float* __restrict__ Lpart) {
  __shared__ ushort_t KL[2][64 * 64];
  __shared__ ushort_t VL[2][64 * 64];

  const int tid = threadIdx.x;
  const int wid = tid >> 6;
  const int lane = tid & 63;
  const int g = lane >> 4;
  const int ql = lane & 15;

  // XCD-aware remap: 1024 blocks, orig&7 = XCD -> L contiguous per XCD.
  int L;
  if (SPLIT2) {
    int orig = blockIdx.x;
    L = (orig & 7) * 128 + (orig >> 3);
  } else {
    L = blockIdx.x;
  }
  const int qt = L & 31;
  const int bhsp = L >> 5;
  const int sp = SPLIT2 ? (bhsp & 1) : 0;
  const int bh = SPLIT2 ? (bhsp >> 1) : bhsp;
  const int NT = SPLIT2 ? 32 : 64;
  const int t0 = sp * NT;

  const ushort_t* Qb = Q + (size_t)bh * S_LEN * DK;
  const ushort_t* Kb = K + (size_t)bh * S_LEN * DK;
  const ushort_t* Vb = Vt + (size_t)bh * DK * S_LEN;

  const int qbase = qt * 128 + wid * 32;

  // Q B-fragments: qf[c][t]: col q = qbase+16c+ql, k = 32t + 8g + j
  bf16x8 qf[2][2];
#pragma unroll
  for (int c = 0; c < 2; ++c) {
    int q = qbase + c * 16 + ql;
#pragma unroll
    for (int t = 0; t < 2; ++t)
      qf[c][t] = *reinterpret_cast<const bf16x8*>(Qb + (size_t)q * DK + t * 32 + g * 8);
  }

  bf16x8 ones;
#pragma unroll
  for (int j = 0; j < 8; ++j) ones[j] = (short)0x3F80;  // bf16 1.0

  f32x4 ot[4][2];
#pragma unroll
  for (int db = 0; db < 4; ++db)
#pragma unroll
    for (int c = 0; c < 2; ++c) ot[db][c] = (f32x4){0.f, 0.f, 0.f, 0.f};
  f32x4 lacc[2];
  lacc[0] = (f32x4){0.f, 0.f, 0.f, 0.f};
  lacc[1] = (f32x4){0.f, 0.f, 0.f, 0.f};

  const int srow = lane >> 3;
  const int schk = lane & 7;

  auto stage = [&](int kt, int buf) {
#pragma unroll
    for (int i = 0; i < 2; ++i) {
      int r = wid * 16 + i * 8 + srow;
      int sc = (schk ^ (r & 7)) << 4;
      const char* gk = (const char*)Kb + ((size_t)(kt * 64 + r)) * 128 + sc;
      char* lk = (char*)&KL[buf][0] + (wid * 16 + i * 8) * 128 + lane * 16;
      gll16(gk, lk);
      const char* gv = (const char*)Vb + (size_t)r * (S_LEN * 2) + (size_t)kt * 128 + sc;
      char* lv = (char*)&VL[buf][0] + (wid * 16 + i * 8) * 128 + lane * 16;
      gll16(gv, lv);
    }
  };

  stage(t0, 0);
  __syncthreads();
  int buf = 0;

  for (int it = 0; it < NT; ++it) {
    const int kt = t0 + it;
    if (it < NT - 1) stage(kt + 1, buf ^ 1);

    const char* KB = (const char*)&KL[buf][0];
    const char* VB = (const char*)&VL[buf][0];

    // ---- S^T = K . Q^T : keys 16kb+4g+reg, cols q = qbase+16c+ql ----
    f32x4 st[4][2];
    __builtin_amdgcn_s_setprio(1);
#pragma unroll
    for (int kb = 0; kb < 4; ++kb) {
      int r = kb * 16 + ql;
      bf16x8 k0 = *reinterpret_cast<const bf16x8*>(KB + r * 128 + (((g) ^ (r & 7)) << 4));
      bf16x8 k1 = *reinterpret_cast<const bf16x8*>(KB + r * 128 + (((g + 4) ^ (r & 7)) << 4));
#pragma unroll
      for (int c = 0; c < 2; ++c) {
        f32x4 z = (f32x4){0.f, 0.f, 0.f, 0.f};
        z = __builtin_amdgcn_mfma_f32_16x16x32_bf16(k0, qf[c][0], z, 0, 0, 0);
        z = __builtin_amdgcn_mfma_f32_16x16x32_bf16(k1, qf[c][1], z, 0, 0, 0);
        st[kb][c] = z;
      }
    }
    __builtin_amdgcn_s_setprio(0);

    // ---- p = exp2(s)  (Q pre-scaled by 0.125*log2e) ----
    unsigned pk[2][4][2];
#pragma unroll
    for (int c = 0; c < 2; ++c)
#pragma unroll
      for (int kb = 0; kb < 4; ++kb)
#pragma unroll
        for (int r2 = 0; r2 < 2; ++r2) {
          float pa = __builtin_amdgcn_exp2f(st[kb][c][2 * r2]);
          float pb_ = __builtin_amdgcn_exp2f(st[kb][c][2 * r2 + 1]);
          pk[c][kb][r2] = packbf(pa, pb_);
        }

    // ---- PV + l: O^T += V^T . P^T ; l = ones . P^T ----
    __builtin_amdgcn_s_setprio(1);
#pragma unroll
    for (int t = 0; t < 2; ++t) {
      union { unsigned u[4]; bf16x8 v; } pb0, pb1;
      pb0.u[0] = pk[0][2 * t][0];     pb0.u[1] = pk[0][2 * t][1];
      pb0.u[2] = pk[0][2 * t + 1][0]; pb0.u[3] = pk[0][2 * t + 1][1];
      pb1.u[0] = pk[1][2 * t][0];     pb1.u[1] = pk[1][2 * t][1];
      pb1.u[2] = pk[1][2 * t + 1][0]; pb1.u[3] = pk[1][2 * t + 1][1];
#pragma unroll
      for (int db = 0; db < 4; ++db) {
        int rd = db * 16 + ql;
        int c1 = t * 4 + (g >> 1);
        int intra = (g & 1) << 3;
        uint2 lo = *reinterpret_cast<const uint2*>(VB + rd * 128 + ((c1 ^ (rd & 7)) << 4) + intra);
        uint2 hi = *reinterpret_cast<const uint2*>(VB + rd * 128 + (((c1 + 2) ^ (rd & 7)) << 4) + intra);
        union { unsigned u[4]; bf16x8 v; } af;
        af.u[0] = lo.x; af.u[1] = lo.y; af.u[2] = hi.x; af.u[3] = hi.y;
        ot[db][0] = __builtin_amdgcn_mfma_f32_16x16x32_bf16(af.v, pb0.v, ot[db][0], 0, 0, 0);
        ot[db][1] = __builtin_amdgcn_mfma_f32_16x16x32_bf16(af.v, pb1.v, ot[db][1], 0, 0, 0);
      }
      lacc[0] = __builtin_amdgcn_mfma_f32_16x16x32_bf16(ones, pb0.v, lacc[0], 0, 0, 0);
      lacc[1] = __builtin_amdgcn_mfma_f32_16x16x32_bf16(ones, pb1.v, lacc[1], 0, 0, 0);
    }
    __builtin_amdgcn_s_setprio(0);

    __syncthreads();
    buf ^= 1;
  }

  if (SPLIT2) {
    float* Ob = Opart + (((size_t)sp * 16 + bh) * S_LEN) * 64;
#pragma unroll
    for (int c = 0; c < 2; ++c) {
      const int q = qbase + c * 16 + ql;
#pragma unroll
      for (int db = 0; db < 4; ++db) {
        float4 o = make_float4(ot[db][c][0], ot[db][c][1], ot[db][c][2], ot[db][c][3]);
        *reinterpret_cast<float4*>(Ob + (size_t)q * 64 + db * 16 + 4 * g) = o;
      }
      if (g == 0) Lpart[((size_t)sp * 16 + bh) * S_LEN + q] = lacc[c][0];
    }
  } else {
    const int b = bh >> 3, h = bh & 7;
#pragma unroll
    for (int c = 0; c < 2; ++c) {
      const int q = qbase + c * 16 + ql;
      float inv = 1.f / lacc[c][0];
#pragma unroll
      for (int db = 0; db < 4; ++db) {
        uint2 o;
        o.x = packbf(ot[db][c][0] * inv, ot[db][c][1] * inv);
        o.y = packbf(ot[db][c][2] * inv, ot[db][c][3] * inv);
        *reinterpret_cast<uint2*>(AO + ((size_t)b * S_LEN + q) * DMODEL + h * DK + db * 16 + g * 4) = o;
      }
    }
  }
}

// ---------------------------------------------------------------------------
// Combine the 2 KV-split partials: AO = (O0+O1)/(l0+l1), bf16.
// ---------------------------------------------------------------------------
__global__ __launch_bounds__(256) void combine_o(
    const float* __restrict__ Opart, const float* __restrict__ Lpart,
    ushort_t* __restrict__ AO) {
  int idx = blockIdx.x * 256 + threadIdx.x;  // 524288 total
  int dblk = idx & 7;
  int q = (idx >> 3) & 4095;
  int bh = idx >> 15;
  size_t o0 = ((size_t)bh * S_LEN + q) * 64 + dblk * 8;
  size_t o1 = o0 + (size_t)16 * S_LEN * 64;
  float4 a0 = *reinterpret_cast<const float4*>(Opart + o0);
  float4 b0 = *reinterpret_cast<const float4*>(Opart + o0 + 4);
  float4 a1 = *reinterpret_cast<const float4*>(Opart + o1);
  float4 b1 = *reinterpret_cast<const float4*>(Opart + o1 + 4);
  float l = Lpart[(size_t)bh * S_LEN + q] + Lpart[(size_t)(16 + bh) * S_LEN + q];
  float inv = 1.0f / l;
  int b = bh >> 3, h = bh & 7;
  uint4 o;
  o.x = packbf((a0.x + a1.x) * inv, (a0.y + a1.y) * inv);
  o.y = packbf((a0.z + a1.z) * inv, (a0.w + a1.w) * inv);
  o.z = packbf((b0.x + b1.x) * inv, (b0.y + b1.y) * inv);
  o.w = packbf((b0.z + b1.z) * inv, (b0.w + b1.w) * inv);
  *reinterpret_cast<uint4*>(AO + ((size_t)b * S_LEN + q) * DMODEL + h * 64 + dblk * 8) = o;
}

extern "C" void kernel_launch(void* const* d_in, const int* in_sizes, int n_in,
                              void* d_out, int out_size, void* d_ws, size_t ws_size,
                              hipStream_t stream) {
  const float* x  = (const float*)d_in[0];
  const float* Wq = (const float*)d_in[1];
  const float* bq = (const float*)d_in[2];
  const float* Wk = (const float*)d_in[3];
  const float* bk = (const float*)d_in[4];
  const float* Wv = (const float*)d_in[5];
  const float* bv = (const float*)d_in[6];
  const float* Wo = (const float*)d_in[7];
  const float* bo = (const float*)d_in[8];
  float* out = (float*)d_out;

  const float CQ = 0.18033688f;  // 0.125 * log2(e)

  char* ws = (char*)d_ws;
  const size_t NBF = (size_t)MROWS * DMODEL;  // 4 Mi elements
  ushort_t* xbf = (ushort_t*)ws;              // 8MB (reused as AOb in split)
  ushort_t* Qbf = (ushort_t*)(ws + NBF * 2);
  ushort_t* Kbf = (ushort_t*)(ws + NBF * 4);
  ushort_t* Vtb = (ushort_t*)(ws + NBF * 6);

  const size_t OFF_WT    = NBF * 8;                        // Wcat 1.5MB + Wot 0.5MB
  const size_t OFF_LPART = OFF_WT + 4 * 512 * 512 * 2;     // 512KB Lpart
  const size_t OFF_OPART = OFF_LPART + 512 * 1024;         // 32MB Opart
  const size_t NEED_SPLIT = OFF_OPART + (size_t)2 * 16 * S_LEN * 64 * 4;
  const bool use_split = ws_size >= NEED_SPLIT;

  ushort_t* Wcat;
  ushort_t* AOb;
  if (use_split) {
    Wcat = (ushort_t*)(ws + OFF_WT);
    AOb = xbf;
  } else {
    AOb = (ushort_t*)(ws + NBF * 8);
    Wcat = (ushort_t*)(ws + NBF * 10);
  }
  ushort_t* Wot = Wcat + 3 * 512 * 512;
  float* Lpart = (float*)(ws + OFF_LPART);
  float* Opart = (float*)(ws + OFF_OPART);

  cvt_bf16<<<MROWS * DMODEL / 2048, 256, 0, stream>>>(x, xbf);
  dim3 gt(16, 16);
  transp_w<<<gt, 256, 0, stream>>>(Wq, Wcat);
  transp_w<<<gt, 256, 0, stream>>>(Wk, Wcat + 512 * 512);
  transp_w<<<gt, 256, 0, stream>>>(Wv, Wcat + 2 * 512 * 512);
  transp_w<<<gt, 256, 0, stream>>>(Wo, Wot);

  dim3 gq(MROWS / 128, 1536 / 128);  // (64, 12)
  gemm_qkv<<<gq, 256, 0, stream>>>(xbf, Wcat, bq, bk, bv, Qbf, Kbf, Vtb, CQ);

  if (use_split) {
    attn_mfma<true><<<1024, 256, 0, stream>>>(Qbf, Kbf, Vtb, AOb, Opart, Lpart);
    combine_o<<<2048, 256, 0, stream>>>(Opart, Lpart, AOb);
  } else {
    attn_mfma<false><<<512, 256, 0, stream>>>(Qbf, Kbf, Vtb, AOb, Opart, Lpart);
  }

  dim3 gg(MROWS / 128, DMODEL / 128);  // (64, 4)
  gemm_wo<<<gg, 256, 0, stream>>>(AOb, Wot, bo, out);
}

// Round 8
// 139.894 us; speedup vs baseline: 11.3789x; 1.0182x over previous
//
#include <hip/hip_runtime.h>
#include <hip/hip_bf16.h>

#define S_LEN 4096
#define DMODEL 512
#define NHEADS 8
#define DK 64
#define BATCH 2
#define MROWS (BATCH * S_LEN)  // 8192

typedef __attribute__((ext_vector_type(8))) short bf16x8;
typedef __attribute__((ext_vector_type(4))) float f32x4;
typedef unsigned short ushort_t;

__device__ __forceinline__ unsigned packbf(float a, float b) {
  union { __hip_bfloat16 h; unsigned short s; } ua, ub;
  ua.h = __float2bfloat16(a);
  ub.h = __float2bfloat16(b);
  return (unsigned)ua.s | ((unsigned)ub.s << 16);
}

__device__ __forceinline__ unsigned short bf1(float a) {
  union { __hip_bfloat16 h; unsigned short s; } u;
  u.h = __float2bfloat16(a);
  return u.s;
}

__device__ __forceinline__ void gll16(const void* g, void* l) {
  __builtin_amdgcn_global_load_lds(
      (const __attribute__((address_space(1))) unsigned*)g,
      (__attribute__((address_space(3))) unsigned*)l, 16, 0, 0);
}

// ---------------------------------------------------------------------------
// x fp32 -> bf16, 8 elems/thread
// ---------------------------------------------------------------------------
__global__ __launch_bounds__(256) void cvt_bf16(const float* __restrict__ in,
                                                ushort_t* __restrict__ out) {
  size_t i = ((size_t)blockIdx.x * 256 + threadIdx.x) * 8;
  float4 a = *reinterpret_cast<const float4*>(in + i);
  float4 b = *reinterpret_cast<const float4*>(in + i + 4);
  uint4 o;
  o.x = packbf(a.x, a.y);
  o.y = packbf(a.z, a.w);
  o.z = packbf(b.x, b.y);
  o.w = packbf(b.z, b.w);
  *reinterpret_cast<uint4*>(out + i) = o;
}

// ---------------------------------------------------------------------------
// W[512,512] fp32 (k,n) -> Wt[512,512] bf16 (n,k). 32x32 tiles, 256 thr.
// ---------------------------------------------------------------------------
__global__ __launch_bounds__(256) void transp_w(const float* __restrict__ W,
                                                ushort_t* __restrict__ Wt) {
  __shared__ float T[32][33];
  const int tid = threadIdx.x;
  const int k0 = blockIdx.x * 32, n0 = blockIdx.y * 32;
  const int r = tid >> 3, c4 = (tid & 7) * 4;
  float4 v = *reinterpret_cast<const float4*>(W + (size_t)(k0 + r) * 512 + n0 + c4);
  T[r][c4 + 0] = v.x; T[r][c4 + 1] = v.y; T[r][c4 + 2] = v.z; T[r][c4 + 3] = v.w;
  __syncthreads();
  uint2 o;
  o.x = packbf(T[c4 + 0][r], T[c4 + 1][r]);
  o.y = packbf(T[c4 + 2][r], T[c4 + 3][r]);
  *reinterpret_cast<uint2*>(Wt + (size_t)(n0 + r) * 512 + k0 + c4) = o;
}

// ---------------------------------------------------------------------------
// Fused QKV GEMM: [Q|K|V] = x[8192,512] @ Wcat[1536,512]^T + b{q,k,v}
// Q region scaled by CQ. Q,K -> bf16 [B,H,S,DK]; V -> bf16 [B,H,DK,S].
// ---------------------------------------------------------------------------
__global__ __launch_bounds__(256) void gemm_qkv(
    const ushort_t* __restrict__ A, const ushort_t* __restrict__ Wcat,
    const float* __restrict__ bq, const float* __restrict__ bk,
    const float* __restrict__ bv, ushort_t* __restrict__ Qo,
    ushort_t* __restrict__ Ko, ushort_t* __restrict__ Vo, float CQ) {
  __shared__ ushort_t AL[2][128 * 32];
  __shared__ ushort_t BL[2][128 * 32];
  const int tid = threadIdx.x;
  const int wid = tid >> 6;
  const int lane = tid & 63;
  const int ql = lane & 15;
  const int g = lane >> 4;
  const int wr = wid >> 1, wc = wid & 1;
  const int m0 = blockIdx.x * 128, n0 = blockIdx.y * 128;
  const int region = n0 >> 9;  // 0=Q 1=K 2=V

  f32x4 acc[4][4];
#pragma unroll
  for (int i = 0; i < 4; ++i)
#pragma unroll
    for (int j = 0; j < 4; ++j) acc[i][j] = (f32x4){0.f, 0.f, 0.f, 0.f};

  auto stage = [&](int k0, int buf) {
#pragma unroll
    for (int i = 0; i < 2; ++i) {
      int idx = i * 256 + tid;
      int r = idx >> 2;
      int c = (idx & 3) * 8;
      gll16(A + (size_t)(m0 + r) * 512 + k0 + c, &AL[buf][idx * 8]);
      gll16(Wcat + (size_t)(n0 + r) * 512 + k0 + c, &BL[buf][idx * 8]);
    }
  };

  stage(0, 0);
  __syncthreads();
  int buf = 0;

  for (int t = 0; t < 16; ++t) {
    if (t < 15) stage((t + 1) * 32, buf ^ 1);
    const ushort_t* ALb = &AL[buf][0];
    const ushort_t* BLb = &BL[buf][0];
    bf16x8 af[4], bfr[4];
#pragma unroll
    for (int mi = 0; mi < 4; ++mi)
      af[mi] = *reinterpret_cast<const bf16x8*>(ALb + (wr * 64 + mi * 16 + ql) * 32 + g * 8);
#pragma unroll
    for (int ni = 0; ni < 4; ++ni)
      bfr[ni] = *reinterpret_cast<const bf16x8*>(BLb + (wc * 64 + ni * 16 + ql) * 32 + g * 8);
#pragma unroll
    for (int mi = 0; mi < 4; ++mi)
#pragma unroll
      for (int ni = 0; ni < 4; ++ni)
        acc[mi][ni] = __builtin_amdgcn_mfma_f32_16x16x32_bf16(af[mi], bfr[ni], acc[mi][ni], 0, 0, 0);
    __syncthreads();
    buf ^= 1;
  }

  const float* bias = region == 0 ? bq : (region == 1 ? bk : bv);
  const float scale = region == 0 ? CQ : 1.0f;
  const int nl0 = n0 - (region << 9);
  ushort_t* outT = region == 0 ? Qo : Ko;

  float bvv[4];
#pragma unroll
  for (int ni = 0; ni < 4; ++ni) bvv[ni] = bias[nl0 + wc * 64 + ni * 16 + ql];

#pragma unroll
  for (int mi = 0; mi < 4; ++mi) {
#pragma unroll
    for (int ni = 0; ni < 4; ++ni) {
      int nl = nl0 + wc * 64 + ni * 16 + ql;
      int h = nl >> 6, d = nl & 63;
#pragma unroll
      for (int reg = 0; reg < 4; ++reg) {
        float val = (acc[mi][ni][reg] + bvv[ni]) * scale;
        int m = m0 + wr * 64 + mi * 16 + 4 * g + reg;
        int b = m >> 12, s = m & 4095;
        if (region <= 1) {
          outT[(((size_t)(b * NHEADS + h) * S_LEN + s) * DK) + d] = bf1(val);
        } else {
          Vo[(((size_t)(b * NHEADS + h) * DK + d) * S_LEN) + s] = bf1(val);
        }
      }
    }
  }
}

// ---------------------------------------------------------------------------
// MFMA GEMM (Wo): out = A[M,512](bf16) @ Wt[512,512]^T + bias, fp32 out.
// ---------------------------------------------------------------------------
__global__ __launch_bounds__(256) void gemm_wo(
    const ushort_t* __restrict__ A, const ushort_t* __restrict__ Wt,
    const float* __restrict__ bias, float* __restrict__ out) {
  __shared__ ushort_t AL[2][128 * 32];
  __shared__ ushort_t BL[2][128 * 32];
  const int tid = threadIdx.x;
  const int wid = tid >> 6;
  const int lane = tid & 63;
  const int ql = lane & 15;
  const int g = lane >> 4;
  const int wr = wid >> 1, wc = wid & 1;
  const int m0 = blockIdx.x * 128, n0 = blockIdx.y * 128;

  f32x4 acc[4][4];
#pragma unroll
  for (int i = 0; i < 4; ++i)
#pragma unroll
    for (int j = 0; j < 4; ++j) acc[i][j] = (f32x4){0.f, 0.f, 0.f, 0.f};

  auto stage = [&](int k0, int buf) {
#pragma unroll
    for (int i = 0; i < 2; ++i) {
      int idx = i * 256 + tid;
      int r = idx >> 2;
      int c = (idx & 3) * 8;
      gll16(A + (size_t)(m0 + r) * 512 + k0 + c, &AL[buf][idx * 8]);
      gll16(Wt + (size_t)(n0 + r) * 512 + k0 + c, &BL[buf][idx * 8]);
    }
  };

  stage(0, 0);
  __syncthreads();
  int buf = 0;

  for (int t = 0; t < 16; ++t) {
    if (t < 15) stage((t + 1) * 32, buf ^ 1);
    const ushort_t* ALb = &AL[buf][0];
    const ushort_t* BLb = &BL[buf][0];
    bf16x8 af[4], bfr[4];
#pragma unroll
    for (int mi = 0; mi < 4; ++mi)
      af[mi] = *reinterpret_cast<const bf16x8*>(ALb + (wr * 64 + mi * 16 + ql) * 32 + g * 8);
#pragma unroll
    for (int ni = 0; ni < 4; ++ni)
      bfr[ni] = *reinterpret_cast<const bf16x8*>(BLb + (wc * 64 + ni * 16 + ql) * 32 + g * 8);
#pragma unroll
    for (int mi = 0; mi < 4; ++mi)
#pragma unroll
      for (int ni = 0; ni < 4; ++ni)
        acc[mi][ni] = __builtin_amdgcn_mfma_f32_16x16x32_bf16(af[mi], bfr[ni], acc[mi][ni], 0, 0, 0);
    __syncthreads();
    buf ^= 1;
  }

  float bv[4];
#pragma unroll
  for (int ni = 0; ni < 4; ++ni) bv[ni] = bias[n0 + wc * 64 + ni * 16 + ql];

#pragma unroll
  for (int mi = 0; mi < 4; ++mi) {
#pragma unroll
    for (int ni = 0; ni < 4; ++ni) {
      int n = n0 + wc * 64 + ni * 16 + ql;
#pragma unroll
      for (int reg = 0; reg < 4; ++reg) {
        int m = m0 + wr * 64 + mi * 16 + 4 * g + reg;
        out[(size_t)m * 512 + n] = acc[mi][ni][reg] + bv[ni];
      }
    }
  }
}

// ---------------------------------------------------------------------------
// MFMA flash attention, no-max softmax, 32 q/wave. All LDS read offsets and
// staging pointers hoisted out of the K-loop; loop unrolled by 2 so the
// double-buffer index is compile-time (zero per-tile address math).
// ---------------------------------------------------------------------------
template <bool SPLIT2>
__global__ __launch_bounds__(256, 4) void attn_mfma(
    const ushort_t* __restrict__ Q, const ushort_t* __restrict__ K,
    const ushort_t* __restrict__ Vt, ushort_t* __restrict__ AO,
    float* __restrict__ Opart, float* __restrict__ Lpart) {
  __shared__ ushort_t KL[2][64 * 64];
  __shared__ ushort_t VL[2][64 * 64];

  const int tid = threadIdx.x;
  const int wid = tid >> 6;
  const int lane = tid & 63;
  const int g = lane >> 4;
  const int ql = lane & 15;

  // XCD-aware remap: 1024 blocks, orig&7 = XCD -> L contiguous per XCD.
  int L;
  if (SPLIT2) {
    int orig = blockIdx.x;
    L = (orig & 7) * 128 + (orig >> 3);
  } else {
    L = blockIdx.x;
  }
  const int qt = L & 31;
  const int bhsp = L >> 5;
  const int sp = SPLIT2 ? (bhsp & 1) : 0;
  const int bh = SPLIT2 ? (bhsp >> 1) : bhsp;
  const int NT = SPLIT2 ? 32 : 64;
  const int t0 = sp * NT;

  const ushort_t* Qb = Q + (size_t)bh * S_LEN * DK;
  const ushort_t* Kb = K + (size_t)bh * S_LEN * DK;
  const ushort_t* Vb = Vt + (size_t)bh * DK * S_LEN;

  const int qbase = qt * 128 + wid * 32;

  // Q B-fragments: qf[c][t]: col q = qbase+16c+ql, k = 32t + 8g + j
  bf16x8 qf[2][2];
#pragma unroll
  for (int c = 0; c < 2; ++c) {
    int q = qbase + c * 16 + ql;
#pragma unroll
    for (int t = 0; t < 2; ++t)
      qf[c][t] = *reinterpret_cast<const bf16x8*>(Qb + (size_t)q * DK + t * 32 + g * 8);
  }

  bf16x8 ones;
#pragma unroll
  for (int j = 0; j < 8; ++j) ones[j] = (short)0x3F80;  // bf16 1.0

  f32x4 ot[4][2];
#pragma unroll
  for (int db = 0; db < 4; ++db)
#pragma unroll
    for (int c = 0; c < 2; ++c) ot[db][c] = (f32x4){0.f, 0.f, 0.f, 0.f};
  f32x4 lacc[2];
  lacc[0] = (f32x4){0.f, 0.f, 0.f, 0.f};
  lacc[1] = (f32x4){0.f, 0.f, 0.f, 0.f};

  // ---- hoisted staging addresses (advance per tile) ----
  const int srow = lane >> 3;
  const int schk = lane & 7;
  const int r0 = wid * 16 + srow;       // rows this lane stages (i=0,1)
  const int r1 = r0 + 8;
  const int ssc = (schk ^ srow) << 4;   // (r&7)==srow for both rows

  const char* gk0 = (const char*)Kb + ((size_t)(t0 * 64 + r0)) * 128 + ssc;
  const char* gk1 = (const char*)Kb + ((size_t)(t0 * 64 + r1)) * 128 + ssc;
  const char* gv0 = (const char*)Vb + (size_t)r0 * (S_LEN * 2) + (size_t)t0 * 128 + ssc;
  const char* gv1 = (const char*)Vb + (size_t)r1 * (S_LEN * 2) + (size_t)t0 * 128 + ssc;

  char* lkA0 = (char*)&KL[0][0] + r0 * 128 + (schk << 4) - (srow << 4) + (lane & 7) * 16;
  // simpler: dest = (wid*16 + i*8)*128 + lane*16  (linear, as before)
  lkA0 = (char*)&KL[0][0] + (wid * 16) * 128 + lane * 16;
  char* lkB0 = lkA0 + 8 * 128;
  char* lkA1 = lkA0 + 8192;
  char* lkB1 = lkB0 + 8192;
  char* lvA0 = (char*)&VL[0][0] + (wid * 16) * 128 + lane * 16;
  char* lvB0 = lvA0 + 8 * 128;
  char* lvA1 = lvA0 + 8192;
  char* lvB1 = lvB0 + 8192;

  // ---- hoisted per-thread LDS read byte-offsets (loop-invariant) ----
  int koA[4], koB[4];
#pragma unroll
  for (int kb = 0; kb < 4; ++kb) {
    int r = kb * 16 + ql;
    koA[kb] = r * 128 + (((g) ^ (r & 7)) << 4);
    koB[kb] = r * 128 + (((g + 4) ^ (r & 7)) << 4);
  }
  const int intra = (g & 1) << 3;
  int voL[2][4], voH[2][4];
#pragma unroll
  for (int t = 0; t < 2; ++t)
#pragma unroll
    for (int db = 0; db < 4; ++db) {
      int rd = db * 16 + ql;
      int c1 = t * 4 + (g >> 1);
      voL[t][db] = rd * 128 + ((c1 ^ (rd & 7)) << 4) + intra;
      voH[t][db] = rd * 128 + (((c1 + 2) ^ (rd & 7)) << 4) + intra;
    }

  // prologue: stage tile t0 into buf0
  gll16(gk0, lkA0); gll16(gk1, lkB0);
  gll16(gv0, lvA0); gll16(gv1, lvB0);
  gk0 += 8192; gk1 += 8192; gv0 += 128; gv1 += 128;
  __syncthreads();

  auto body = [&](const char* KB, const char* VB, char* dkA, char* dkB,
                  char* dvA, char* dvB, bool pref) {
    if (pref) {
      gll16(gk0, dkA); gll16(gk1, dkB);
      gll16(gv0, dvA); gll16(gv1, dvB);
      gk0 += 8192; gk1 += 8192; gv0 += 128; gv1 += 128;
    }

    // ---- S^T = K . Q^T ----
    f32x4 st[4][2];
    __builtin_amdgcn_s_setprio(1);
#pragma unroll
    for (int kb = 0; kb < 4; ++kb) {
      bf16x8 k0 = *reinterpret_cast<const bf16x8*>(KB + koA[kb]);
      bf16x8 k1 = *reinterpret_cast<const bf16x8*>(KB + koB[kb]);
#pragma unroll
      for (int c = 0; c < 2; ++c) {
        f32x4 z = (f32x4){0.f, 0.f, 0.f, 0.f};
        z = __builtin_amdgcn_mfma_f32_16x16x32_bf16(k0, qf[c][0], z, 0, 0, 0);
        z = __builtin_amdgcn_mfma_f32_16x16x32_bf16(k1, qf[c][1], z, 0, 0, 0);
        st[kb][c] = z;
      }
    }
    __builtin_amdgcn_s_setprio(0);

    // ---- p = exp2(s) (Q pre-scaled by 0.125*log2e) ----
    unsigned pk[2][4][2];
#pragma unroll
    for (int c = 0; c < 2; ++c)
#pragma unroll
      for (int kb = 0; kb < 4; ++kb)
#pragma unroll
        for (int r2 = 0; r2 < 2; ++r2) {
          float pa = __builtin_amdgcn_exp2f(st[kb][c][2 * r2]);
          float pb_ = __builtin_amdgcn_exp2f(st[kb][c][2 * r2 + 1]);
          pk[c][kb][r2] = packbf(pa, pb_);
        }

    // ---- PV + l ----
    __builtin_amdgcn_s_setprio(1);
#pragma unroll
    for (int t = 0; t < 2; ++t) {
      union { unsigned u[4]; bf16x8 v; } pb0, pb1;
      pb0.u[0] = pk[0][2 * t][0];     pb0.u[1] = pk[0][2 * t][1];
      pb0.u[2] = pk[0][2 * t + 1][0]; pb0.u[3] = pk[0][2 * t + 1][1];
      pb1.u[0] = pk[1][2 * t][0];     pb1.u[1] = pk[1][2 * t][1];
      pb1.u[2] = pk[1][2 * t + 1][0]; pb1.u[3] = pk[1][2 * t + 1][1];
#pragma unroll
      for (int db = 0; db < 4; ++db) {
        uint2 lo = *reinterpret_cast<const uint2*>(VB + voL[t][db]);
        uint2 hi = *reinterpret_cast<const uint2*>(VB + voH[t][db]);
        union { unsigned u[4]; bf16x8 v; } af;
        af.u[0] = lo.x; af.u[1] = lo.y; af.u[2] = hi.x; af.u[3] = hi.y;
        ot[db][0] = __builtin_amdgcn_mfma_f32_16x16x32_bf16(af.v, pb0.v, ot[db][0], 0, 0, 0);
        ot[db][1] = __builtin_amdgcn_mfma_f32_16x16x32_bf16(af.v, pb1.v, ot[db][1], 0, 0, 0);
      }
      lacc[0] = __builtin_amdgcn_mfma_f32_16x16x32_bf16(ones, pb0.v, lacc[0], 0, 0, 0);
      lacc[1] = __builtin_amdgcn_mfma_f32_16x16x32_bf16(ones, pb1.v, lacc[1], 0, 0, 0);
    }
    __builtin_amdgcn_s_setprio(0);

    __syncthreads();
  };

  const char* KB0 = (const char*)&KL[0][0];
  const char* VB0 = (const char*)&VL[0][0];
  const char* KB1 = (const char*)&KL[1][0];
  const char* VB1 = (const char*)&VL[1][0];

  for (int it = 0; it < NT; it += 2) {
    body(KB0, VB0, lkA1, lkB1, lvA1, lvB1, true);            // tile it (buf0), prefetch it+1
    body(KB1, VB1, lkA0, lkB0, lvA0, lvB0, it + 2 < NT);     // tile it+1 (buf1), prefetch it+2
  }

  if (SPLIT2) {
    float* Ob = Opart + (((size_t)sp * 16 + bh) * S_LEN) * 64;
#pragma unroll
    for (int c = 0; c < 2; ++c) {
      const int q = qbase + c * 16 + ql;
#pragma unroll
      for (int db = 0; db < 4; ++db) {
        float4 o = make_float4(ot[db][c][0], ot[db][c][1], ot[db][c][2], ot[db][c][3]);
        *reinterpret_cast<float4*>(Ob + (size_t)q * 64 + db * 16 + 4 * g) = o;
      }
      if (g == 0) Lpart[((size_t)sp * 16 + bh) * S_LEN + q] = lacc[c][0];
    }
  } else {
    const int b = bh >> 3, h = bh & 7;
#pragma unroll
    for (int c = 0; c < 2; ++c) {
      const int q = qbase + c * 16 + ql;
      float inv = 1.f / lacc[c][0];
#pragma unroll
      for (int db = 0; db < 4; ++db) {
        uint2 o;
        o.x = packbf(ot[db][c][0] * inv, ot[db][c][1] * inv);
        o.y = packbf(ot[db][c][2] * inv, ot[db][c][3] * inv);
        *reinterpret_cast<uint2*>(AO + ((size_t)b * S_LEN + q) * DMODEL + h * DK + db * 16 + g * 4) = o;
      }
    }
  }
}

// ---------------------------------------------------------------------------
// Combine the 2 KV-split partials: AO = (O0+O1)/(l0+l1), bf16.
// ---------------------------------------------------------------------------
__global__ __launch_bounds__(256) void combine_o(
    const float* __restrict__ Opart, const float* __restrict__ Lpart,
    ushort_t* __restrict__ AO) {
  int idx = blockIdx.x * 256 + threadIdx.x;  // 524288 total
  int dblk = idx & 7;
  int q = (idx >> 3) & 4095;
  int bh = idx >> 15;
  size_t o0 = ((size_t)bh * S_LEN + q) * 64 + dblk * 8;
  size_t o1 = o0 + (size_t)16 * S_LEN * 64;
  float4 a0 = *reinterpret_cast<const float4*>(Opart + o0);
  float4 b0 = *reinterpret_cast<const float4*>(Opart + o0 + 4);
  float4 a1 = *reinterpret_cast<const float4*>(Opart + o1);
  float4 b1 = *reinterpret_cast<const float4*>(Opart + o1 + 4);
  float l = Lpart[(size_t)bh * S_LEN + q] + Lpart[(size_t)(16 + bh) * S_LEN + q];
  float inv = 1.0f / l;
  int b = bh >> 3, h = bh & 7;
  uint4 o;
  o.x = packbf((a0.x + a1.x) * inv, (a0.y + a1.y) * inv);
  o.y = packbf((a0.z + a1.z) * inv, (a0.w + a1.w) * inv);
  o.z = packbf((b0.x + b1.x) * inv, (b0.y + b1.y) * inv);
  o.w = packbf((b0.z + b1.z) * inv, (b0.w + b1.w) * inv);
  *reinterpret_cast<uint4*>(AO + ((size_t)b * S_LEN + q) * DMODEL + h * 64 + dblk * 8) = o;
}

extern "C" void kernel_launch(void* const* d_in, const int* in_sizes, int n_in,
                              void* d_out, int out_size, void* d_ws, size_t ws_size,
                              hipStream_t stream) {
  const float* x  = (const float*)d_in[0];
  const float* Wq = (const float*)d_in[1];
  const float* bq = (const float*)d_in[2];
  const float* Wk = (const float*)d_in[3];
  const float* bk = (const float*)d_in[4];
  const float* Wv = (const float*)d_in[5];
  const float* bv = (const float*)d_in[6];
  const float* Wo = (const float*)d_in[7];
  const float* bo = (const float*)d_in[8];
  float* out = (float*)d_out;

  const float CQ = 0.18033688f;  // 0.125 * log2(e)

  char* ws = (char*)d_ws;
  const size_t NBF = (size_t)MROWS * DMODEL;  // 4 Mi elements
  ushort_t* xbf = (ushort_t*)ws;              // 8MB (reused as AOb in split)
  ushort_t* Qbf = (ushort_t*)(ws + NBF * 2);
  ushort_t* Kbf = (ushort_t*)(ws + NBF * 4);
  ushort_t* Vtb = (ushort_t*)(ws + NBF * 6);

  const size_t OFF_WT    = NBF * 8;                        // Wcat 1.5MB + Wot 0.5MB
  const size_t OFF_LPART = OFF_WT + 4 * 512 * 512 * 2;     // 512KB Lpart
  const size_t OFF_OPART = OFF_LPART + 512 * 1024;         // 32MB Opart
  const size_t NEED_SPLIT = OFF_OPART + (size_t)2 * 16 * S_LEN * 64 * 4;
  const bool use_split = ws_size >= NEED_SPLIT;

  ushort_t* Wcat;
  ushort_t* AOb;
  if (use_split) {
    Wcat = (ushort_t*)(ws + OFF_WT);
    AOb = xbf;
  } else {
    AOb = (ushort_t*)(ws + NBF * 8);
    Wcat = (ushort_t*)(ws + NBF * 10);
  }
  ushort_t* Wot = Wcat + 3 * 512 * 512;
  float* Lpart = (float*)(ws + OFF_LPART);
  float* Opart = (float*)(ws + OFF_OPART);

  cvt_bf16<<<MROWS * DMODEL / 2048, 256, 0, stream>>>(x, xbf);
  dim3 gt(16, 16);
  transp_w<<<gt, 256, 0, stream>>>(Wq, Wcat);
  transp_w<<<gt, 256, 0, stream>>>(Wk, Wcat + 512 * 512);
  transp_w<<<gt, 256, 0, stream>>>(Wv, Wcat + 2 * 512 * 512);
  transp_w<<<gt, 256, 0, stream>>>(Wo, Wot);

  dim3 gq(MROWS / 128, 1536 / 128);  // (64, 12)
  gemm_qkv<<<gq, 256, 0, stream>>>(xbf, Wcat, bq, bk, bv, Qbf, Kbf, Vtb, CQ);

  if (use_split) {
    attn_mfma<true><<<1024, 256, 0, stream>>>(Qbf, Kbf, Vtb, AOb, Opart, Lpart);
    combine_o<<<2048, 256, 0, stream>>>(Opart, Lpart, AOb);
  } else {
    attn_mfma<false><<<512, 256, 0, stream>>>(Qbf, Kbf, Vtb, AOb, Opart, Lpart);
  }

  dim3 gg(MROWS / 128, DMODEL / 128);  // (64, 4)
  gemm_wo<<<gg, 256, 0, stream>>>(AOb, Wot, bo, out);
}

// Round 9
// 127.916 us; speedup vs baseline: 12.4445x; 1.0936x over previous
//
#include <hip/hip_runtime.h>
#include <hip/hip_bf16.h>

#define S_LEN 4096
#define DMODEL 512
#define NHEADS 8
#define DK 64
#define BATCH 2
#define MROWS (BATCH * S_LEN)  // 8192

typedef __attribute__((ext_vector_type(8))) short bf16x8;
typedef __attribute__((ext_vector_type(4))) float f32x4;
typedef unsigned short ushort_t;

// single-instruction pack: low16 = bf16(a), high16 = bf16(b), RNE (same as
// __float2bfloat16 rounding)
__device__ __forceinline__ unsigned packbf(float a, float b) {
  unsigned r;
  asm("v_cvt_pk_bf16_f32 %0, %1, %2" : "=v"(r) : "v"(a), "v"(b));
  return r;
}

__device__ __forceinline__ unsigned short bf1(float a) {
  union { __hip_bfloat16 h; unsigned short s; } u;
  u.h = __float2bfloat16(a);
  return u.s;
}

__device__ __forceinline__ void gll16(const void* g, void* l) {
  __builtin_amdgcn_global_load_lds(
      (const __attribute__((address_space(1))) unsigned*)g,
      (__attribute__((address_space(3))) unsigned*)l, 16, 0, 0);
}

// ---------------------------------------------------------------------------
// x fp32 -> bf16, 8 elems/thread
// ---------------------------------------------------------------------------
__global__ __launch_bounds__(256) void cvt_bf16(const float* __restrict__ in,
                                                ushort_t* __restrict__ out) {
  size_t i = ((size_t)blockIdx.x * 256 + threadIdx.x) * 8;
  float4 a = *reinterpret_cast<const float4*>(in + i);
  float4 b = *reinterpret_cast<const float4*>(in + i + 4);
  uint4 o;
  o.x = packbf(a.x, a.y);
  o.y = packbf(a.z, a.w);
  o.z = packbf(b.x, b.y);
  o.w = packbf(b.z, b.w);
  *reinterpret_cast<uint4*>(out + i) = o;
}

// ---------------------------------------------------------------------------
// W[512,512] fp32 (k,n) -> Wt[512,512] bf16 (n,k). 32x32 tiles, 256 thr.
// ---------------------------------------------------------------------------
__global__ __launch_bounds__(256) void transp_w(const float* __restrict__ W,
                                                ushort_t* __restrict__ Wt) {
  __shared__ float T[32][33];
  const int tid = threadIdx.x;
  const int k0 = blockIdx.x * 32, n0 = blockIdx.y * 32;
  const int r = tid >> 3, c4 = (tid & 7) * 4;
  float4 v = *reinterpret_cast<const float4*>(W + (size_t)(k0 + r) * 512 + n0 + c4);
  T[r][c4 + 0] = v.x; T[r][c4 + 1] = v.y; T[r][c4 + 2] = v.z; T[r][c4 + 3] = v.w;
  __syncthreads();
  uint2 o;
  o.x = packbf(T[c4 + 0][r], T[c4 + 1][r]);
  o.y = packbf(T[c4 + 2][r], T[c4 + 3][r]);
  *reinterpret_cast<uint2*>(Wt + (size_t)(n0 + r) * 512 + k0 + c4) = o;
}

// ---------------------------------------------------------------------------
// Fused QKV GEMM: [Q|K|V] = x[8192,512] @ Wcat[1536,512]^T + b{q,k,v}
// Q region scaled by CQ. Q,K -> bf16 [B,H,S,DK].
// V -> bf16 [B,H,DK,S] with WITHIN-64-KEY-TILE PERMUTED s order so the attn
// PV A-fragment (slot 8g+j <-> key 32t+16(j>>2)+4g+(j&3)) is contiguous 16B:
//   pos(k6) = (k6&32) | ((k6>>2&3)<<3) | ((k6>>4&1)<<2) | (k6&3)
// ---------------------------------------------------------------------------
__global__ __launch_bounds__(256) void gemm_qkv(
    const ushort_t* __restrict__ A, const ushort_t* __restrict__ Wcat,
    const float* __restrict__ bq, const float* __restrict__ bk,
    const float* __restrict__ bv, ushort_t* __restrict__ Qo,
    ushort_t* __restrict__ Ko, ushort_t* __restrict__ Vo, float CQ) {
  __shared__ ushort_t AL[2][128 * 32];
  __shared__ ushort_t BL[2][128 * 32];
  const int tid = threadIdx.x;
  const int wid = tid >> 6;
  const int lane = tid & 63;
  const int ql = lane & 15;
  const int g = lane >> 4;
  const int wr = wid >> 1, wc = wid & 1;
  const int m0 = blockIdx.x * 128, n0 = blockIdx.y * 128;
  const int region = n0 >> 9;  // 0=Q 1=K 2=V

  f32x4 acc[4][4];
#pragma unroll
  for (int i = 0; i < 4; ++i)
#pragma unroll
    for (int j = 0; j < 4; ++j) acc[i][j] = (f32x4){0.f, 0.f, 0.f, 0.f};

  auto stage = [&](int k0, int buf) {
#pragma unroll
    for (int i = 0; i < 2; ++i) {
      int idx = i * 256 + tid;
      int r = idx >> 2;
      int c = (idx & 3) * 8;
      gll16(A + (size_t)(m0 + r) * 512 + k0 + c, &AL[buf][idx * 8]);
      gll16(Wcat + (size_t)(n0 + r) * 512 + k0 + c, &BL[buf][idx * 8]);
    }
  };

  stage(0, 0);
  __syncthreads();
  int buf = 0;

  for (int t = 0; t < 16; ++t) {
    if (t < 15) stage((t + 1) * 32, buf ^ 1);
    const ushort_t* ALb = &AL[buf][0];
    const ushort_t* BLb = &BL[buf][0];
    bf16x8 af[4], bfr[4];
#pragma unroll
    for (int mi = 0; mi < 4; ++mi)
      af[mi] = *reinterpret_cast<const bf16x8*>(ALb + (wr * 64 + mi * 16 + ql) * 32 + g * 8);
#pragma unroll
    for (int ni = 0; ni < 4; ++ni)
      bfr[ni] = *reinterpret_cast<const bf16x8*>(BLb + (wc * 64 + ni * 16 + ql) * 32 + g * 8);
#pragma unroll
    for (int mi = 0; mi < 4; ++mi)
#pragma unroll
      for (int ni = 0; ni < 4; ++ni)
        acc[mi][ni] = __builtin_amdgcn_mfma_f32_16x16x32_bf16(af[mi], bfr[ni], acc[mi][ni], 0, 0, 0);
    __syncthreads();
    buf ^= 1;
  }

  const float* bias = region == 0 ? bq : (region == 1 ? bk : bv);
  const float scale = region == 0 ? CQ : 1.0f;
  const int nl0 = n0 - (region << 9);
  ushort_t* outT = region == 0 ? Qo : Ko;

  float bvv[4];
#pragma unroll
  for (int ni = 0; ni < 4; ++ni) bvv[ni] = bias[nl0 + wc * 64 + ni * 16 + ql];

#pragma unroll
  for (int mi = 0; mi < 4; ++mi) {
#pragma unroll
    for (int ni = 0; ni < 4; ++ni) {
      int nl = nl0 + wc * 64 + ni * 16 + ql;
      int h = nl >> 6, d = nl & 63;
#pragma unroll
      for (int reg = 0; reg < 4; ++reg) {
        float val = (acc[mi][ni][reg] + bvv[ni]) * scale;
        int m = m0 + wr * 64 + mi * 16 + 4 * g + reg;
        int b = m >> 12, s = m & 4095;
        if (region <= 1) {
          outT[(((size_t)(b * NHEADS + h) * S_LEN + s) * DK) + d] = bf1(val);
        } else {
          int k6 = s & 63;
          int pos = (k6 & 32) | (((k6 >> 2) & 3) << 3) | (((k6 >> 4) & 1) << 2) | (k6 & 3);
          int sperm = (s & ~63) | pos;
          Vo[(((size_t)(b * NHEADS + h) * DK + d) * S_LEN) + sperm] = bf1(val);
        }
      }
    }
  }
}

// ---------------------------------------------------------------------------
// MFMA GEMM (Wo): out = A[M,512](bf16) @ Wt[512,512]^T + bias, fp32 out.
// ---------------------------------------------------------------------------
__global__ __launch_bounds__(256) void gemm_wo(
    const ushort_t* __restrict__ A, const ushort_t* __restrict__ Wt,
    const float* __restrict__ bias, float* __restrict__ out) {
  __shared__ ushort_t AL[2][128 * 32];
  __shared__ ushort_t BL[2][128 * 32];
  const int tid = threadIdx.x;
  const int wid = tid >> 6;
  const int lane = tid & 63;
  const int ql = lane & 15;
  const int g = lane >> 4;
  const int wr = wid >> 1, wc = wid & 1;
  const int m0 = blockIdx.x * 128, n0 = blockIdx.y * 128;

  f32x4 acc[4][4];
#pragma unroll
  for (int i = 0; i < 4; ++i)
#pragma unroll
    for (int j = 0; j < 4; ++j) acc[i][j] = (f32x4){0.f, 0.f, 0.f, 0.f};

  auto stage = [&](int k0, int buf) {
#pragma unroll
    for (int i = 0; i < 2; ++i) {
      int idx = i * 256 + tid;
      int r = idx >> 2;
      int c = (idx & 3) * 8;
      gll16(A + (size_t)(m0 + r) * 512 + k0 + c, &AL[buf][idx * 8]);
      gll16(Wt + (size_t)(n0 + r) * 512 + k0 + c, &BL[buf][idx * 8]);
    }
  };

  stage(0, 0);
  __syncthreads();
  int buf = 0;

  for (int t = 0; t < 16; ++t) {
    if (t < 15) stage((t + 1) * 32, buf ^ 1);
    const ushort_t* ALb = &AL[buf][0];
    const ushort_t* BLb = &BL[buf][0];
    bf16x8 af[4], bfr[4];
#pragma unroll
    for (int mi = 0; mi < 4; ++mi)
      af[mi] = *reinterpret_cast<const bf16x8*>(ALb + (wr * 64 + mi * 16 + ql) * 32 + g * 8);
#pragma unroll
    for (int ni = 0; ni < 4; ++ni)
      bfr[ni] = *reinterpret_cast<const bf16x8*>(BLb + (wc * 64 + ni * 16 + ql) * 32 + g * 8);
#pragma unroll
    for (int mi = 0; mi < 4; ++mi)
#pragma unroll
      for (int ni = 0; ni < 4; ++ni)
        acc[mi][ni] = __builtin_amdgcn_mfma_f32_16x16x32_bf16(af[mi], bfr[ni], acc[mi][ni], 0, 0, 0);
    __syncthreads();
    buf ^= 1;
  }

  float bv[4];
#pragma unroll
  for (int ni = 0; ni < 4; ++ni) bv[ni] = bias[n0 + wc * 64 + ni * 16 + ql];

#pragma unroll
  for (int mi = 0; mi < 4; ++mi) {
#pragma unroll
    for (int ni = 0; ni < 4; ++ni) {
      int n = n0 + wc * 64 + ni * 16 + ql;
#pragma unroll
      for (int reg = 0; reg < 4; ++reg) {
        int m = m0 + wr * 64 + mi * 16 + 4 * g + reg;
        out[(size_t)m * 512 + n] = acc[mi][ni][reg] + bv[ni];
      }
    }
  }
}

// ---------------------------------------------------------------------------
// MFMA flash attention, no-max softmax, 32 q/wave. V pre-permuted so PV
// A-fragments are single ds_read_b128. cvt_pk packing. Unrolled-by-2 dbuf.
// ---------------------------------------------------------------------------
template <bool SPLIT2>
__global__ __launch_bounds__(256, 4) void attn_mfma(
    const ushort_t* __restrict__ Q, const ushort_t* __restrict__ K,
    const ushort_t* __restrict__ Vt, ushort_t* __restrict__ AO,
    float* __restrict__ Opart, float* __restrict__ Lpart) {
  __shared__ ushort_t KL[2][64 * 64];
  __shared__ ushort_t VL[2][64 * 64];

  const int tid = threadIdx.x;
  const int wid = tid >> 6;
  const int lane = tid & 63;
  const int g = lane >> 4;
  const int ql = lane & 15;

  // XCD-aware remap: 1024 blocks, orig&7 = XCD -> L contiguous per XCD.
  int L;
  if (SPLIT2) {
    int orig = blockIdx.x;
    L = (orig & 7) * 128 + (orig >> 3);
  } else {
    L = blockIdx.x;
  }
  const int qt = L & 31;
  const int bhsp = L >> 5;
  const int sp = SPLIT2 ? (bhsp & 1) : 0;
  const int bh = SPLIT2 ? (bhsp >> 1) : bhsp;
  const int NT = SPLIT2 ? 32 : 64;
  const int t0 = sp * NT;

  const ushort_t* Qb = Q + (size_t)bh * S_LEN * DK;
  const ushort_t* Kb = K + (size_t)bh * S_LEN * DK;
  const ushort_t* Vb = Vt + (size_t)bh * DK * S_LEN;

  const int qbase = qt * 128 + wid * 32;

  bf16x8 qf[2][2];
#pragma unroll
  for (int c = 0; c < 2; ++c) {
    int q = qbase + c * 16 + ql;
#pragma unroll
    for (int t = 0; t < 2; ++t)
      qf[c][t] = *reinterpret_cast<const bf16x8*>(Qb + (size_t)q * DK + t * 32 + g * 8);
  }

  bf16x8 ones;
#pragma unroll
  for (int j = 0; j < 8; ++j) ones[j] = (short)0x3F80;  // bf16 1.0

  f32x4 ot[4][2];
#pragma unroll
  for (int db = 0; db < 4; ++db)
#pragma unroll
    for (int c = 0; c < 2; ++c) ot[db][c] = (f32x4){0.f, 0.f, 0.f, 0.f};
  f32x4 lacc[2];
  lacc[0] = (f32x4){0.f, 0.f, 0.f, 0.f};
  lacc[1] = (f32x4){0.f, 0.f, 0.f, 0.f};

  // ---- hoisted staging addresses ----
  const int srow = lane >> 3;
  const int schk = lane & 7;
  const int r0 = wid * 16 + srow;
  const int r1 = r0 + 8;
  const int ssc = (schk ^ srow) << 4;  // (r&7)==srow for both staged rows

  const char* gk0 = (const char*)Kb + ((size_t)(t0 * 64 + r0)) * 128 + ssc;
  const char* gk1 = (const char*)Kb + ((size_t)(t0 * 64 + r1)) * 128 + ssc;
  const char* gv0 = (const char*)Vb + (size_t)r0 * (S_LEN * 2) + (size_t)t0 * 128 + ssc;
  const char* gv1 = (const char*)Vb + (size_t)r1 * (S_LEN * 2) + (size_t)t0 * 128 + ssc;

  char* lkA0 = (char*)&KL[0][0] + (wid * 16) * 128 + lane * 16;
  char* lkB0 = lkA0 + 8 * 128;
  char* lkA1 = lkA0 + 8192;
  char* lkB1 = lkB0 + 8192;
  char* lvA0 = (char*)&VL[0][0] + (wid * 16) * 128 + lane * 16;
  char* lvB0 = lvA0 + 8 * 128;
  char* lvA1 = lvA0 + 8192;
  char* lvB1 = lvB0 + 8192;

  // ---- hoisted LDS read byte-offsets ----
  int koA[4], koB[4];
#pragma unroll
  for (int kb = 0; kb < 4; ++kb) {
    int r = kb * 16 + ql;
    koA[kb] = r * 128 + (((g) ^ (r & 7)) << 4);
    koB[kb] = r * 128 + (((g + 4) ^ (r & 7)) << 4);
  }
  int voP[2][4];
#pragma unroll
  for (int t = 0; t < 2; ++t)
#pragma unroll
    for (int db = 0; db < 4; ++db) {
      int rd = db * 16 + ql;
      voP[t][db] = rd * 128 + (((t * 4 + g) ^ (rd & 7)) << 4);
    }

  // prologue: stage tile t0 into buf0
  gll16(gk0, lkA0); gll16(gk1, lkB0);
  gll16(gv0, lvA0); gll16(gv1, lvB0);
  gk0 += 8192; gk1 += 8192; gv0 += 128; gv1 += 128;
  __syncthreads();

  auto body = [&](const char* KB, const char* VB, char* dkA, char* dkB,
                  char* dvA, char* dvB, bool pref) {
    if (pref) {
      gll16(gk0, dkA); gll16(gk1, dkB);
      gll16(gv0, dvA); gll16(gv1, dvB);
      gk0 += 8192; gk1 += 8192; gv0 += 128; gv1 += 128;
    }

    // ---- S^T = K . Q^T ----
    f32x4 st[4][2];
    __builtin_amdgcn_s_setprio(1);
#pragma unroll
    for (int kb = 0; kb < 4; ++kb) {
      bf16x8 k0 = *reinterpret_cast<const bf16x8*>(KB + koA[kb]);
      bf16x8 k1 = *reinterpret_cast<const bf16x8*>(KB + koB[kb]);
#pragma unroll
      for (int c = 0; c < 2; ++c) {
        f32x4 z = (f32x4){0.f, 0.f, 0.f, 0.f};
        z = __builtin_amdgcn_mfma_f32_16x16x32_bf16(k0, qf[c][0], z, 0, 0, 0);
        z = __builtin_amdgcn_mfma_f32_16x16x32_bf16(k1, qf[c][1], z, 0, 0, 0);
        st[kb][c] = z;
      }
    }
    __builtin_amdgcn_s_setprio(0);

    // ---- p = exp2(s); pack via v_cvt_pk_bf16_f32 ----
    unsigned pk[2][4][2];
#pragma unroll
    for (int c = 0; c < 2; ++c)
#pragma unroll
      for (int kb = 0; kb < 4; ++kb)
#pragma unroll
        for (int r2 = 0; r2 < 2; ++r2) {
          float pa = __builtin_amdgcn_exp2f(st[kb][c][2 * r2]);
          float pb_ = __builtin_amdgcn_exp2f(st[kb][c][2 * r2 + 1]);
          pk[c][kb][r2] = packbf(pa, pb_);
        }

    // ---- PV + l: A-fragment = single b128 (pre-permuted V) ----
    __builtin_amdgcn_s_setprio(1);
#pragma unroll
    for (int t = 0; t < 2; ++t) {
      union { unsigned u[4]; bf16x8 v; } pb0, pb1;
      pb0.u[0] = pk[0][2 * t][0];     pb0.u[1] = pk[0][2 * t][1];
      pb0.u[2] = pk[0][2 * t + 1][0]; pb0.u[3] = pk[0][2 * t + 1][1];
      pb1.u[0] = pk[1][2 * t][0];     pb1.u[1] = pk[1][2 * t][1];
      pb1.u[2] = pk[1][2 * t + 1][0]; pb1.u[3] = pk[1][2 * t + 1][1];
#pragma unroll
      for (int db = 0; db < 4; ++db) {
        bf16x8 af = *reinterpret_cast<const bf16x8*>(VB + voP[t][db]);
        ot[db][0] = __builtin_amdgcn_mfma_f32_16x16x32_bf16(af, pb0.v, ot[db][0], 0, 0, 0);
        ot[db][1] = __builtin_amdgcn_mfma_f32_16x16x32_bf16(af, pb1.v, ot[db][1], 0, 0, 0);
      }
      lacc[0] = __builtin_amdgcn_mfma_f32_16x16x32_bf16(ones, pb0.v, lacc[0], 0, 0, 0);
      lacc[1] = __builtin_amdgcn_mfma_f32_16x16x32_bf16(ones, pb1.v, lacc[1], 0, 0, 0);
    }
    __builtin_amdgcn_s_setprio(0);

    __syncthreads();
  };

  const char* KB0 = (const char*)&KL[0][0];
  const char* VB0 = (const char*)&VL[0][0];
  const char* KB1 = (const char*)&KL[1][0];
  const char* VB1 = (const char*)&VL[1][0];

  for (int it = 0; it < NT; it += 2) {
    body(KB0, VB0, lkA1, lkB1, lvA1, lvB1, true);
    body(KB1, VB1, lkA0, lkB0, lvA0, lvB0, it + 2 < NT);
  }

  if (SPLIT2) {
    float* Ob = Opart + (((size_t)sp * 16 + bh) * S_LEN) * 64;
#pragma unroll
    for (int c = 0; c < 2; ++c) {
      const int q = qbase + c * 16 + ql;
#pragma unroll
      for (int db = 0; db < 4; ++db) {
        float4 o = make_float4(ot[db][c][0], ot[db][c][1], ot[db][c][2], ot[db][c][3]);
        *reinterpret_cast<float4*>(Ob + (size_t)q * 64 + db * 16 + 4 * g) = o;
      }
      if (g == 0) Lpart[((size_t)sp * 16 + bh) * S_LEN + q] = lacc[c][0];
    }
  } else {
    const int b = bh >> 3, h = bh & 7;
#pragma unroll
    for (int c = 0; c < 2; ++c) {
      const int q = qbase + c * 16 + ql;
      float inv = 1.f / lacc[c][0];
#pragma unroll
      for (int db = 0; db < 4; ++db) {
        uint2 o;
        o.x = packbf(ot[db][c][0] * inv, ot[db][c][1] * inv);
        o.y = packbf(ot[db][c][2] * inv, ot[db][c][3] * inv);
        *reinterpret_cast<uint2*>(AO + ((size_t)b * S_LEN + q) * DMODEL + h * DK + db * 16 + g * 4) = o;
      }
    }
  }
}

// ---------------------------------------------------------------------------
// Combine the 2 KV-split partials: AO = (O0+O1)/(l0+l1), bf16.
// ---------------------------------------------------------------------------
__global__ __launch_bounds__(256) void combine_o(
    const float* __restrict__ Opart, const float* __restrict__ Lpart,
    ushort_t* __restrict__ AO) {
  int idx = blockIdx.x * 256 + threadIdx.x;  // 524288 total
  int dblk = idx & 7;
  int q = (idx >> 3) & 4095;
  int bh = idx >> 15;
  size_t o0 = ((size_t)bh * S_LEN + q) * 64 + dblk * 8;
  size_t o1 = o0 + (size_t)16 * S_LEN * 64;
  float4 a0 = *reinterpret_cast<const float4*>(Opart + o0);
  float4 b0 = *reinterpret_cast<const float4*>(Opart + o0 + 4);
  float4 a1 = *reinterpret_cast<const float4*>(Opart + o1);
  float4 b1 = *reinterpret_cast<const float4*>(Opart + o1 + 4);
  float l = Lpart[(size_t)bh * S_LEN + q] + Lpart[(size_t)(16 + bh) * S_LEN + q];
  float inv = 1.0f / l;
  int b = bh >> 3, h = bh & 7;
  uint4 o;
  o.x = packbf((a0.x + a1.x) * inv, (a0.y + a1.y) * inv);
  o.y = packbf((a0.z + a1.z) * inv, (a0.w + a1.w) * inv);
  o.z = packbf((b0.x + b1.x) * inv, (b0.y + b1.y) * inv);
  o.w = packbf((b0.z + b1.z) * inv, (b0.w + b1.w) * inv);
  *reinterpret_cast<uint4*>(AO + ((size_t)b * S_LEN + q) * DMODEL + h * 64 + dblk * 8) = o;
}

extern "C" void kernel_launch(void* const* d_in, const int* in_sizes, int n_in,
                              void* d_out, int out_size, void* d_ws, size_t ws_size,
                              hipStream_t stream) {
  const float* x  = (const float*)d_in[0];
  const float* Wq = (const float*)d_in[1];
  const float* bq = (const float*)d_in[2];
  const float* Wk = (const float*)d_in[3];
  const float* bk = (const float*)d_in[4];
  const float* Wv = (const float*)d_in[5];
  const float* bv = (const float*)d_in[6];
  const float* Wo = (const float*)d_in[7];
  const float* bo = (const float*)d_in[8];
  float* out = (float*)d_out;

  const float CQ = 0.18033688f;  // 0.125 * log2(e)

  char* ws = (char*)d_ws;
  const size_t NBF = (size_t)MROWS * DMODEL;  // 4 Mi elements
  ushort_t* xbf = (ushort_t*)ws;              // 8MB (reused as AOb in split)
  ushort_t* Qbf = (ushort_t*)(ws + NBF * 2);
  ushort_t* Kbf = (ushort_t*)(ws + NBF * 4);
  ushort_t* Vtb = (ushort_t*)(ws + NBF * 6);

  const size_t OFF_WT    = NBF * 8;
  const size_t OFF_LPART = OFF_WT + 4 * 512 * 512 * 2;
  const size_t OFF_OPART = OFF_LPART + 512 * 1024;
  const size_t NEED_SPLIT = OFF_OPART + (size_t)2 * 16 * S_LEN * 64 * 4;
  const bool use_split = ws_size >= NEED_SPLIT;

  ushort_t* Wcat;
  ushort_t* AOb;
  if (use_split) {
    Wcat = (ushort_t*)(ws + OFF_WT);
    AOb = xbf;
  } else {
    AOb = (ushort_t*)(ws + NBF * 8);
    Wcat = (ushort_t*)(ws + NBF * 10);
  }
  ushort_t* Wot = Wcat + 3 * 512 * 512;
  float* Lpart = (float*)(ws + OFF_LPART);
  float* Opart = (float*)(ws + OFF_OPART);

  cvt_bf16<<<MROWS * DMODEL / 2048, 256, 0, stream>>>(x, xbf);
  dim3 gt(16, 16);
  transp_w<<<gt, 256, 0, stream>>>(Wq, Wcat);
  transp_w<<<gt, 256, 0, stream>>>(Wk, Wcat + 512 * 512);
  transp_w<<<gt, 256, 0, stream>>>(Wv, Wcat + 2 * 512 * 512);
  transp_w<<<gt, 256, 0, stream>>>(Wo, Wot);

  dim3 gq(MROWS / 128, 1536 / 128);  // (64, 12)
  gemm_qkv<<<gq, 256, 0, stream>>>(xbf, Wcat, bq, bk, bv, Qbf, Kbf, Vtb, CQ);

  if (use_split) {
    attn_mfma<true><<<1024, 256, 0, stream>>>(Qbf, Kbf, Vtb, AOb, Opart, Lpart);
    combine_o<<<2048, 256, 0, stream>>>(Opart, Lpart, AOb);
  } else {
    attn_mfma<false><<<512, 256, 0, stream>>>(Qbf, Kbf, Vtb, AOb, Opart, Lpart);
  }

  dim3 gg(MROWS / 128, DMODEL / 128);  // (64, 4)
  gemm_wo<<<gg, 256, 0, stream>>>(AOb, Wot, bo, out);
}

// Round 10
// 122.373 us; speedup vs baseline: 13.0082x; 1.0453x over previous
//
#include <hip/hip_runtime.h>
#include <hip/hip_bf16.h>

#define S_LEN 4096
#define DMODEL 512
#define NHEADS 8
#define DK 64
#define BATCH 2
#define MROWS (BATCH * S_LEN)  // 8192

typedef __attribute__((ext_vector_type(8))) short bf16x8;
typedef __attribute__((ext_vector_type(4))) float f32x4;
typedef unsigned short ushort_t;

// single-instruction pack: low16 = bf16(a), high16 = bf16(b), RNE
__device__ __forceinline__ unsigned packbf(float a, float b) {
  unsigned r;
  asm("v_cvt_pk_bf16_f32 %0, %1, %2" : "=v"(r) : "v"(a), "v"(b));
  return r;
}

__device__ __forceinline__ unsigned short bf1(float a) {
  union { __hip_bfloat16 h; unsigned short s; } u;
  u.h = __float2bfloat16(a);
  return u.s;
}

__device__ __forceinline__ float bflo(unsigned u) { return __uint_as_float(u << 16); }
__device__ __forceinline__ float bfhi(unsigned u) { return __uint_as_float(u & 0xFFFF0000u); }

__device__ __forceinline__ float fastrcp(float x) {
  float r;
  asm("v_rcp_f32 %0, %1" : "=v"(r) : "v"(x));
  return r;
}

__device__ __forceinline__ void gll16(const void* g, void* l) {
  __builtin_amdgcn_global_load_lds(
      (const __attribute__((address_space(1))) unsigned*)g,
      (__attribute__((address_space(3))) unsigned*)l, 16, 0, 0);
}

// ---------------------------------------------------------------------------
// Fused prep: blocks [0,2048) convert x fp32->bf16 (8 elems/thread);
// blocks [2048,3072) transpose the 4 weights to bf16 (n,k).
// ---------------------------------------------------------------------------
__global__ __launch_bounds__(256) void prep(
    const float* __restrict__ x, const float* __restrict__ Wq,
    const float* __restrict__ Wk, const float* __restrict__ Wv,
    const float* __restrict__ Wo, ushort_t* __restrict__ xbf,
    ushort_t* __restrict__ Wcat, ushort_t* __restrict__ Wot) {
  __shared__ float T[32][33];
  const int bid = blockIdx.x;
  const int tid = threadIdx.x;
  if (bid < 2048) {
    size_t i = ((size_t)bid * 256 + tid) * 8;
    float4 a = *reinterpret_cast<const float4*>(x + i);
    float4 b = *reinterpret_cast<const float4*>(x + i + 4);
    uint4 o;
    o.x = packbf(a.x, a.y);
    o.y = packbf(a.z, a.w);
    o.z = packbf(b.x, b.y);
    o.w = packbf(b.z, b.w);
    *reinterpret_cast<uint4*>(xbf + i) = o;
  } else {
    int t = bid - 2048;
    int w = t >> 8;
    int tile = t & 255;
    int k0 = (tile & 15) * 32, n0 = (tile >> 4) * 32;
    const float* W = w == 0 ? Wq : (w == 1 ? Wk : (w == 2 ? Wv : Wo));
    ushort_t* out = (w == 3) ? Wot : (Wcat + (size_t)w * 512 * 512);
    const int r = tid >> 3, c4 = (tid & 7) * 4;
    float4 v = *reinterpret_cast<const float4*>(W + (size_t)(k0 + r) * 512 + n0 + c4);
    T[r][c4 + 0] = v.x; T[r][c4 + 1] = v.y; T[r][c4 + 2] = v.z; T[r][c4 + 3] = v.w;
    __syncthreads();
    uint2 o;
    o.x = packbf(T[c4 + 0][r], T[c4 + 1][r]);
    o.y = packbf(T[c4 + 2][r], T[c4 + 3][r]);
    *reinterpret_cast<uint2*>(out + (size_t)(n0 + r) * 512 + k0 + c4) = o;
  }
}

// ---------------------------------------------------------------------------
// Fused QKV GEMM: [Q|K|V] = x[8192,512] @ Wcat[1536,512]^T + b{q,k,v}
// Flat grid 768 with XCD grouping (same-m panels share an XCD L2).
// Q region scaled by CQ. Q,K -> bf16 [B,H,S,DK]; V -> [B,H,DK,S] with
// within-64-key-tile permuted s order (PV A-fragment contiguous).
// ---------------------------------------------------------------------------
__global__ __launch_bounds__(256) void gemm_qkv(
    const ushort_t* __restrict__ A, const ushort_t* __restrict__ Wcat,
    const float* __restrict__ bq, const float* __restrict__ bk,
    const float* __restrict__ bv, ushort_t* __restrict__ Qo,
    ushort_t* __restrict__ Ko, ushort_t* __restrict__ Vo, float CQ) {
  __shared__ ushort_t AL[2][128 * 32];
  __shared__ ushort_t BL[2][128 * 32];
  const int tid = threadIdx.x;
  const int wid = tid >> 6;
  const int lane = tid & 63;
  const int ql = lane & 15;
  const int g = lane >> 4;
  const int wr = wid >> 1, wc = wid & 1;

  // XCD grouping: 768 = 8 XCD x 96; within XCD: 8 m-panels x 12 n-blocks.
  const int p = blockIdx.x;
  const int xcd = p & 7, q_ = p >> 3;
  const int mi = xcd * 8 + q_ / 12;
  const int ni = q_ % 12;
  const int m0 = mi * 128, n0 = ni * 128;
  const int region = n0 >> 9;  // 0=Q 1=K 2=V

  f32x4 acc[4][4];
#pragma unroll
  for (int i = 0; i < 4; ++i)
#pragma unroll
    for (int j = 0; j < 4; ++j) acc[i][j] = (f32x4){0.f, 0.f, 0.f, 0.f};

  auto stage = [&](int k0, int buf) {
#pragma unroll
    for (int i = 0; i < 2; ++i) {
      int idx = i * 256 + tid;
      int r = idx >> 2;
      int c = (idx & 3) * 8;
      gll16(A + (size_t)(m0 + r) * 512 + k0 + c, &AL[buf][idx * 8]);
      gll16(Wcat + (size_t)(n0 + r) * 512 + k0 + c, &BL[buf][idx * 8]);
    }
  };

  stage(0, 0);
  __syncthreads();
  int buf = 0;

  for (int t = 0; t < 16; ++t) {
    if (t < 15) stage((t + 1) * 32, buf ^ 1);
    const ushort_t* ALb = &AL[buf][0];
    const ushort_t* BLb = &BL[buf][0];
    bf16x8 af[4], bfr[4];
#pragma unroll
    for (int mi2 = 0; mi2 < 4; ++mi2)
      af[mi2] = *reinterpret_cast<const bf16x8*>(ALb + (wr * 64 + mi2 * 16 + ql) * 32 + g * 8);
#pragma unroll
    for (int ni2 = 0; ni2 < 4; ++ni2)
      bfr[ni2] = *reinterpret_cast<const bf16x8*>(BLb + (wc * 64 + ni2 * 16 + ql) * 32 + g * 8);
#pragma unroll
    for (int mi2 = 0; mi2 < 4; ++mi2)
#pragma unroll
      for (int ni2 = 0; ni2 < 4; ++ni2)
        acc[mi2][ni2] = __builtin_amdgcn_mfma_f32_16x16x32_bf16(af[mi2], bfr[ni2], acc[mi2][ni2], 0, 0, 0);
    __syncthreads();
    buf ^= 1;
  }

  const float* bias = region == 0 ? bq : (region == 1 ? bk : bv);
  const float scale = region == 0 ? CQ : 1.0f;
  const int nl0 = n0 - (region << 9);
  ushort_t* outT = region == 0 ? Qo : Ko;

  float bvv[4];
#pragma unroll
  for (int ni2 = 0; ni2 < 4; ++ni2) bvv[ni2] = bias[nl0 + wc * 64 + ni2 * 16 + ql];

#pragma unroll
  for (int mi2 = 0; mi2 < 4; ++mi2) {
#pragma unroll
    for (int ni2 = 0; ni2 < 4; ++ni2) {
      int nl = nl0 + wc * 64 + ni2 * 16 + ql;
      int h = nl >> 6, d = nl & 63;
#pragma unroll
      for (int reg = 0; reg < 4; ++reg) {
        float val = (acc[mi2][ni2][reg] + bvv[ni2]) * scale;
        int m = m0 + wr * 64 + mi2 * 16 + 4 * g + reg;
        int b = m >> 12, s = m & 4095;
        if (region <= 1) {
          outT[(((size_t)(b * NHEADS + h) * S_LEN + s) * DK) + d] = bf1(val);
        } else {
          int k6 = s & 63;
          int pos = (k6 & 32) | (((k6 >> 2) & 3) << 3) | (((k6 >> 4) & 1) << 2) | (k6 & 3);
          int sperm = (s & ~63) | pos;
          Vo[(((size_t)(b * NHEADS + h) * DK + d) * S_LEN) + sperm] = bf1(val);
        }
      }
    }
  }
}

// ---------------------------------------------------------------------------
// Fused Wo GEMM + split-combine: A = (O0+O1)*rcp(l0+l1) staged in-regs ->
// bf16 -> ds_write; B via global_load_lds. out fp32 [M,512].
// Flat grid 256 with XCD grouping (4 n-blocks share an m-panel in L2).
// ---------------------------------------------------------------------------
__global__ __launch_bounds__(256) void gemm_wo_fused(
    const ushort_t* __restrict__ Opart, const float* __restrict__ Lpart,
    const ushort_t* __restrict__ Wt, const float* __restrict__ bias,
    float* __restrict__ out) {
  __shared__ ushort_t AL[2][128 * 32];
  __shared__ ushort_t BL[2][128 * 32];
  const int tid = threadIdx.x;
  const int wid = tid >> 6;
  const int lane = tid & 63;
  const int ql = lane & 15;
  const int g = lane >> 4;
  const int wr = wid >> 1, wc = wid & 1;

  // 256 = 8 XCD x 32; within XCD: 8 m-panels x 4 n-blocks
  const int p = blockIdx.x;
  const int L = (p & 7) * 32 + (p >> 3);
  const int m0 = (L >> 2) * 128, n0 = (L & 3) * 128;

  f32x4 acc[4][4];
#pragma unroll
  for (int i = 0; i < 4; ++i)
#pragma unroll
    for (int j = 0; j < 4; ++j) acc[i][j] = (f32x4){0.f, 0.f, 0.f, 0.f};

  // per-thread staged rows (fixed across k-steps)
  const int r_[2] = {tid >> 2, 256 / 4 + (tid >> 2)};  // idx>>2 for i=0,1
  const int c8 = (tid & 3) * 8;                        // k-chunk within 32

  int sA[2], bhbase[2];
#pragma unroll
  for (int i = 0; i < 2; ++i) {
    int m = m0 + r_[i];
    int b = m >> 12;
    sA[i] = m & 4095;
    bhbase[i] = b * 8;
  }

  // load A-chunk (8 bf16 from each split) + combine -> uint4
  auto loadA = [&](int k0, uint4 av[2], float inv[2]) {
    int kg = k0 + c8;
    int h = kg >> 6, d = kg & 63;
#pragma unroll
    for (int i = 0; i < 2; ++i) {
      int bh = bhbase[i] + h;
      size_t off = ((size_t)bh * S_LEN + sA[i]) * 64 + d;
      av[i] = *reinterpret_cast<const uint4*>(Opart + off);
      uint4 a1 = *reinterpret_cast<const uint4*>(Opart + off + (size_t)16 * S_LEN * 64);
      float l = Lpart[(size_t)bh * S_LEN + sA[i]] + Lpart[((size_t)(16 + bh)) * S_LEN + sA[i]];
      inv[i] = fastrcp(l);
      // combine in place: av[i] = packed bf16 of (a0+a1)*inv
      unsigned u0[4] = {av[i].x, av[i].y, av[i].z, av[i].w};
      unsigned u1[4] = {a1.x, a1.y, a1.z, a1.w};
      unsigned r[4];
#pragma unroll
      for (int j = 0; j < 4; ++j) {
        float e0 = (bflo(u0[j]) + bflo(u1[j])) * inv[i];
        float e1 = (bfhi(u0[j]) + bfhi(u1[j])) * inv[i];
        r[j] = packbf(e0, e1);
      }
      av[i].x = r[0]; av[i].y = r[1]; av[i].z = r[2]; av[i].w = r[3];
    }
  };

  auto writeA = [&](int buf, uint4 av[2]) {
#pragma unroll
    for (int i = 0; i < 2; ++i) {
      int idx = i * 256 + tid;
      *reinterpret_cast<uint4*>(&AL[buf][idx * 8]) = av[i];
    }
  };

  auto stageB = [&](int k0, int buf) {
#pragma unroll
    for (int i = 0; i < 2; ++i) {
      int idx = i * 256 + tid;
      int r = idx >> 2;
      int c = (idx & 3) * 8;
      gll16(Wt + (size_t)(n0 + r) * 512 + k0 + c, &BL[buf][idx * 8]);
    }
  };

  {
    uint4 av[2]; float inv[2];
    loadA(0, av, inv);
    writeA(0, av);
    stageB(0, 0);
  }
  __syncthreads();

  for (int t = 0; t < 16; ++t) {
    const int buf = t & 1;
    uint4 av[2]; float inv[2];
    if (t < 15) {
      stageB((t + 1) * 32, buf ^ 1);
      loadA((t + 1) * 32, av, inv);
    }
    const ushort_t* ALb = &AL[buf][0];
    const ushort_t* BLb = &BL[buf][0];
    bf16x8 af[4], bfr[4];
#pragma unroll
    for (int mi = 0; mi < 4; ++mi)
      af[mi] = *reinterpret_cast<const bf16x8*>(ALb + (wr * 64 + mi * 16 + ql) * 32 + g * 8);
#pragma unroll
    for (int ni = 0; ni < 4; ++ni)
      bfr[ni] = *reinterpret_cast<const bf16x8*>(BLb + (wc * 64 + ni * 16 + ql) * 32 + g * 8);
#pragma unroll
    for (int mi = 0; mi < 4; ++mi)
#pragma unroll
      for (int ni = 0; ni < 4; ++ni)
        acc[mi][ni] = __builtin_amdgcn_mfma_f32_16x16x32_bf16(af[mi], bfr[ni], acc[mi][ni], 0, 0, 0);
    if (t < 15) writeA(buf ^ 1, av);  // other buffer: race-free before barrier
    __syncthreads();
  }

  float bv[4];
#pragma unroll
  for (int ni = 0; ni < 4; ++ni) bv[ni] = bias[n0 + wc * 64 + ni * 16 + ql];

#pragma unroll
  for (int mi = 0; mi < 4; ++mi) {
#pragma unroll
    for (int ni = 0; ni < 4; ++ni) {
      int n = n0 + wc * 64 + ni * 16 + ql;
#pragma unroll
      for (int reg = 0; reg < 4; ++reg) {
        int m = m0 + wr * 64 + mi * 16 + 4 * g + reg;
        out[(size_t)m * 512 + n] = acc[mi][ni][reg] + bv[ni];
      }
    }
  }
}

// ---------------------------------------------------------------------------
// Plain Wo GEMM (fallback, bf16 A input): out = A @ Wt^T + bias, fp32.
// ---------------------------------------------------------------------------
__global__ __launch_bounds__(256) void gemm_wo(
    const ushort_t* __restrict__ A, const ushort_t* __restrict__ Wt,
    const float* __restrict__ bias, float* __restrict__ out) {
  __shared__ ushort_t AL[2][128 * 32];
  __shared__ ushort_t BL[2][128 * 32];
  const int tid = threadIdx.x;
  const int wid = tid >> 6;
  const int lane = tid & 63;
  const int ql = lane & 15;
  const int g = lane >> 4;
  const int wr = wid >> 1, wc = wid & 1;
  const int m0 = blockIdx.x * 128, n0 = blockIdx.y * 128;

  f32x4 acc[4][4];
#pragma unroll
  for (int i = 0; i < 4; ++i)
#pragma unroll
    for (int j = 0; j < 4; ++j) acc[i][j] = (f32x4){0.f, 0.f, 0.f, 0.f};

  auto stage = [&](int k0, int buf) {
#pragma unroll
    for (int i = 0; i < 2; ++i) {
      int idx = i * 256 + tid;
      int r = idx >> 2;
      int c = (idx & 3) * 8;
      gll16(A + (size_t)(m0 + r) * 512 + k0 + c, &AL[buf][idx * 8]);
      gll16(Wt + (size_t)(n0 + r) * 512 + k0 + c, &BL[buf][idx * 8]);
    }
  };

  stage(0, 0);
  __syncthreads();
  int buf = 0;

  for (int t = 0; t < 16; ++t) {
    if (t < 15) stage((t + 1) * 32, buf ^ 1);
    const ushort_t* ALb = &AL[buf][0];
    const ushort_t* BLb = &BL[buf][0];
    bf16x8 af[4], bfr[4];
#pragma unroll
    for (int mi = 0; mi < 4; ++mi)
      af[mi] = *reinterpret_cast<const bf16x8*>(ALb + (wr * 64 + mi * 16 + ql) * 32 + g * 8);
#pragma unroll
    for (int ni = 0; ni < 4; ++ni)
      bfr[ni] = *reinterpret_cast<const bf16x8*>(BLb + (wc * 64 + ni * 16 + ql) * 32 + g * 8);
#pragma unroll
    for (int mi = 0; mi < 4; ++mi)
#pragma unroll
      for (int ni = 0; ni < 4; ++ni)
        acc[mi][ni] = __builtin_amdgcn_mfma_f32_16x16x32_bf16(af[mi], bfr[ni], acc[mi][ni], 0, 0, 0);
    __syncthreads();
    buf ^= 1;
  }

  float bv[4];
#pragma unroll
  for (int ni = 0; ni < 4; ++ni) bv[ni] = bias[n0 + wc * 64 + ni * 16 + ql];

#pragma unroll
  for (int mi = 0; mi < 4; ++mi) {
#pragma unroll
    for (int ni = 0; ni < 4; ++ni) {
      int n = n0 + wc * 64 + ni * 16 + ql;
#pragma unroll
      for (int reg = 0; reg < 4; ++reg) {
        int m = m0 + wr * 64 + mi * 16 + 4 * g + reg;
        out[(size_t)m * 512 + n] = acc[mi][ni][reg] + bv[ni];
      }
    }
  }
}

// ---------------------------------------------------------------------------
// MFMA flash attention, no-max softmax, 32 q/wave. V pre-permuted (single
// b128 PV fragments), cvt_pk packing, unrolled-by-2 dbuf, bf16 partials.
// ---------------------------------------------------------------------------
template <bool SPLIT2>
__global__ __launch_bounds__(256, 4) void attn_mfma(
    const ushort_t* __restrict__ Q, const ushort_t* __restrict__ K,
    const ushort_t* __restrict__ Vt, ushort_t* __restrict__ AO,
    ushort_t* __restrict__ Opart, float* __restrict__ Lpart) {
  __shared__ ushort_t KL[2][64 * 64];
  __shared__ ushort_t VL[2][64 * 64];

  const int tid = threadIdx.x;
  const int wid = tid >> 6;
  const int lane = tid & 63;
  const int g = lane >> 4;
  const int ql = lane & 15;

  int L;
  if (SPLIT2) {
    int orig = blockIdx.x;
    L = (orig & 7) * 128 + (orig >> 3);
  } else {
    L = blockIdx.x;
  }
  const int qt = L & 31;
  const int bhsp = L >> 5;
  const int sp = SPLIT2 ? (bhsp & 1) : 0;
  const int bh = SPLIT2 ? (bhsp >> 1) : bhsp;
  const int NT = SPLIT2 ? 32 : 64;
  const int t0 = sp * NT;

  const ushort_t* Qb = Q + (size_t)bh * S_LEN * DK;
  const ushort_t* Kb = K + (size_t)bh * S_LEN * DK;
  const ushort_t* Vb = Vt + (size_t)bh * DK * S_LEN;

  const int qbase = qt * 128 + wid * 32;

  bf16x8 qf[2][2];
#pragma unroll
  for (int c = 0; c < 2; ++c) {
    int q = qbase + c * 16 + ql;
#pragma unroll
    for (int t = 0; t < 2; ++t)
      qf[c][t] = *reinterpret_cast<const bf16x8*>(Qb + (size_t)q * DK + t * 32 + g * 8);
  }

  bf16x8 ones;
#pragma unroll
  for (int j = 0; j < 8; ++j) ones[j] = (short)0x3F80;

  f32x4 ot[4][2];
#pragma unroll
  for (int db = 0; db < 4; ++db)
#pragma unroll
    for (int c = 0; c < 2; ++c) ot[db][c] = (f32x4){0.f, 0.f, 0.f, 0.f};
  f32x4 lacc[2];
  lacc[0] = (f32x4){0.f, 0.f, 0.f, 0.f};
  lacc[1] = (f32x4){0.f, 0.f, 0.f, 0.f};

  const int srow = lane >> 3;
  const int schk = lane & 7;
  const int r0 = wid * 16 + srow;
  const int r1 = r0 + 8;
  const int ssc = (schk ^ srow) << 4;

  const char* gk0 = (const char*)Kb + ((size_t)(t0 * 64 + r0)) * 128 + ssc;
  const char* gk1 = (const char*)Kb + ((size_t)(t0 * 64 + r1)) * 128 + ssc;
  const char* gv0 = (const char*)Vb + (size_t)r0 * (S_LEN * 2) + (size_t)t0 * 128 + ssc;
  const char* gv1 = (const char*)Vb + (size_t)r1 * (S_LEN * 2) + (size_t)t0 * 128 + ssc;

  char* lkA0 = (char*)&KL[0][0] + (wid * 16) * 128 + lane * 16;
  char* lkB0 = lkA0 + 8 * 128;
  char* lkA1 = lkA0 + 8192;
  char* lkB1 = lkB0 + 8192;
  char* lvA0 = (char*)&VL[0][0] + (wid * 16) * 128 + lane * 16;
  char* lvB0 = lvA0 + 8 * 128;
  char* lvA1 = lvA0 + 8192;
  char* lvB1 = lvB0 + 8192;

  int koA[4], koB[4];
#pragma unroll
  for (int kb = 0; kb < 4; ++kb) {
    int r = kb * 16 + ql;
    koA[kb] = r * 128 + (((g) ^ (r & 7)) << 4);
    koB[kb] = r * 128 + (((g + 4) ^ (r & 7)) << 4);
  }
  int voP[2][4];
#pragma unroll
  for (int t = 0; t < 2; ++t)
#pragma unroll
    for (int db = 0; db < 4; ++db) {
      int rd = db * 16 + ql;
      voP[t][db] = rd * 128 + (((t * 4 + g) ^ (rd & 7)) << 4);
    }

  gll16(gk0, lkA0); gll16(gk1, lkB0);
  gll16(gv0, lvA0); gll16(gv1, lvB0);
  gk0 += 8192; gk1 += 8192; gv0 += 128; gv1 += 128;
  __syncthreads();

  auto body = [&](const char* KB, const char* VB, char* dkA, char* dkB,
                  char* dvA, char* dvB, bool pref) {
    if (pref) {
      gll16(gk0, dkA); gll16(gk1, dkB);
      gll16(gv0, dvA); gll16(gv1, dvB);
      gk0 += 8192; gk1 += 8192; gv0 += 128; gv1 += 128;
    }

    f32x4 st[4][2];
    __builtin_amdgcn_s_setprio(1);
#pragma unroll
    for (int kb = 0; kb < 4; ++kb) {
      bf16x8 k0 = *reinterpret_cast<const bf16x8*>(KB + koA[kb]);
      bf16x8 k1 = *reinterpret_cast<const bf16x8*>(KB + koB[kb]);
#pragma unroll
      for (int c = 0; c < 2; ++c) {
        f32x4 z = (f32x4){0.f, 0.f, 0.f, 0.f};
        z = __builtin_amdgcn_mfma_f32_16x16x32_bf16(k0, qf[c][0], z, 0, 0, 0);
        z = __builtin_amdgcn_mfma_f32_16x16x32_bf16(k1, qf[c][1], z, 0, 0, 0);
        st[kb][c] = z;
      }
    }
    __builtin_amdgcn_s_setprio(0);

    unsigned pk[2][4][2];
#pragma unroll
    for (int c = 0; c < 2; ++c)
#pragma unroll
      for (int kb = 0; kb < 4; ++kb)
#pragma unroll
        for (int r2 = 0; r2 < 2; ++r2) {
          float pa = __builtin_amdgcn_exp2f(st[kb][c][2 * r2]);
          float pb_ = __builtin_amdgcn_exp2f(st[kb][c][2 * r2 + 1]);
          pk[c][kb][r2] = packbf(pa, pb_);
        }

    __builtin_amdgcn_s_setprio(1);
#pragma unroll
    for (int t = 0; t < 2; ++t) {
      union { unsigned u[4]; bf16x8 v; } pb0, pb1;
      pb0.u[0] = pk[0][2 * t][0];     pb0.u[1] = pk[0][2 * t][1];
      pb0.u[2] = pk[0][2 * t + 1][0]; pb0.u[3] = pk[0][2 * t + 1][1];
      pb1.u[0] = pk[1][2 * t][0];     pb1.u[1] = pk[1][2 * t][1];
      pb1.u[2] = pk[1][2 * t + 1][0]; pb1.u[3] = pk[1][2 * t + 1][1];
#pragma unroll
      for (int db = 0; db < 4; ++db) {
        bf16x8 af = *reinterpret_cast<const bf16x8*>(VB + voP[t][db]);
        ot[db][0] = __builtin_amdgcn_mfma_f32_16x16x32_bf16(af, pb0.v, ot[db][0], 0, 0, 0);
        ot[db][1] = __builtin_amdgcn_mfma_f32_16x16x32_bf16(af, pb1.v, ot[db][1], 0, 0, 0);
      }
      lacc[0] = __builtin_amdgcn_mfma_f32_16x16x32_bf16(ones, pb0.v, lacc[0], 0, 0, 0);
      lacc[1] = __builtin_amdgcn_mfma_f32_16x16x32_bf16(ones, pb1.v, lacc[1], 0, 0, 0);
    }
    __builtin_amdgcn_s_setprio(0);

    __syncthreads();
  };

  const char* KB0 = (const char*)&KL[0][0];
  const char* VB0 = (const char*)&VL[0][0];
  const char* KB1 = (const char*)&KL[1][0];
  const char* VB1 = (const char*)&VL[1][0];

  for (int it = 0; it < NT; it += 2) {
    body(KB0, VB0, lkA1, lkB1, lvA1, lvB1, true);
    body(KB1, VB1, lkA0, lkB0, lvA0, lvB0, it + 2 < NT);
  }

  if (SPLIT2) {
    ushort_t* Ob = Opart + (((size_t)sp * 16 + bh) * S_LEN) * 64;
#pragma unroll
    for (int c = 0; c < 2; ++c) {
      const int q = qbase + c * 16 + ql;
#pragma unroll
      for (int db = 0; db < 4; ++db) {
        uint2 o;
        o.x = packbf(ot[db][c][0], ot[db][c][1]);
        o.y = packbf(ot[db][c][2], ot[db][c][3]);
        *reinterpret_cast<uint2*>(Ob + (size_t)q * 64 + db * 16 + 4 * g) = o;
      }
      if (g == 0) Lpart[((size_t)sp * 16 + bh) * S_LEN + q] = lacc[c][0];
    }
  } else {
    const int b = bh >> 3, h = bh & 7;
#pragma unroll
    for (int c = 0; c < 2; ++c) {
      const int q = qbase + c * 16 + ql;
      float inv = 1.f / lacc[c][0];
#pragma unroll
      for (int db = 0; db < 4; ++db) {
        uint2 o;
        o.x = packbf(ot[db][c][0] * inv, ot[db][c][1] * inv);
        o.y = packbf(ot[db][c][2] * inv, ot[db][c][3] * inv);
        *reinterpret_cast<uint2*>(AO + ((size_t)b * S_LEN + q) * DMODEL + h * DK + db * 16 + g * 4) = o;
      }
    }
  }
}

extern "C" void kernel_launch(void* const* d_in, const int* in_sizes, int n_in,
                              void* d_out, int out_size, void* d_ws, size_t ws_size,
                              hipStream_t stream) {
  const float* x  = (const float*)d_in[0];
  const float* Wq = (const float*)d_in[1];
  const float* bq = (const float*)d_in[2];
  const float* Wk = (const float*)d_in[3];
  const float* bk = (const float*)d_in[4];
  const float* Wv = (const float*)d_in[5];
  const float* bv = (const float*)d_in[6];
  const float* Wo = (const float*)d_in[7];
  const float* bo = (const float*)d_in[8];
  float* out = (float*)d_out;

  const float CQ = 0.18033688f;  // 0.125 * log2(e)

  char* ws = (char*)d_ws;
  const size_t NBF = (size_t)MROWS * DMODEL;  // 4 Mi elements
  ushort_t* xbf = (ushort_t*)ws;              // 8MB (AOb reuse in split path)
  ushort_t* Qbf = (ushort_t*)(ws + NBF * 2);
  ushort_t* Kbf = (ushort_t*)(ws + NBF * 4);
  ushort_t* Vtb = (ushort_t*)(ws + NBF * 6);

  const size_t OFF_WT    = NBF * 8;
  const size_t OFF_LPART = OFF_WT + 4 * 512 * 512 * 2;
  const size_t OFF_OPART = OFF_LPART + 512 * 1024;
  const size_t NEED_SPLIT = OFF_OPART + (size_t)2 * 16 * S_LEN * 64 * 2;  // bf16 partials
  const bool use_split = ws_size >= NEED_SPLIT;

  ushort_t* Wcat;
  ushort_t* AOb;
  if (use_split) {
    Wcat = (ushort_t*)(ws + OFF_WT);
    AOb = xbf;
  } else {
    AOb = (ushort_t*)(ws + NBF * 8);
    Wcat = (ushort_t*)(ws + NBF * 10);
  }
  ushort_t* Wot = Wcat + 3 * 512 * 512;
  float* Lpart = (float*)(ws + OFF_LPART);
  ushort_t* Opart = (ushort_t*)(ws + OFF_OPART);

  prep<<<3072, 256, 0, stream>>>(x, Wq, Wk, Wv, Wo, xbf, Wcat, Wot);

  gemm_qkv<<<768, 256, 0, stream>>>(xbf, Wcat, bq, bk, bv, Qbf, Kbf, Vtb, CQ);

  if (use_split) {
    attn_mfma<true><<<1024, 256, 0, stream>>>(Qbf, Kbf, Vtb, AOb, Opart, Lpart);
    gemm_wo_fused<<<256, 256, 0, stream>>>(Opart, Lpart, Wot, bo, out);
  } else {
    attn_mfma<false><<<512, 256, 0, stream>>>(Qbf, Kbf, Vtb, AOb, Opart, Lpart);
    dim3 gg(MROWS / 128, DMODEL / 128);
    gemm_wo<<<gg, 256, 0, stream>>>(AOb, Wot, bo, out);
  }
}

// Round 11
// 117.093 us; speedup vs baseline: 13.5947x; 1.0451x over previous
//
#include <hip/hip_runtime.h>
#include <hip/hip_bf16.h>

#define S_LEN 4096
#define DMODEL 512
#define NHEADS 8
#define DK 64
#define BATCH 2
#define MROWS (BATCH * S_LEN)  // 8192

typedef __attribute__((ext_vector_type(8))) short bf16x8;
typedef __attribute__((ext_vector_type(4))) float f32x4;
typedef unsigned short ushort_t;

// single-instruction pack: low16 = bf16(a), high16 = bf16(b), RNE
__device__ __forceinline__ unsigned packbf(float a, float b) {
  unsigned r;
  asm("v_cvt_pk_bf16_f32 %0, %1, %2" : "=v"(r) : "v"(a), "v"(b));
  return r;
}

__device__ __forceinline__ unsigned short bf1(float a) {
  union { __hip_bfloat16 h; unsigned short s; } u;
  u.h = __float2bfloat16(a);
  return u.s;
}

__device__ __forceinline__ float bflo(unsigned u) { return __uint_as_float(u << 16); }
__device__ __forceinline__ float bfhi(unsigned u) { return __uint_as_float(u & 0xFFFF0000u); }

__device__ __forceinline__ float fastrcp(float x) {
  float r;
  asm("v_rcp_f32 %0, %1" : "=v"(r) : "v"(x));
  return r;
}

__device__ __forceinline__ void gll16(const void* g, void* l) {
  __builtin_amdgcn_global_load_lds(
      (const __attribute__((address_space(1))) unsigned*)g,
      (__attribute__((address_space(3))) unsigned*)l, 16, 0, 0);
}

// ---------------------------------------------------------------------------
// Prep: transpose the 4 weights fp32 (k,n) -> bf16 (n,k). 1024 blocks.
// ---------------------------------------------------------------------------
__global__ __launch_bounds__(256) void prep(
    const float* __restrict__ Wq, const float* __restrict__ Wk,
    const float* __restrict__ Wv, const float* __restrict__ Wo,
    ushort_t* __restrict__ Wcat, ushort_t* __restrict__ Wot) {
  __shared__ float T[32][33];
  const int bid = blockIdx.x;
  const int tid = threadIdx.x;
  int w = bid >> 8;
  int tile = bid & 255;
  int k0 = (tile & 15) * 32, n0 = (tile >> 4) * 32;
  const float* W = w == 0 ? Wq : (w == 1 ? Wk : (w == 2 ? Wv : Wo));
  ushort_t* out = (w == 3) ? Wot : (Wcat + (size_t)w * 512 * 512);
  const int r = tid >> 3, c4 = (tid & 7) * 4;
  float4 v = *reinterpret_cast<const float4*>(W + (size_t)(k0 + r) * 512 + n0 + c4);
  T[r][c4 + 0] = v.x; T[r][c4 + 1] = v.y; T[r][c4 + 2] = v.z; T[r][c4 + 3] = v.w;
  __syncthreads();
  uint2 o;
  o.x = packbf(T[c4 + 0][r], T[c4 + 1][r]);
  o.y = packbf(T[c4 + 2][r], T[c4 + 3][r]);
  *reinterpret_cast<uint2*>(out + (size_t)(n0 + r) * 512 + k0 + c4) = o;
}

// ---------------------------------------------------------------------------
// Fused QKV GEMM: [Q|K|V] = x[8192,512](fp32, reg-staged->bf16) @ Wcat^T + b
// Flat grid 768, XCD grouping. Q scaled by CQ. Q,K -> [B,H,S,DK];
// V -> [B,H,DK,S] with within-64-key-tile permuted s order.
// ---------------------------------------------------------------------------
__global__ __launch_bounds__(256) void gemm_qkv(
    const float* __restrict__ x, const ushort_t* __restrict__ Wcat,
    const float* __restrict__ bq, const float* __restrict__ bk,
    const float* __restrict__ bv, ushort_t* __restrict__ Qo,
    ushort_t* __restrict__ Ko, ushort_t* __restrict__ Vo, float CQ) {
  __shared__ ushort_t AL[2][128 * 32];
  __shared__ ushort_t BL[2][128 * 32];
  const int tid = threadIdx.x;
  const int wid = tid >> 6;
  const int lane = tid & 63;
  const int ql = lane & 15;
  const int g = lane >> 4;
  const int wr = wid >> 1, wc = wid & 1;

  // XCD grouping: 768 = 8 XCD x 96; within XCD: 8 m-panels x 12 n-blocks.
  const int p = blockIdx.x;
  const int xcd = p & 7, q_ = p >> 3;
  const int mi = xcd * 8 + q_ / 12;
  const int ni = q_ % 12;
  const int m0 = mi * 128, n0 = ni * 128;
  const int region = n0 >> 9;  // 0=Q 1=K 2=V

  f32x4 acc[4][4];
#pragma unroll
  for (int i = 0; i < 4; ++i)
#pragma unroll
    for (int j = 0; j < 4; ++j) acc[i][j] = (f32x4){0.f, 0.f, 0.f, 0.f};

  auto loadA = [&](int k0, uint4 av[2]) {
#pragma unroll
    for (int i = 0; i < 2; ++i) {
      int idx = i * 256 + tid;
      int r = idx >> 2;
      int c = (idx & 3) * 8;
      const float* src = x + (size_t)(m0 + r) * 512 + k0 + c;
      float4 a = *reinterpret_cast<const float4*>(src);
      float4 b = *reinterpret_cast<const float4*>(src + 4);
      av[i].x = packbf(a.x, a.y);
      av[i].y = packbf(a.z, a.w);
      av[i].z = packbf(b.x, b.y);
      av[i].w = packbf(b.z, b.w);
    }
  };
  auto writeA = [&](int buf, uint4 av[2]) {
#pragma unroll
    for (int i = 0; i < 2; ++i) {
      int idx = i * 256 + tid;
      *reinterpret_cast<uint4*>(&AL[buf][idx * 8]) = av[i];
    }
  };
  auto stageB = [&](int k0, int buf) {
#pragma unroll
    for (int i = 0; i < 2; ++i) {
      int idx = i * 256 + tid;
      int r = idx >> 2;
      int c = (idx & 3) * 8;
      gll16(Wcat + (size_t)(n0 + r) * 512 + k0 + c, &BL[buf][idx * 8]);
    }
  };

  {
    uint4 av[2];
    loadA(0, av);
    writeA(0, av);
    stageB(0, 0);
  }
  __syncthreads();

  for (int t = 0; t < 16; ++t) {
    const int buf = t & 1;
    uint4 av[2];
    if (t < 15) {
      stageB((t + 1) * 32, buf ^ 1);
      loadA((t + 1) * 32, av);
    }
    const ushort_t* ALb = &AL[buf][0];
    const ushort_t* BLb = &BL[buf][0];
    bf16x8 af[4], bfr[4];
#pragma unroll
    for (int mi2 = 0; mi2 < 4; ++mi2)
      af[mi2] = *reinterpret_cast<const bf16x8*>(ALb + (wr * 64 + mi2 * 16 + ql) * 32 + g * 8);
#pragma unroll
    for (int ni2 = 0; ni2 < 4; ++ni2)
      bfr[ni2] = *reinterpret_cast<const bf16x8*>(BLb + (wc * 64 + ni2 * 16 + ql) * 32 + g * 8);
#pragma unroll
    for (int mi2 = 0; mi2 < 4; ++mi2)
#pragma unroll
      for (int ni2 = 0; ni2 < 4; ++ni2)
        acc[mi2][ni2] = __builtin_amdgcn_mfma_f32_16x16x32_bf16(af[mi2], bfr[ni2], acc[mi2][ni2], 0, 0, 0);
    if (t < 15) writeA(buf ^ 1, av);
    __syncthreads();
  }

  const float* bias = region == 0 ? bq : (region == 1 ? bk : bv);
  const float scale = region == 0 ? CQ : 1.0f;
  const int nl0 = n0 - (region << 9);
  ushort_t* outT = region == 0 ? Qo : Ko;

  float bvv[4];
#pragma unroll
  for (int ni2 = 0; ni2 < 4; ++ni2) bvv[ni2] = bias[nl0 + wc * 64 + ni2 * 16 + ql];

#pragma unroll
  for (int mi2 = 0; mi2 < 4; ++mi2) {
#pragma unroll
    for (int ni2 = 0; ni2 < 4; ++ni2) {
      int nl = nl0 + wc * 64 + ni2 * 16 + ql;
      int h = nl >> 6, d = nl & 63;
#pragma unroll
      for (int reg = 0; reg < 4; ++reg) {
        float val = (acc[mi2][ni2][reg] + bvv[ni2]) * scale;
        int m = m0 + wr * 64 + mi2 * 16 + 4 * g + reg;
        int b = m >> 12, s = m & 4095;
        if (region <= 1) {
          outT[(((size_t)(b * NHEADS + h) * S_LEN + s) * DK) + d] = bf1(val);
        } else {
          int k6 = s & 63;
          int pos = (k6 & 32) | (((k6 >> 2) & 3) << 3) | (((k6 >> 4) & 1) << 2) | (k6 & 3);
          int sperm = (s & ~63) | pos;
          Vo[(((size_t)(b * NHEADS + h) * DK + d) * S_LEN) + sperm] = bf1(val);
        }
      }
    }
  }
}

// ---------------------------------------------------------------------------
// Fused Wo GEMM + split-combine, 64x128 tiles, 512 blocks (2/CU), XCD-grouped.
// A = (O0+O1)*rcp(l0+l1) reg-staged -> bf16 -> ds_write; B via gll16.
// ---------------------------------------------------------------------------
__global__ __launch_bounds__(256) void gemm_wo_fused(
    const ushort_t* __restrict__ Opart, const float* __restrict__ Lpart,
    const ushort_t* __restrict__ Wt, const float* __restrict__ bias,
    float* __restrict__ out) {
  __shared__ ushort_t AL[2][64 * 32];
  __shared__ ushort_t BL[2][128 * 32];
  const int tid = threadIdx.x;
  const int wid = tid >> 6;
  const int lane = tid & 63;
  const int ql = lane & 15;
  const int g = lane >> 4;
  const int wr = wid >> 1, wc = wid & 1;

  // 512 = 8 XCD x 64; within XCD: 16 m-panels x 4 n-blocks.
  const int p = blockIdx.x;
  const int L = (p & 7) * 64 + (p >> 3);
  const int m0 = (L >> 2) * 64, n0 = (L & 3) * 128;

  f32x4 acc[2][4];
#pragma unroll
  for (int i = 0; i < 2; ++i)
#pragma unroll
    for (int j = 0; j < 4; ++j) acc[i][j] = (f32x4){0.f, 0.f, 0.f, 0.f};

  const int rA = tid >> 2;          // 0..63
  const int c8 = (tid & 3) * 8;
  const int mrow = m0 + rA;
  const int bb = mrow >> 12;
  const int sA = mrow & 4095;
  const int bhbase = bb * 8;

  auto loadA = [&](int k0, uint4& av) {
    int kg = k0 + c8;
    int h = kg >> 6, d = kg & 63;
    int bh = bhbase + h;
    size_t off = ((size_t)bh * S_LEN + sA) * 64 + d;
    uint4 a0 = *reinterpret_cast<const uint4*>(Opart + off);
    uint4 a1 = *reinterpret_cast<const uint4*>(Opart + off + (size_t)16 * S_LEN * 64);
    float l = Lpart[(size_t)bh * S_LEN + sA] + Lpart[(size_t)(16 + bh) * S_LEN + sA];
    float inv = fastrcp(l);
    unsigned u0[4] = {a0.x, a0.y, a0.z, a0.w};
    unsigned u1[4] = {a1.x, a1.y, a1.z, a1.w};
    unsigned r[4];
#pragma unroll
    for (int j = 0; j < 4; ++j) {
      float e0 = (bflo(u0[j]) + bflo(u1[j])) * inv;
      float e1 = (bfhi(u0[j]) + bfhi(u1[j])) * inv;
      r[j] = packbf(e0, e1);
    }
    av.x = r[0]; av.y = r[1]; av.z = r[2]; av.w = r[3];
  };
  auto writeA = [&](int buf, uint4 av) {
    *reinterpret_cast<uint4*>(&AL[buf][tid * 8]) = av;  // = rA*32 + c8
  };
  auto stageB = [&](int k0, int buf) {
#pragma unroll
    for (int i = 0; i < 2; ++i) {
      int idx = i * 256 + tid;
      int r = idx >> 2;
      int c = (idx & 3) * 8;
      gll16(Wt + (size_t)(n0 + r) * 512 + k0 + c, &BL[buf][idx * 8]);
    }
  };

  {
    uint4 av;
    loadA(0, av);
    writeA(0, av);
    stageB(0, 0);
  }
  __syncthreads();

  for (int t = 0; t < 16; ++t) {
    const int buf = t & 1;
    uint4 av;
    if (t < 15) {
      stageB((t + 1) * 32, buf ^ 1);
      loadA((t + 1) * 32, av);
    }
    const ushort_t* ALb = &AL[buf][0];
    const ushort_t* BLb = &BL[buf][0];
    bf16x8 af[2], bfr[4];
#pragma unroll
    for (int mi = 0; mi < 2; ++mi)
      af[mi] = *reinterpret_cast<const bf16x8*>(ALb + (wr * 32 + mi * 16 + ql) * 32 + g * 8);
#pragma unroll
    for (int ni = 0; ni < 4; ++ni)
      bfr[ni] = *reinterpret_cast<const bf16x8*>(BLb + (wc * 64 + ni * 16 + ql) * 32 + g * 8);
#pragma unroll
    for (int mi = 0; mi < 2; ++mi)
#pragma unroll
      for (int ni = 0; ni < 4; ++ni)
        acc[mi][ni] = __builtin_amdgcn_mfma_f32_16x16x32_bf16(af[mi], bfr[ni], acc[mi][ni], 0, 0, 0);
    if (t < 15) writeA(buf ^ 1, av);
    __syncthreads();
  }

  float bv[4];
#pragma unroll
  for (int ni = 0; ni < 4; ++ni) bv[ni] = bias[n0 + wc * 64 + ni * 16 + ql];

#pragma unroll
  for (int mi = 0; mi < 2; ++mi) {
#pragma unroll
    for (int ni = 0; ni < 4; ++ni) {
      int n = n0 + wc * 64 + ni * 16 + ql;
#pragma unroll
      for (int reg = 0; reg < 4; ++reg) {
        int m = m0 + wr * 32 + mi * 16 + 4 * g + reg;
        out[(size_t)m * 512 + n] = acc[mi][ni][reg] + bv[ni];
      }
    }
  }
}

// ---------------------------------------------------------------------------
// Plain Wo GEMM (fallback, bf16 A): out = A @ Wt^T + bias, fp32.
// ---------------------------------------------------------------------------
__global__ __launch_bounds__(256) void gemm_wo(
    const ushort_t* __restrict__ A, const ushort_t* __restrict__ Wt,
    const float* __restrict__ bias, float* __restrict__ out) {
  __shared__ ushort_t AL[2][128 * 32];
  __shared__ ushort_t BL[2][128 * 32];
  const int tid = threadIdx.x;
  const int wid = tid >> 6;
  const int lane = tid & 63;
  const int ql = lane & 15;
  const int g = lane >> 4;
  const int wr = wid >> 1, wc = wid & 1;
  const int m0 = blockIdx.x * 128, n0 = blockIdx.y * 128;

  f32x4 acc[4][4];
#pragma unroll
  for (int i = 0; i < 4; ++i)
#pragma unroll
    for (int j = 0; j < 4; ++j) acc[i][j] = (f32x4){0.f, 0.f, 0.f, 0.f};

  auto stage = [&](int k0, int buf) {
#pragma unroll
    for (int i = 0; i < 2; ++i) {
      int idx = i * 256 + tid;
      int r = idx >> 2;
      int c = (idx & 3) * 8;
      gll16(A + (size_t)(m0 + r) * 512 + k0 + c, &AL[buf][idx * 8]);
      gll16(Wt + (size_t)(n0 + r) * 512 + k0 + c, &BL[buf][idx * 8]);
    }
  };

  stage(0, 0);
  __syncthreads();
  int buf = 0;

  for (int t = 0; t < 16; ++t) {
    if (t < 15) stage((t + 1) * 32, buf ^ 1);
    const ushort_t* ALb = &AL[buf][0];
    const ushort_t* BLb = &BL[buf][0];
    bf16x8 af[4], bfr[4];
#pragma unroll
    for (int mi = 0; mi < 4; ++mi)
      af[mi] = *reinterpret_cast<const bf16x8*>(ALb + (wr * 64 + mi * 16 + ql) * 32 + g * 8);
#pragma unroll
    for (int ni = 0; ni < 4; ++ni)
      bfr[ni] = *reinterpret_cast<const bf16x8*>(BLb + (wc * 64 + ni * 16 + ql) * 32 + g * 8);
#pragma unroll
    for (int mi = 0; mi < 4; ++mi)
#pragma unroll
      for (int ni = 0; ni < 4; ++ni)
        acc[mi][ni] = __builtin_amdgcn_mfma_f32_16x16x32_bf16(af[mi], bfr[ni], acc[mi][ni], 0, 0, 0);
    __syncthreads();
    buf ^= 1;
  }

  float bv[4];
#pragma unroll
  for (int ni = 0; ni < 4; ++ni) bv[ni] = bias[n0 + wc * 64 + ni * 16 + ql];

#pragma unroll
  for (int mi = 0; mi < 4; ++mi) {
#pragma unroll
    for (int ni = 0; ni < 4; ++ni) {
      int n = n0 + wc * 64 + ni * 16 + ql;
#pragma unroll
      for (int reg = 0; reg < 4; ++reg) {
        int m = m0 + wr * 64 + mi * 16 + 4 * g + reg;
        out[(size_t)m * 512 + n] = acc[mi][ni][reg] + bv[ni];
      }
    }
  }
}

// ---------------------------------------------------------------------------
// MFMA flash attention, no-max softmax, 8 waves/block (256 q), 32 q/wave.
// V pre-permuted (single b128 PV fragments), cvt_pk, unrolled-by-2 dbuf,
// bf16 partials. 2 blocks/CU -> 16 waves/CU.
// ---------------------------------------------------------------------------
template <bool SPLIT2>
__global__ __launch_bounds__(512, 2) void attn_mfma(
    const ushort_t* __restrict__ Q, const ushort_t* __restrict__ K,
    const ushort_t* __restrict__ Vt, ushort_t* __restrict__ AO,
    ushort_t* __restrict__ Opart, float* __restrict__ Lpart) {
  __shared__ ushort_t KL[2][64 * 64];
  __shared__ ushort_t VL[2][64 * 64];

  const int tid = threadIdx.x;
  const int wid = tid >> 6;   // 0..7
  const int lane = tid & 63;
  const int g = lane >> 4;
  const int ql = lane & 15;

  // XCD-aware remap: 512 blocks = 8 XCD x 64 (16 qt x 4 bhsp each).
  int L;
  if (SPLIT2) {
    int orig = blockIdx.x;
    L = (orig & 7) * 64 + (orig >> 3);
  } else {
    L = blockIdx.x;
  }
  const int qt = L & 15;
  const int bhsp = L >> 4;
  const int sp = SPLIT2 ? (bhsp & 1) : 0;
  const int bh = SPLIT2 ? (bhsp >> 1) : bhsp;
  const int NT = SPLIT2 ? 32 : 64;
  const int t0 = sp * NT;

  const ushort_t* Qb = Q + (size_t)bh * S_LEN * DK;
  const ushort_t* Kb = K + (size_t)bh * S_LEN * DK;
  const ushort_t* Vb = Vt + (size_t)bh * DK * S_LEN;

  const int qbase = qt * 256 + wid * 32;

  bf16x8 qf[2][2];
#pragma unroll
  for (int c = 0; c < 2; ++c) {
    int q = qbase + c * 16 + ql;
#pragma unroll
    for (int t = 0; t < 2; ++t)
      qf[c][t] = *reinterpret_cast<const bf16x8*>(Qb + (size_t)q * DK + t * 32 + g * 8);
  }

  bf16x8 ones;
#pragma unroll
  for (int j = 0; j < 8; ++j) ones[j] = (short)0x3F80;

  f32x4 ot[4][2];
#pragma unroll
  for (int db = 0; db < 4; ++db)
#pragma unroll
    for (int c = 0; c < 2; ++c) ot[db][c] = (f32x4){0.f, 0.f, 0.f, 0.f};
  f32x4 lacc[2];
  lacc[0] = (f32x4){0.f, 0.f, 0.f, 0.f};
  lacc[1] = (f32x4){0.f, 0.f, 0.f, 0.f};

  // ---- staging: 8 waves x 8 rows each ----
  const int srow = lane >> 3;
  const int schk = lane & 7;
  const int r0 = wid * 8 + srow;        // 0..63
  const int ssc = (schk ^ srow) << 4;   // r0&7 == srow

  const char* gk0 = (const char*)Kb + ((size_t)(t0 * 64 + r0)) * 128 + ssc;
  const char* gv0 = (const char*)Vb + (size_t)r0 * (S_LEN * 2) + (size_t)t0 * 128 + ssc;

  char* lkA0 = (char*)&KL[0][0] + (wid * 8) * 128 + lane * 16;
  char* lkA1 = lkA0 + 8192;
  char* lvA0 = (char*)&VL[0][0] + (wid * 8) * 128 + lane * 16;
  char* lvA1 = lvA0 + 8192;

  int koA[4], koB[4];
#pragma unroll
  for (int kb = 0; kb < 4; ++kb) {
    int r = kb * 16 + ql;
    koA[kb] = r * 128 + (((g) ^ (r & 7)) << 4);
    koB[kb] = r * 128 + (((g + 4) ^ (r & 7)) << 4);
  }
  int voP[2][4];
#pragma unroll
  for (int t = 0; t < 2; ++t)
#pragma unroll
    for (int db = 0; db < 4; ++db) {
      int rd = db * 16 + ql;
      voP[t][db] = rd * 128 + (((t * 4 + g) ^ (rd & 7)) << 4);
    }

  gll16(gk0, lkA0);
  gll16(gv0, lvA0);
  gk0 += 8192; gv0 += 128;
  __syncthreads();

  auto body = [&](const char* KB, const char* VB, char* dkA, char* dvA, bool pref) {
    if (pref) {
      gll16(gk0, dkA);
      gll16(gv0, dvA);
      gk0 += 8192; gv0 += 128;
    }

    f32x4 st[4][2];
    __builtin_amdgcn_s_setprio(1);
#pragma unroll
    for (int kb = 0; kb < 4; ++kb) {
      bf16x8 k0 = *reinterpret_cast<const bf16x8*>(KB + koA[kb]);
      bf16x8 k1 = *reinterpret_cast<const bf16x8*>(KB + koB[kb]);
#pragma unroll
      for (int c = 0; c < 2; ++c) {
        f32x4 z = (f32x4){0.f, 0.f, 0.f, 0.f};
        z = __builtin_amdgcn_mfma_f32_16x16x32_bf16(k0, qf[c][0], z, 0, 0, 0);
        z = __builtin_amdgcn_mfma_f32_16x16x32_bf16(k1, qf[c][1], z, 0, 0, 0);
        st[kb][c] = z;
      }
    }
    __builtin_amdgcn_s_setprio(0);

    unsigned pk[2][4][2];
#pragma unroll
    for (int c = 0; c < 2; ++c)
#pragma unroll
      for (int kb = 0; kb < 4; ++kb)
#pragma unroll
        for (int r2 = 0; r2 < 2; ++r2) {
          float pa = __builtin_amdgcn_exp2f(st[kb][c][2 * r2]);
          float pb_ = __builtin_amdgcn_exp2f(st[kb][c][2 * r2 + 1]);
          pk[c][kb][r2] = packbf(pa, pb_);
        }

    __builtin_amdgcn_s_setprio(1);
#pragma unroll
    for (int t = 0; t < 2; ++t) {
      union { unsigned u[4]; bf16x8 v; } pb0, pb1;
      pb0.u[0] = pk[0][2 * t][0];     pb0.u[1] = pk[0][2 * t][1];
      pb0.u[2] = pk[0][2 * t + 1][0]; pb0.u[3] = pk[0][2 * t + 1][1];
      pb1.u[0] = pk[1][2 * t][0];     pb1.u[1] = pk[1][2 * t][1];
      pb1.u[2] = pk[1][2 * t + 1][0]; pb1.u[3] = pk[1][2 * t + 1][1];
#pragma unroll
      for (int db = 0; db < 4; ++db) {
        bf16x8 af = *reinterpret_cast<const bf16x8*>(VB + voP[t][db]);
        ot[db][0] = __builtin_amdgcn_mfma_f32_16x16x32_bf16(af, pb0.v, ot[db][0], 0, 0, 0);
        ot[db][1] = __builtin_amdgcn_mfma_f32_16x16x32_bf16(af, pb1.v, ot[db][1], 0, 0, 0);
      }
      lacc[0] = __builtin_amdgcn_mfma_f32_16x16x32_bf16(ones, pb0.v, lacc[0], 0, 0, 0);
      lacc[1] = __builtin_amdgcn_mfma_f32_16x16x32_bf16(ones, pb1.v, lacc[1], 0, 0, 0);
    }
    __builtin_amdgcn_s_setprio(0);

    __syncthreads();
  };

  const char* KB0 = (const char*)&KL[0][0];
  const char* VB0 = (const char*)&VL[0][0];
  const char* KB1 = (const char*)&KL[1][0];
  const char* VB1 = (const char*)&VL[1][0];

  for (int it = 0; it < NT; it += 2) {
    body(KB0, VB0, lkA1, lvA1, true);
    body(KB1, VB1, lkA0, lvA0, it + 2 < NT);
  }

  if (SPLIT2) {
    ushort_t* Ob = Opart + (((size_t)sp * 16 + bh) * S_LEN) * 64;
#pragma unroll
    for (int c = 0; c < 2; ++c) {
      const int q = qbase + c * 16 + ql;
#pragma unroll
      for (int db = 0; db < 4; ++db) {
        uint2 o;
        o.x = packbf(ot[db][c][0], ot[db][c][1]);
        o.y = packbf(ot[db][c][2], ot[db][c][3]);
        *reinterpret_cast<uint2*>(Ob + (size_t)q * 64 + db * 16 + 4 * g) = o;
      }
      if (g == 0) Lpart[((size_t)sp * 16 + bh) * S_LEN + q] = lacc[c][0];
    }
  } else {
    const int b = bh >> 3, h = bh & 7;
#pragma unroll
    for (int c = 0; c < 2; ++c) {
      const int q = qbase + c * 16 + ql;
      float inv = 1.f / lacc[c][0];
#pragma unroll
      for (int db = 0; db < 4; ++db) {
        uint2 o;
        o.x = packbf(ot[db][c][0] * inv, ot[db][c][1] * inv);
        o.y = packbf(ot[db][c][2] * inv, ot[db][c][3] * inv);
        *reinterpret_cast<uint2*>(AO + ((size_t)b * S_LEN + q) * DMODEL + h * DK + db * 16 + g * 4) = o;
      }
    }
  }
}

extern "C" void kernel_launch(void* const* d_in, const int* in_sizes, int n_in,
                              void* d_out, int out_size, void* d_ws, size_t ws_size,
                              hipStream_t stream) {
  const float* x  = (const float*)d_in[0];
  const float* Wq = (const float*)d_in[1];
  const float* bq = (const float*)d_in[2];
  const float* Wk = (const float*)d_in[3];
  const float* bk = (const float*)d_in[4];
  const float* Wv = (const float*)d_in[5];
  const float* bv = (const float*)d_in[6];
  const float* Wo = (const float*)d_in[7];
  const float* bo = (const float*)d_in[8];
  float* out = (float*)d_out;

  const float CQ = 0.18033688f;  // 0.125 * log2(e)

  char* ws = (char*)d_ws;
  const size_t NBF = (size_t)MROWS * DMODEL;  // 4 Mi elements
  ushort_t* AObuf = (ushort_t*)ws;            // 8MB (fallback AO)
  ushort_t* Qbf = (ushort_t*)(ws + NBF * 2);
  ushort_t* Kbf = (ushort_t*)(ws + NBF * 4);
  ushort_t* Vtb = (ushort_t*)(ws + NBF * 6);

  const size_t OFF_WT    = NBF * 8;
  const size_t OFF_LPART = OFF_WT + 4 * 512 * 512 * 2;
  const size_t OFF_OPART = OFF_LPART + 512 * 1024;
  const size_t NEED_SPLIT = OFF_OPART + (size_t)2 * 16 * S_LEN * 64 * 2;  // bf16 partials
  const bool use_split = ws_size >= NEED_SPLIT;

  ushort_t* Wcat;
  if (use_split) {
    Wcat = (ushort_t*)(ws + OFF_WT);
  } else {
    Wcat = (ushort_t*)(ws + NBF * 10);
  }
  ushort_t* Wot = Wcat + 3 * 512 * 512;
  float* Lpart = (float*)(ws + OFF_LPART);
  ushort_t* Opart = (ushort_t*)(ws + OFF_OPART);

  prep<<<1024, 256, 0, stream>>>(Wq, Wk, Wv, Wo, Wcat, Wot);

  gemm_qkv<<<768, 256, 0, stream>>>(x, Wcat, bq, bk, bv, Qbf, Kbf, Vtb, CQ);

  if (use_split) {
    attn_mfma<true><<<512, 512, 0, stream>>>(Qbf, Kbf, Vtb, AObuf, Opart, Lpart);
    gemm_wo_fused<<<512, 256, 0, stream>>>(Opart, Lpart, Wot, bo, out);
  } else {
    attn_mfma<false><<<256, 512, 0, stream>>>(Qbf, Kbf, Vtb, AObuf, Opart, Lpart);
    dim3 gg(MROWS / 128, DMODEL / 128);
    gemm_wo<<<gg, 256, 0, stream>>>(AObuf, Wot, bo, out);
  }
}

// Round 12
// 115.887 us; speedup vs baseline: 13.7362x; 1.0104x over previous
//
#include <hip/hip_runtime.h>
#include <hip/hip_bf16.h>

#define S_LEN 4096
#define DMODEL 512
#define NHEADS 8
#define DK 64
#define BATCH 2
#define MROWS (BATCH * S_LEN)  // 8192

typedef __attribute__((ext_vector_type(8))) short bf16x8;
typedef __attribute__((ext_vector_type(4))) float f32x4;
typedef unsigned short ushort_t;

// single-instruction pack: low16 = bf16(a), high16 = bf16(b), RNE
__device__ __forceinline__ unsigned packbf(float a, float b) {
  unsigned r;
  asm("v_cvt_pk_bf16_f32 %0, %1, %2" : "=v"(r) : "v"(a), "v"(b));
  return r;
}

__device__ __forceinline__ unsigned short bf1(float a) {
  union { __hip_bfloat16 h; unsigned short s; } u;
  u.h = __float2bfloat16(a);
  return u.s;
}

__device__ __forceinline__ float bflo(unsigned u) { return __uint_as_float(u << 16); }
__device__ __forceinline__ float bfhi(unsigned u) { return __uint_as_float(u & 0xFFFF0000u); }

__device__ __forceinline__ float fastrcp(float x) {
  float r;
  asm("v_rcp_f32 %0, %1" : "=v"(r) : "v"(x));
  return r;
}

__device__ __forceinline__ void gll16(const void* g, void* l) {
  __builtin_amdgcn_global_load_lds(
      (const __attribute__((address_space(1))) unsigned*)g,
      (__attribute__((address_space(3))) unsigned*)l, 16, 0, 0);
}

// ---------------------------------------------------------------------------
// Prep: transpose the 4 weights fp32 (k,n) -> bf16 (n,k). 1024 blocks.
// ---------------------------------------------------------------------------
__global__ __launch_bounds__(256) void prep(
    const float* __restrict__ Wq, const float* __restrict__ Wk,
    const float* __restrict__ Wv, const float* __restrict__ Wo,
    ushort_t* __restrict__ Wcat, ushort_t* __restrict__ Wot) {
  __shared__ float T[32][33];
  const int bid = blockIdx.x;
  const int tid = threadIdx.x;
  int w = bid >> 8;
  int tile = bid & 255;
  int k0 = (tile & 15) * 32, n0 = (tile >> 4) * 32;
  const float* W = w == 0 ? Wq : (w == 1 ? Wk : (w == 2 ? Wv : Wo));
  ushort_t* out = (w == 3) ? Wot : (Wcat + (size_t)w * 512 * 512);
  const int r = tid >> 3, c4 = (tid & 7) * 4;
  float4 v = *reinterpret_cast<const float4*>(W + (size_t)(k0 + r) * 512 + n0 + c4);
  T[r][c4 + 0] = v.x; T[r][c4 + 1] = v.y; T[r][c4 + 2] = v.z; T[r][c4 + 3] = v.w;
  __syncthreads();
  uint2 o;
  o.x = packbf(T[c4 + 0][r], T[c4 + 1][r]);
  o.y = packbf(T[c4 + 2][r], T[c4 + 3][r]);
  *reinterpret_cast<uint2*>(out + (size_t)(n0 + r) * 512 + k0 + c4) = o;
}

// ---------------------------------------------------------------------------
// Fused QKV GEMM: [Q|K|V] = x[8192,512](fp32, reg-staged->bf16) @ Wcat^T + b
// Flat grid 768, XCD grouping. Q scaled by CQ. Q,K -> [B,H,S,DK];
// V -> [B,H,DK,S] with within-64-key-tile permuted s order.
// ---------------------------------------------------------------------------
__global__ __launch_bounds__(256) void gemm_qkv(
    const float* __restrict__ x, const ushort_t* __restrict__ Wcat,
    const float* __restrict__ bq, const float* __restrict__ bk,
    const float* __restrict__ bv, ushort_t* __restrict__ Qo,
    ushort_t* __restrict__ Ko, ushort_t* __restrict__ Vo, float CQ) {
  __shared__ ushort_t AL[2][128 * 32];
  __shared__ ushort_t BL[2][128 * 32];
  const int tid = threadIdx.x;
  const int wid = tid >> 6;
  const int lane = tid & 63;
  const int ql = lane & 15;
  const int g = lane >> 4;
  const int wr = wid >> 1, wc = wid & 1;

  // XCD grouping: 768 = 8 XCD x 96; within XCD: 8 m-panels x 12 n-blocks.
  const int p = blockIdx.x;
  const int xcd = p & 7, q_ = p >> 3;
  const int mi = xcd * 8 + q_ / 12;
  const int ni = q_ % 12;
  const int m0 = mi * 128, n0 = ni * 128;
  const int region = n0 >> 9;  // 0=Q 1=K 2=V

  f32x4 acc[4][4];
#pragma unroll
  for (int i = 0; i < 4; ++i)
#pragma unroll
    for (int j = 0; j < 4; ++j) acc[i][j] = (f32x4){0.f, 0.f, 0.f, 0.f};

  auto loadA = [&](int k0, uint4 av[2]) {
#pragma unroll
    for (int i = 0; i < 2; ++i) {
      int idx = i * 256 + tid;
      int r = idx >> 2;
      int c = (idx & 3) * 8;
      const float* src = x + (size_t)(m0 + r) * 512 + k0 + c;
      float4 a = *reinterpret_cast<const float4*>(src);
      float4 b = *reinterpret_cast<const float4*>(src + 4);
      av[i].x = packbf(a.x, a.y);
      av[i].y = packbf(a.z, a.w);
      av[i].z = packbf(b.x, b.y);
      av[i].w = packbf(b.z, b.w);
    }
  };
  auto writeA = [&](int buf, uint4 av[2]) {
#pragma unroll
    for (int i = 0; i < 2; ++i) {
      int idx = i * 256 + tid;
      *reinterpret_cast<uint4*>(&AL[buf][idx * 8]) = av[i];
    }
  };
  auto stageB = [&](int k0, int buf) {
#pragma unroll
    for (int i = 0; i < 2; ++i) {
      int idx = i * 256 + tid;
      int r = idx >> 2;
      int c = (idx & 3) * 8;
      gll16(Wcat + (size_t)(n0 + r) * 512 + k0 + c, &BL[buf][idx * 8]);
    }
  };

  {
    uint4 av[2];
    loadA(0, av);
    writeA(0, av);
    stageB(0, 0);
  }
  __syncthreads();

  for (int t = 0; t < 16; ++t) {
    const int buf = t & 1;
    uint4 av[2];
    if (t < 15) {
      stageB((t + 1) * 32, buf ^ 1);
      loadA((t + 1) * 32, av);
    }
    const ushort_t* ALb = &AL[buf][0];
    const ushort_t* BLb = &BL[buf][0];
    bf16x8 af[4], bfr[4];
#pragma unroll
    for (int mi2 = 0; mi2 < 4; ++mi2)
      af[mi2] = *reinterpret_cast<const bf16x8*>(ALb + (wr * 64 + mi2 * 16 + ql) * 32 + g * 8);
#pragma unroll
    for (int ni2 = 0; ni2 < 4; ++ni2)
      bfr[ni2] = *reinterpret_cast<const bf16x8*>(BLb + (wc * 64 + ni2 * 16 + ql) * 32 + g * 8);
#pragma unroll
    for (int mi2 = 0; mi2 < 4; ++mi2)
#pragma unroll
      for (int ni2 = 0; ni2 < 4; ++ni2)
        acc[mi2][ni2] = __builtin_amdgcn_mfma_f32_16x16x32_bf16(af[mi2], bfr[ni2], acc[mi2][ni2], 0, 0, 0);
    if (t < 15) writeA(buf ^ 1, av);
    __syncthreads();
  }

  const float* bias = region == 0 ? bq : (region == 1 ? bk : bv);
  const float scale = region == 0 ? CQ : 1.0f;
  const int nl0 = n0 - (region << 9);
  ushort_t* outT = region == 0 ? Qo : Ko;

  float bvv[4];
#pragma unroll
  for (int ni2 = 0; ni2 < 4; ++ni2) bvv[ni2] = bias[nl0 + wc * 64 + ni2 * 16 + ql];

#pragma unroll
  for (int mi2 = 0; mi2 < 4; ++mi2) {
#pragma unroll
    for (int ni2 = 0; ni2 < 4; ++ni2) {
      int nl = nl0 + wc * 64 + ni2 * 16 + ql;
      int h = nl >> 6, d = nl & 63;
#pragma unroll
      for (int reg = 0; reg < 4; ++reg) {
        float val = (acc[mi2][ni2][reg] + bvv[ni2]) * scale;
        int m = m0 + wr * 64 + mi2 * 16 + 4 * g + reg;
        int b = m >> 12, s = m & 4095;
        if (region <= 1) {
          outT[(((size_t)(b * NHEADS + h) * S_LEN + s) * DK) + d] = bf1(val);
        } else {
          int k6 = s & 63;
          int pos = (k6 & 32) | (((k6 >> 2) & 3) << 3) | (((k6 >> 4) & 1) << 2) | (k6 & 3);
          int sperm = (s & ~63) | pos;
          Vo[(((size_t)(b * NHEADS + h) * DK + d) * S_LEN) + sperm] = bf1(val);
        }
      }
    }
  }
}

// ---------------------------------------------------------------------------
// Fused Wo GEMM + split-combine, 64x128 tiles, 512 blocks (2/CU), XCD-grouped.
// A = (O0+O1)*rcp(l0+l1) reg-staged -> bf16 -> ds_write; B via gll16.
// ---------------------------------------------------------------------------
__global__ __launch_bounds__(256) void gemm_wo_fused(
    const ushort_t* __restrict__ Opart, const float* __restrict__ Lpart,
    const ushort_t* __restrict__ Wt, const float* __restrict__ bias,
    float* __restrict__ out) {
  __shared__ ushort_t AL[2][64 * 32];
  __shared__ ushort_t BL[2][128 * 32];
  const int tid = threadIdx.x;
  const int wid = tid >> 6;
  const int lane = tid & 63;
  const int ql = lane & 15;
  const int g = lane >> 4;
  const int wr = wid >> 1, wc = wid & 1;

  // 512 = 8 XCD x 64; within XCD: 16 m-panels x 4 n-blocks.
  const int p = blockIdx.x;
  const int L = (p & 7) * 64 + (p >> 3);
  const int m0 = (L >> 2) * 64, n0 = (L & 3) * 128;

  f32x4 acc[2][4];
#pragma unroll
  for (int i = 0; i < 2; ++i)
#pragma unroll
    for (int j = 0; j < 4; ++j) acc[i][j] = (f32x4){0.f, 0.f, 0.f, 0.f};

  const int rA = tid >> 2;          // 0..63
  const int c8 = (tid & 3) * 8;
  const int mrow = m0 + rA;
  const int bb = mrow >> 12;
  const int sA = mrow & 4095;
  const int bhbase = bb * 8;

  auto loadA = [&](int k0, uint4& av) {
    int kg = k0 + c8;
    int h = kg >> 6, d = kg & 63;
    int bh = bhbase + h;
    size_t off = ((size_t)bh * S_LEN + sA) * 64 + d;
    uint4 a0 = *reinterpret_cast<const uint4*>(Opart + off);
    uint4 a1 = *reinterpret_cast<const uint4*>(Opart + off + (size_t)16 * S_LEN * 64);
    float l = Lpart[(size_t)bh * S_LEN + sA] + Lpart[(size_t)(16 + bh) * S_LEN + sA];
    float inv = fastrcp(l);
    unsigned u0[4] = {a0.x, a0.y, a0.z, a0.w};
    unsigned u1[4] = {a1.x, a1.y, a1.z, a1.w};
    unsigned r[4];
#pragma unroll
    for (int j = 0; j < 4; ++j) {
      float e0 = (bflo(u0[j]) + bflo(u1[j])) * inv;
      float e1 = (bfhi(u0[j]) + bfhi(u1[j])) * inv;
      r[j] = packbf(e0, e1);
    }
    av.x = r[0]; av.y = r[1]; av.z = r[2]; av.w = r[3];
  };
  auto writeA = [&](int buf, uint4 av) {
    *reinterpret_cast<uint4*>(&AL[buf][tid * 8]) = av;  // = rA*32 + c8
  };
  auto stageB = [&](int k0, int buf) {
#pragma unroll
    for (int i = 0; i < 2; ++i) {
      int idx = i * 256 + tid;
      int r = idx >> 2;
      int c = (idx & 3) * 8;
      gll16(Wt + (size_t)(n0 + r) * 512 + k0 + c, &BL[buf][idx * 8]);
    }
  };

  {
    uint4 av;
    loadA(0, av);
    writeA(0, av);
    stageB(0, 0);
  }
  __syncthreads();

  for (int t = 0; t < 16; ++t) {
    const int buf = t & 1;
    uint4 av;
    if (t < 15) {
      stageB((t + 1) * 32, buf ^ 1);
      loadA((t + 1) * 32, av);
    }
    const ushort_t* ALb = &AL[buf][0];
    const ushort_t* BLb = &BL[buf][0];
    bf16x8 af[2], bfr[4];
#pragma unroll
    for (int mi = 0; mi < 2; ++mi)
      af[mi] = *reinterpret_cast<const bf16x8*>(ALb + (wr * 32 + mi * 16 + ql) * 32 + g * 8);
#pragma unroll
    for (int ni = 0; ni < 4; ++ni)
      bfr[ni] = *reinterpret_cast<const bf16x8*>(BLb + (wc * 64 + ni * 16 + ql) * 32 + g * 8);
#pragma unroll
    for (int mi = 0; mi < 2; ++mi)
#pragma unroll
      for (int ni = 0; ni < 4; ++ni)
        acc[mi][ni] = __builtin_amdgcn_mfma_f32_16x16x32_bf16(af[mi], bfr[ni], acc[mi][ni], 0, 0, 0);
    if (t < 15) writeA(buf ^ 1, av);
    __syncthreads();
  }

  float bv[4];
#pragma unroll
  for (int ni = 0; ni < 4; ++ni) bv[ni] = bias[n0 + wc * 64 + ni * 16 + ql];

#pragma unroll
  for (int mi = 0; mi < 2; ++mi) {
#pragma unroll
    for (int ni = 0; ni < 4; ++ni) {
      int n = n0 + wc * 64 + ni * 16 + ql;
#pragma unroll
      for (int reg = 0; reg < 4; ++reg) {
        int m = m0 + wr * 32 + mi * 16 + 4 * g + reg;
        out[(size_t)m * 512 + n] = acc[mi][ni][reg] + bv[ni];
      }
    }
  }
}

// ---------------------------------------------------------------------------
// Plain Wo GEMM (fallback, bf16 A): out = A @ Wt^T + bias, fp32.
// ---------------------------------------------------------------------------
__global__ __launch_bounds__(256) void gemm_wo(
    const ushort_t* __restrict__ A, const ushort_t* __restrict__ Wt,
    const float* __restrict__ bias, float* __restrict__ out) {
  __shared__ ushort_t AL[2][128 * 32];
  __shared__ ushort_t BL[2][128 * 32];
  const int tid = threadIdx.x;
  const int wid = tid >> 6;
  const int lane = tid & 63;
  const int ql = lane & 15;
  const int g = lane >> 4;
  const int wr = wid >> 1, wc = wid & 1;
  const int m0 = blockIdx.x * 128, n0 = blockIdx.y * 128;

  f32x4 acc[4][4];
#pragma unroll
  for (int i = 0; i < 4; ++i)
#pragma unroll
    for (int j = 0; j < 4; ++j) acc[i][j] = (f32x4){0.f, 0.f, 0.f, 0.f};

  auto stage = [&](int k0, int buf) {
#pragma unroll
    for (int i = 0; i < 2; ++i) {
      int idx = i * 256 + tid;
      int r = idx >> 2;
      int c = (idx & 3) * 8;
      gll16(A + (size_t)(m0 + r) * 512 + k0 + c, &AL[buf][idx * 8]);
      gll16(Wt + (size_t)(n0 + r) * 512 + k0 + c, &BL[buf][idx * 8]);
    }
  };

  stage(0, 0);
  __syncthreads();
  int buf = 0;

  for (int t = 0; t < 16; ++t) {
    if (t < 15) stage((t + 1) * 32, buf ^ 1);
    const ushort_t* ALb = &AL[buf][0];
    const ushort_t* BLb = &BL[buf][0];
    bf16x8 af[4], bfr[4];
#pragma unroll
    for (int mi = 0; mi < 4; ++mi)
      af[mi] = *reinterpret_cast<const bf16x8*>(ALb + (wr * 64 + mi * 16 + ql) * 32 + g * 8);
#pragma unroll
    for (int ni = 0; ni < 4; ++ni)
      bfr[ni] = *reinterpret_cast<const bf16x8*>(BLb + (wc * 64 + ni * 16 + ql) * 32 + g * 8);
#pragma unroll
    for (int mi = 0; mi < 4; ++mi)
#pragma unroll
      for (int ni = 0; ni < 4; ++ni)
        acc[mi][ni] = __builtin_amdgcn_mfma_f32_16x16x32_bf16(af[mi], bfr[ni], acc[mi][ni], 0, 0, 0);
    __syncthreads();
    buf ^= 1;
  }

  float bv[4];
#pragma unroll
  for (int ni = 0; ni < 4; ++ni) bv[ni] = bias[n0 + wc * 64 + ni * 16 + ql];

#pragma unroll
  for (int mi = 0; mi < 4; ++mi) {
#pragma unroll
    for (int ni = 0; ni < 4; ++ni) {
      int n = n0 + wc * 64 + ni * 16 + ql;
#pragma unroll
      for (int reg = 0; reg < 4; ++reg) {
        int m = m0 + wr * 64 + mi * 16 + 4 * g + reg;
        out[(size_t)m * 512 + n] = acc[mi][ni][reg] + bv[ni];
      }
    }
  }
}

// ---------------------------------------------------------------------------
// MFMA flash attention, no-max softmax, 8 waves/block (256 q), 32 q/wave.
// 128-key tiles as 2x 64-key sub-buffers: ONE barrier per 128 keys (half the
// barrier/drain overhead) while reusing all verified 64-key offset math.
// V pre-permuted (single b128 PV fragments), cvt_pk, bf16 partials.
// ---------------------------------------------------------------------------
template <bool SPLIT2>
__global__ __launch_bounds__(512, 2) void attn_mfma(
    const ushort_t* __restrict__ Q, const ushort_t* __restrict__ K,
    const ushort_t* __restrict__ Vt, ushort_t* __restrict__ AO,
    ushort_t* __restrict__ Opart, float* __restrict__ Lpart) {
  // [buf][sub][64 rows x 64 cols]
  __shared__ ushort_t KL[2][2][64 * 64];
  __shared__ ushort_t VL[2][2][64 * 64];

  const int tid = threadIdx.x;
  const int wid = tid >> 6;   // 0..7
  const int lane = tid & 63;
  const int g = lane >> 4;
  const int ql = lane & 15;

  // XCD-aware remap: 512 blocks = 8 XCD x 64 (16 qt x 4 bhsp each).
  int L;
  if (SPLIT2) {
    int orig = blockIdx.x;
    L = (orig & 7) * 64 + (orig >> 3);
  } else {
    L = blockIdx.x;
  }
  const int qt = L & 15;
  const int bhsp = L >> 4;
  const int sp = SPLIT2 ? (bhsp & 1) : 0;
  const int bh = SPLIT2 ? (bhsp >> 1) : bhsp;
  const int NT = SPLIT2 ? 16 : 32;        // 128-key tiles
  const int key0 = SPLIT2 ? sp * 2048 : 0;

  const ushort_t* Qb = Q + (size_t)bh * S_LEN * DK;
  const ushort_t* Kb = K + (size_t)bh * S_LEN * DK;
  const ushort_t* Vb = Vt + (size_t)bh * DK * S_LEN;

  const int qbase = qt * 256 + wid * 32;

  bf16x8 qf[2][2];
#pragma unroll
  for (int c = 0; c < 2; ++c) {
    int q = qbase + c * 16 + ql;
#pragma unroll
    for (int t = 0; t < 2; ++t)
      qf[c][t] = *reinterpret_cast<const bf16x8*>(Qb + (size_t)q * DK + t * 32 + g * 8);
  }

  bf16x8 ones;
#pragma unroll
  for (int j = 0; j < 8; ++j) ones[j] = (short)0x3F80;

  f32x4 ot[4][2];
#pragma unroll
  for (int db = 0; db < 4; ++db)
#pragma unroll
    for (int c = 0; c < 2; ++c) ot[db][c] = (f32x4){0.f, 0.f, 0.f, 0.f};
  f32x4 lacc[2];
  lacc[0] = (f32x4){0.f, 0.f, 0.f, 0.f};
  lacc[1] = (f32x4){0.f, 0.f, 0.f, 0.f};

  // ---- staging: 8 waves x 8 rows per sub-tile ----
  const int srow = lane >> 3;
  const int schk = lane & 7;
  const int r0 = wid * 8 + srow;        // 0..63
  const int ssc = (schk ^ srow) << 4;   // r0&7 == srow

  // K: sub0 = keys [0,64), sub1 = keys [64,128) of the 128-key tile
  const char* gk0 = (const char*)Kb + ((size_t)(key0 + r0)) * 128 + ssc;
  const char* gk1 = gk0 + 64 * 128;
  // V^T rows are d (0..63); sub advances 64 keys = 128 B along the row
  const char* gv0 = (const char*)Vb + (size_t)r0 * (S_LEN * 2) + (size_t)key0 * 2 + ssc;
  const char* gv1 = gv0 + 128;

  char* lkBase = (char*)&KL[0][0][0] + (wid * 8) * 128 + lane * 16;
  char* lvBase = (char*)&VL[0][0][0] + (wid * 8) * 128 + lane * 16;
  // strides: buf = 16384 B, sub = 8192 B

  int koA[4], koB[4];
#pragma unroll
  for (int kb = 0; kb < 4; ++kb) {
    int r = kb * 16 + ql;
    koA[kb] = r * 128 + (((g) ^ (r & 7)) << 4);
    koB[kb] = r * 128 + (((g + 4) ^ (r & 7)) << 4);
  }
  int voP[2][4];
#pragma unroll
  for (int t = 0; t < 2; ++t)
#pragma unroll
    for (int db = 0; db < 4; ++db) {
      int rd = db * 16 + ql;
      voP[t][db] = rd * 128 + (((t * 4 + g) ^ (rd & 7)) << 4);
    }

  // prologue: stage 128-key tile 0 into buf0
  gll16(gk0, lkBase);           gll16(gk1, lkBase + 8192);
  gll16(gv0, lvBase);           gll16(gv1, lvBase + 8192);
  gk0 += 16384; gk1 += 16384; gv0 += 256; gv1 += 256;
  __syncthreads();

  // one 64-key sub-tile: QK -> exp -> PV (no barrier)
  auto half = [&](const char* KB, const char* VB) {
    f32x4 st[4][2];
    __builtin_amdgcn_s_setprio(1);
#pragma unroll
    for (int kb = 0; kb < 4; ++kb) {
      bf16x8 k0 = *reinterpret_cast<const bf16x8*>(KB + koA[kb]);
      bf16x8 k1 = *reinterpret_cast<const bf16x8*>(KB + koB[kb]);
#pragma unroll
      for (int c = 0; c < 2; ++c) {
        f32x4 z = (f32x4){0.f, 0.f, 0.f, 0.f};
        z = __builtin_amdgcn_mfma_f32_16x16x32_bf16(k0, qf[c][0], z, 0, 0, 0);
        z = __builtin_amdgcn_mfma_f32_16x16x32_bf16(k1, qf[c][1], z, 0, 0, 0);
        st[kb][c] = z;
      }
    }
    __builtin_amdgcn_s_setprio(0);

    unsigned pk[2][4][2];
#pragma unroll
    for (int c = 0; c < 2; ++c)
#pragma unroll
      for (int kb = 0; kb < 4; ++kb)
#pragma unroll
        for (int r2 = 0; r2 < 2; ++r2) {
          float pa = __builtin_amdgcn_exp2f(st[kb][c][2 * r2]);
          float pb_ = __builtin_amdgcn_exp2f(st[kb][c][2 * r2 + 1]);
          pk[c][kb][r2] = packbf(pa, pb_);
        }

    __builtin_amdgcn_s_setprio(1);
#pragma unroll
    for (int t = 0; t < 2; ++t) {
      union { unsigned u[4]; bf16x8 v; } pb0, pb1;
      pb0.u[0] = pk[0][2 * t][0];     pb0.u[1] = pk[0][2 * t][1];
      pb0.u[2] = pk[0][2 * t + 1][0]; pb0.u[3] = pk[0][2 * t + 1][1];
      pb1.u[0] = pk[1][2 * t][0];     pb1.u[1] = pk[1][2 * t][1];
      pb1.u[2] = pk[1][2 * t + 1][0]; pb1.u[3] = pk[1][2 * t + 1][1];
#pragma unroll
      for (int db = 0; db < 4; ++db) {
        bf16x8 af = *reinterpret_cast<const bf16x8*>(VB + voP[t][db]);
        ot[db][0] = __builtin_amdgcn_mfma_f32_16x16x32_bf16(af, pb0.v, ot[db][0], 0, 0, 0);
        ot[db][1] = __builtin_amdgcn_mfma_f32_16x16x32_bf16(af, pb1.v, ot[db][1], 0, 0, 0);
      }
      lacc[0] = __builtin_amdgcn_mfma_f32_16x16x32_bf16(ones, pb0.v, lacc[0], 0, 0, 0);
      lacc[1] = __builtin_amdgcn_mfma_f32_16x16x32_bf16(ones, pb1.v, lacc[1], 0, 0, 0);
    }
    __builtin_amdgcn_s_setprio(0);
  };

  // one 128-key tile: prefetch next tile, both halves, ONE barrier
  auto body = [&](const char* KB, const char* VB, char* dk, char* dv, bool pref) {
    if (pref) {
      gll16(gk0, dk);           gll16(gk1, dk + 8192);
      gll16(gv0, dv);           gll16(gv1, dv + 8192);
      gk0 += 16384; gk1 += 16384; gv0 += 256; gv1 += 256;
    }
    half(KB, VB);
    half(KB + 8192, VB + 8192);
    __syncthreads();
  };

  const char* KB0 = (const char*)&KL[0][0][0];
  const char* VB0 = (const char*)&VL[0][0][0];
  const char* KB1 = KB0 + 16384;
  const char* VB1 = VB0 + 16384;

  for (int it = 0; it < NT; it += 2) {
    body(KB0, VB0, lkBase + 16384, lvBase + 16384, true);
    body(KB1, VB1, lkBase, lvBase, it + 2 < NT);
  }

  if (SPLIT2) {
    ushort_t* Ob = Opart + (((size_t)sp * 16 + bh) * S_LEN) * 64;
#pragma unroll
    for (int c = 0; c < 2; ++c) {
      const int q = qbase + c * 16 + ql;
#pragma unroll
      for (int db = 0; db < 4; ++db) {
        uint2 o;
        o.x = packbf(ot[db][c][0], ot[db][c][1]);
        o.y = packbf(ot[db][c][2], ot[db][c][3]);
        *reinterpret_cast<uint2*>(Ob + (size_t)q * 64 + db * 16 + 4 * g) = o;
      }
      if (g == 0) Lpart[((size_t)sp * 16 + bh) * S_LEN + q] = lacc[c][0];
    }
  } else {
    const int b = bh >> 3, h = bh & 7;
#pragma unroll
    for (int c = 0; c < 2; ++c) {
      const int q = qbase + c * 16 + ql;
      float inv = 1.f / lacc[c][0];
#pragma unroll
      for (int db = 0; db < 4; ++db) {
        uint2 o;
        o.x = packbf(ot[db][c][0] * inv, ot[db][c][1] * inv);
        o.y = packbf(ot[db][c][2] * inv, ot[db][c][3] * inv);
        *reinterpret_cast<uint2*>(AO + ((size_t)b * S_LEN + q) * DMODEL + h * DK + db * 16 + g * 4) = o;
      }
    }
  }
}

extern "C" void kernel_launch(void* const* d_in, const int* in_sizes, int n_in,
                              void* d_out, int out_size, void* d_ws, size_t ws_size,
                              hipStream_t stream) {
  const float* x  = (const float*)d_in[0];
  const float* Wq = (const float*)d_in[1];
  const float* bq = (const float*)d_in[2];
  const float* Wk = (const float*)d_in[3];
  const float* bk = (const float*)d_in[4];
  const float* Wv = (const float*)d_in[5];
  const float* bv = (const float*)d_in[6];
  const float* Wo = (const float*)d_in[7];
  const float* bo = (const float*)d_in[8];
  float* out = (float*)d_out;

  const float CQ = 0.18033688f;  // 0.125 * log2(e)

  char* ws = (char*)d_ws;
  const size_t NBF = (size_t)MROWS * DMODEL;  // 4 Mi elements
  ushort_t* AObuf = (ushort_t*)ws;            // 8MB (fallback AO)
  ushort_t* Qbf = (ushort_t*)(ws + NBF * 2);
  ushort_t* Kbf = (ushort_t*)(ws + NBF * 4);
  ushort_t* Vtb = (ushort_t*)(ws + NBF * 6);

  const size_t OFF_WT    = NBF * 8;
  const size_t OFF_LPART = OFF_WT + 4 * 512 * 512 * 2;
  const size_t OFF_OPART = OFF_LPART + 512 * 1024;
  const size_t NEED_SPLIT = OFF_OPART + (size_t)2 * 16 * S_LEN * 64 * 2;  // bf16 partials
  const bool use_split = ws_size >= NEED_SPLIT;

  ushort_t* Wcat;
  if (use_split) {
    Wcat = (ushort_t*)(ws + OFF_WT);
  } else {
    Wcat = (ushort_t*)(ws + NBF * 10);
  }
  ushort_t* Wot = Wcat + 3 * 512 * 512;
  float* Lpart = (float*)(ws + OFF_LPART);
  ushort_t* Opart = (ushort_t*)(ws + OFF_OPART);

  prep<<<1024, 256, 0, stream>>>(Wq, Wk, Wv, Wo, Wcat, Wot);

  gemm_qkv<<<768, 256, 0, stream>>>(x, Wcat, bq, bk, bv, Qbf, Kbf, Vtb, CQ);

  if (use_split) {
    attn_mfma<true><<<512, 512, 0, stream>>>(Qbf, Kbf, Vtb, AObuf, Opart, Lpart);
    gemm_wo_fused<<<512, 256, 0, stream>>>(Opart, Lpart, Wot, bo, out);
  } else {
    attn_mfma<false><<<256, 512, 0, stream>>>(Qbf, Kbf, Vtb, AObuf, Opart, Lpart);
    dim3 gg(MROWS / 128, DMODEL / 128);
    gemm_wo<<<gg, 256, 0, stream>>>(AObuf, Wot, bo, out);
  }
}

// Round 13
// 115.583 us; speedup vs baseline: 13.7724x; 1.0026x over previous
//
#include <hip/hip_runtime.h>
#include <hip/hip_bf16.h>

#define S_LEN 4096
#define DMODEL 512
#define NHEADS 8
#define DK 64
#define BATCH 2
#define MROWS (BATCH * S_LEN)  // 8192

typedef __attribute__((ext_vector_type(8))) short bf16x8;
typedef __attribute__((ext_vector_type(4))) float f32x4;
typedef unsigned short ushort_t;

// single-instruction pack: low16 = bf16(a), high16 = bf16(b), RNE
__device__ __forceinline__ unsigned packbf(float a, float b) {
  unsigned r;
  asm("v_cvt_pk_bf16_f32 %0, %1, %2" : "=v"(r) : "v"(a), "v"(b));
  return r;
}

__device__ __forceinline__ unsigned short bf1(float a) {
  union { __hip_bfloat16 h; unsigned short s; } u;
  u.h = __float2bfloat16(a);
  return u.s;
}

__device__ __forceinline__ float bflo(unsigned u) { return __uint_as_float(u << 16); }
__device__ __forceinline__ float bfhi(unsigned u) { return __uint_as_float(u & 0xFFFF0000u); }

__device__ __forceinline__ float fastrcp(float x) {
  float r;
  asm("v_rcp_f32 %0, %1" : "=v"(r) : "v"(x));
  return r;
}

__device__ __forceinline__ void gll16(const void* g, void* l) {
  __builtin_amdgcn_global_load_lds(
      (const __attribute__((address_space(1))) unsigned*)g,
      (__attribute__((address_space(3))) unsigned*)l, 16, 0, 0);
}

// ---------------------------------------------------------------------------
// Prep: transpose the 4 weights fp32 (k,n) -> bf16 (n,k). 1024 blocks.
// ---------------------------------------------------------------------------
__global__ __launch_bounds__(256) void prep(
    const float* __restrict__ Wq, const float* __restrict__ Wk,
    const float* __restrict__ Wv, const float* __restrict__ Wo,
    ushort_t* __restrict__ Wcat, ushort_t* __restrict__ Wot) {
  __shared__ float T[32][33];
  const int bid = blockIdx.x;
  const int tid = threadIdx.x;
  int w = bid >> 8;
  int tile = bid & 255;
  int k0 = (tile & 15) * 32, n0 = (tile >> 4) * 32;
  const float* W = w == 0 ? Wq : (w == 1 ? Wk : (w == 2 ? Wv : Wo));
  ushort_t* out = (w == 3) ? Wot : (Wcat + (size_t)w * 512 * 512);
  const int r = tid >> 3, c4 = (tid & 7) * 4;
  float4 v = *reinterpret_cast<const float4*>(W + (size_t)(k0 + r) * 512 + n0 + c4);
  T[r][c4 + 0] = v.x; T[r][c4 + 1] = v.y; T[r][c4 + 2] = v.z; T[r][c4 + 3] = v.w;
  __syncthreads();
  uint2 o;
  o.x = packbf(T[c4 + 0][r], T[c4 + 1][r]);
  o.y = packbf(T[c4 + 2][r], T[c4 + 3][r]);
  *reinterpret_cast<uint2*>(out + (size_t)(n0 + r) * 512 + k0 + c4) = o;
}

// ---------------------------------------------------------------------------
// Fused QKV GEMM: [Q|K|V] = x[8192,512](fp32, reg-staged->bf16) @ Wcat^T + b
// Flat grid 768, XCD grouping. Q scaled by CQ. Q,K -> [B,H,S,DK];
// V -> [B,H,DK,S] with within-64-key-tile permuted s order.
// Epilogue v2: Q/K via LDS-transposed 128B-coalesced uint4 stores (staging
// LDS overlaid); V via packed uint2 (pos() is identity on low 2 bits).
// ---------------------------------------------------------------------------
__global__ __launch_bounds__(256) void gemm_qkv(
    const float* __restrict__ x, const ushort_t* __restrict__ Wcat,
    const float* __restrict__ bq, const float* __restrict__ bk,
    const float* __restrict__ bv, ushort_t* __restrict__ Qo,
    ushort_t* __restrict__ Ko, ushort_t* __restrict__ Vo, float CQ) {
  __shared__ __align__(16) ushort_t SM[4][128 * 32];  // AL=SM[0..1], BL=SM[2..3]; EP overlay
  const int tid = threadIdx.x;
  const int wid = tid >> 6;
  const int lane = tid & 63;
  const int ql = lane & 15;
  const int g = lane >> 4;
  const int wr = wid >> 1, wc = wid & 1;

  // XCD grouping: 768 = 8 XCD x 96; within XCD: 8 m-panels x 12 n-blocks.
  const int p = blockIdx.x;
  const int xcd = p & 7, q_ = p >> 3;
  const int mi = xcd * 8 + q_ / 12;
  const int ni = q_ % 12;
  const int m0 = mi * 128, n0 = ni * 128;
  const int region = n0 >> 9;  // 0=Q 1=K 2=V

  f32x4 acc[4][4];
#pragma unroll
  for (int i = 0; i < 4; ++i)
#pragma unroll
    for (int j = 0; j < 4; ++j) acc[i][j] = (f32x4){0.f, 0.f, 0.f, 0.f};

  auto loadA = [&](int k0, uint4 av[2]) {
#pragma unroll
    for (int i = 0; i < 2; ++i) {
      int idx = i * 256 + tid;
      int r = idx >> 2;
      int c = (idx & 3) * 8;
      const float* src = x + (size_t)(m0 + r) * 512 + k0 + c;
      float4 a = *reinterpret_cast<const float4*>(src);
      float4 b = *reinterpret_cast<const float4*>(src + 4);
      av[i].x = packbf(a.x, a.y);
      av[i].y = packbf(a.z, a.w);
      av[i].z = packbf(b.x, b.y);
      av[i].w = packbf(b.z, b.w);
    }
  };
  auto writeA = [&](int buf, uint4 av[2]) {
#pragma unroll
    for (int i = 0; i < 2; ++i) {
      int idx = i * 256 + tid;
      *reinterpret_cast<uint4*>(&SM[buf][idx * 8]) = av[i];
    }
  };
  auto stageB = [&](int k0, int buf) {
#pragma unroll
    for (int i = 0; i < 2; ++i) {
      int idx = i * 256 + tid;
      int r = idx >> 2;
      int c = (idx & 3) * 8;
      gll16(Wcat + (size_t)(n0 + r) * 512 + k0 + c, &SM[2 + buf][idx * 8]);
    }
  };

  {
    uint4 av[2];
    loadA(0, av);
    writeA(0, av);
    stageB(0, 0);
  }
  __syncthreads();

  for (int t = 0; t < 16; ++t) {
    const int buf = t & 1;
    uint4 av[2];
    if (t < 15) {
      stageB((t + 1) * 32, buf ^ 1);
      loadA((t + 1) * 32, av);
    }
    const ushort_t* ALb = &SM[buf][0];
    const ushort_t* BLb = &SM[2 + buf][0];
    bf16x8 af[4], bfr[4];
#pragma unroll
    for (int mi2 = 0; mi2 < 4; ++mi2)
      af[mi2] = *reinterpret_cast<const bf16x8*>(ALb + (wr * 64 + mi2 * 16 + ql) * 32 + g * 8);
#pragma unroll
    for (int ni2 = 0; ni2 < 4; ++ni2)
      bfr[ni2] = *reinterpret_cast<const bf16x8*>(BLb + (wc * 64 + ni2 * 16 + ql) * 32 + g * 8);
#pragma unroll
    for (int mi2 = 0; mi2 < 4; ++mi2)
#pragma unroll
      for (int ni2 = 0; ni2 < 4; ++ni2)
        acc[mi2][ni2] = __builtin_amdgcn_mfma_f32_16x16x32_bf16(af[mi2], bfr[ni2], acc[mi2][ni2], 0, 0, 0);
    if (t < 15) writeA(buf ^ 1, av);
    __syncthreads();
  }

  const float* bias = region == 0 ? bq : (region == 1 ? bk : bv);
  const float scale = region == 0 ? CQ : 1.0f;
  const int nl0 = n0 - (region << 9);

  float bvv[4];
#pragma unroll
  for (int ni2 = 0; ni2 < 4; ++ni2) bvv[ni2] = bias[nl0 + wc * 64 + ni2 * 16 + ql];

  if (region <= 1) {
    // ---- Q/K: stash bf16 C-tile in LDS [128 m][128 n], read back coalesced
    ushort_t* EP = &SM[0][0];  // 32 KB overlay (staging dead after final barrier)
#pragma unroll
    for (int mi2 = 0; mi2 < 4; ++mi2) {
#pragma unroll
      for (int ni2 = 0; ni2 < 4; ++ni2) {
        int n = wc * 64 + ni2 * 16 + ql;
#pragma unroll
        for (int reg = 0; reg < 4; ++reg) {
          int m = wr * 64 + mi2 * 16 + 4 * g + reg;
          EP[m * 128 + n] = bf1((acc[mi2][ni2][reg] + bvv[ni2]) * scale);
        }
      }
    }
    __syncthreads();
    ushort_t* outT = region == 0 ? Qo : Ko;
    const int hb = nl0 >> 6;  // first head of this n-block (n-block = 2 heads)
#pragma unroll
    for (int j = 0; j < 8; ++j) {
      int idx = j * 256 + tid;
      int row = idx >> 4;       // 0..127
      int chunk = idx & 15;     // 16B chunk: n = chunk*8..chunk*8+7
      uint4 v = *reinterpret_cast<const uint4*>(&EP[row * 128 + chunk * 8]);
      int h = hb + (chunk >> 3);
      int d = (chunk & 7) * 8;
      int m = m0 + row;
      int b = m >> 12, s = m & 4095;
      *reinterpret_cast<uint4*>(&outT[(((size_t)(b * NHEADS + h) * S_LEN + s) * DK) + d]) = v;
    }
  } else {
    // ---- V: packed uint2 stores; pos() identity on low 2 bits -> 4
    // consecutive regs = 4 consecutive sperm.
#pragma unroll
    for (int mi2 = 0; mi2 < 4; ++mi2) {
#pragma unroll
      for (int ni2 = 0; ni2 < 4; ++ni2) {
        int nl = nl0 + wc * 64 + ni2 * 16 + ql;
        int h = nl >> 6, d = nl & 63;
        int m = m0 + wr * 64 + mi2 * 16 + 4 * g;  // aligned to 4
        int b = m >> 12, s = m & 4095;
        int k6 = s & 63;
        int pos = (k6 & 32) | (((k6 >> 2) & 3) << 3) | (((k6 >> 4) & 1) << 2);
        int sperm = (s & ~63) | pos;  // + reg via contiguity
        uint2 o;
        o.x = packbf(acc[mi2][ni2][0] + bvv[ni2], acc[mi2][ni2][1] + bvv[ni2]);
        o.y = packbf(acc[mi2][ni2][2] + bvv[ni2], acc[mi2][ni2][3] + bvv[ni2]);
        *reinterpret_cast<uint2*>(&Vo[(((size_t)(b * NHEADS + h) * DK + d) * S_LEN) + sperm]) = o;
      }
    }
  }
}

// ---------------------------------------------------------------------------
// Fused Wo GEMM + split-combine, 64x128 tiles, 512 blocks (2/CU), XCD-grouped.
// A = (O0+O1)*rcp(l0+l1) reg-staged -> bf16 -> ds_write; B via gll16.
// ---------------------------------------------------------------------------
__global__ __launch_bounds__(256) void gemm_wo_fused(
    const ushort_t* __restrict__ Opart, const float* __restrict__ Lpart,
    const ushort_t* __restrict__ Wt, const float* __restrict__ bias,
    float* __restrict__ out) {
  __shared__ ushort_t AL[2][64 * 32];
  __shared__ ushort_t BL[2][128 * 32];
  const int tid = threadIdx.x;
  const int wid = tid >> 6;
  const int lane = tid & 63;
  const int ql = lane & 15;
  const int g = lane >> 4;
  const int wr = wid >> 1, wc = wid & 1;

  // 512 = 8 XCD x 64; within XCD: 16 m-panels x 4 n-blocks.
  const int p = blockIdx.x;
  const int L = (p & 7) * 64 + (p >> 3);
  const int m0 = (L >> 2) * 64, n0 = (L & 3) * 128;

  f32x4 acc[2][4];
#pragma unroll
  for (int i = 0; i < 2; ++i)
#pragma unroll
    for (int j = 0; j < 4; ++j) acc[i][j] = (f32x4){0.f, 0.f, 0.f, 0.f};

  const int rA = tid >> 2;          // 0..63
  const int c8 = (tid & 3) * 8;
  const int mrow = m0 + rA;
  const int bb = mrow >> 12;
  const int sA = mrow & 4095;
  const int bhbase = bb * 8;

  auto loadA = [&](int k0, uint4& av) {
    int kg = k0 + c8;
    int h = kg >> 6, d = kg & 63;
    int bh = bhbase + h;
    size_t off = ((size_t)bh * S_LEN + sA) * 64 + d;
    uint4 a0 = *reinterpret_cast<const uint4*>(Opart + off);
    uint4 a1 = *reinterpret_cast<const uint4*>(Opart + off + (size_t)16 * S_LEN * 64);
    float l = Lpart[(size_t)bh * S_LEN + sA] + Lpart[(size_t)(16 + bh) * S_LEN + sA];
    float inv = fastrcp(l);
    unsigned u0[4] = {a0.x, a0.y, a0.z, a0.w};
    unsigned u1[4] = {a1.x, a1.y, a1.z, a1.w};
    unsigned r[4];
#pragma unroll
    for (int j = 0; j < 4; ++j) {
      float e0 = (bflo(u0[j]) + bflo(u1[j])) * inv;
      float e1 = (bfhi(u0[j]) + bfhi(u1[j])) * inv;
      r[j] = packbf(e0, e1);
    }
    av.x = r[0]; av.y = r[1]; av.z = r[2]; av.w = r[3];
  };
  auto writeA = [&](int buf, uint4 av) {
    *reinterpret_cast<uint4*>(&AL[buf][tid * 8]) = av;  // = rA*32 + c8
  };
  auto stageB = [&](int k0, int buf) {
#pragma unroll
    for (int i = 0; i < 2; ++i) {
      int idx = i * 256 + tid;
      int r = idx >> 2;
      int c = (idx & 3) * 8;
      gll16(Wt + (size_t)(n0 + r) * 512 + k0 + c, &BL[buf][idx * 8]);
    }
  };

  {
    uint4 av;
    loadA(0, av);
    writeA(0, av);
    stageB(0, 0);
  }
  __syncthreads();

  for (int t = 0; t < 16; ++t) {
    const int buf = t & 1;
    uint4 av;
    if (t < 15) {
      stageB((t + 1) * 32, buf ^ 1);
      loadA((t + 1) * 32, av);
    }
    const ushort_t* ALb = &AL[buf][0];
    const ushort_t* BLb = &BL[buf][0];
    bf16x8 af[2], bfr[4];
#pragma unroll
    for (int mi = 0; mi < 2; ++mi)
      af[mi] = *reinterpret_cast<const bf16x8*>(ALb + (wr * 32 + mi * 16 + ql) * 32 + g * 8);
#pragma unroll
    for (int ni = 0; ni < 4; ++ni)
      bfr[ni] = *reinterpret_cast<const bf16x8*>(BLb + (wc * 64 + ni * 16 + ql) * 32 + g * 8);
#pragma unroll
    for (int mi = 0; mi < 2; ++mi)
#pragma unroll
      for (int ni = 0; ni < 4; ++ni)
        acc[mi][ni] = __builtin_amdgcn_mfma_f32_16x16x32_bf16(af[mi], bfr[ni], acc[mi][ni], 0, 0, 0);
    if (t < 15) writeA(buf ^ 1, av);
    __syncthreads();
  }

  float bv[4];
#pragma unroll
  for (int ni = 0; ni < 4; ++ni) bv[ni] = bias[n0 + wc * 64 + ni * 16 + ql];

#pragma unroll
  for (int mi = 0; mi < 2; ++mi) {
#pragma unroll
    for (int ni = 0; ni < 4; ++ni) {
      int n = n0 + wc * 64 + ni * 16 + ql;
#pragma unroll
      for (int reg = 0; reg < 4; ++reg) {
        int m = m0 + wr * 32 + mi * 16 + 4 * g + reg;
        out[(size_t)m * 512 + n] = acc[mi][ni][reg] + bv[ni];
      }
    }
  }
}

// ---------------------------------------------------------------------------
// Plain Wo GEMM (fallback, bf16 A): out = A @ Wt^T + bias, fp32.
// ---------------------------------------------------------------------------
__global__ __launch_bounds__(256) void gemm_wo(
    const ushort_t* __restrict__ A, const ushort_t* __restrict__ Wt,
    const float* __restrict__ bias, float* __restrict__ out) {
  __shared__ ushort_t AL[2][128 * 32];
  __shared__ ushort_t BL[2][128 * 32];
  const int tid = threadIdx.x;
  const int wid = tid >> 6;
  const int lane = tid & 63;
  const int ql = lane & 15;
  const int g = lane >> 4;
  const int wr = wid >> 1, wc = wid & 1;
  const int m0 = blockIdx.x * 128, n0 = blockIdx.y * 128;

  f32x4 acc[4][4];
#pragma unroll
  for (int i = 0; i < 4; ++i)
#pragma unroll
    for (int j = 0; j < 4; ++j) acc[i][j] = (f32x4){0.f, 0.f, 0.f, 0.f};

  auto stage = [&](int k0, int buf) {
#pragma unroll
    for (int i = 0; i < 2; ++i) {
      int idx = i * 256 + tid;
      int r = idx >> 2;
      int c = (idx & 3) * 8;
      gll16(A + (size_t)(m0 + r) * 512 + k0 + c, &AL[buf][idx * 8]);
      gll16(Wt + (size_t)(n0 + r) * 512 + k0 + c, &BL[buf][idx * 8]);
    }
  };

  stage(0, 0);
  __syncthreads();
  int buf = 0;

  for (int t = 0; t < 16; ++t) {
    if (t < 15) stage((t + 1) * 32, buf ^ 1);
    const ushort_t* ALb = &AL[buf][0];
    const ushort_t* BLb = &BL[buf][0];
    bf16x8 af[4], bfr[4];
#pragma unroll
    for (int mi = 0; mi < 4; ++mi)
      af[mi] = *reinterpret_cast<const bf16x8*>(ALb + (wr * 64 + mi * 16 + ql) * 32 + g * 8);
#pragma unroll
    for (int ni = 0; ni < 4; ++ni)
      bfr[ni] = *reinterpret_cast<const bf16x8*>(BLb + (wc * 64 + ni * 16 + ql) * 32 + g * 8);
#pragma unroll
    for (int mi = 0; mi < 4; ++mi)
#pragma unroll
      for (int ni = 0; ni < 4; ++ni)
        acc[mi][ni] = __builtin_amdgcn_mfma_f32_16x16x32_bf16(af[mi], bfr[ni], acc[mi][ni], 0, 0, 0);
    __syncthreads();
    buf ^= 1;
  }

  float bv[4];
#pragma unroll
  for (int ni = 0; ni < 4; ++ni) bv[ni] = bias[n0 + wc * 64 + ni * 16 + ql];

#pragma unroll
  for (int mi = 0; mi < 4; ++mi) {
#pragma unroll
    for (int ni = 0; ni < 4; ++ni) {
      int n = n0 + wc * 64 + ni * 16 + ql;
#pragma unroll
      for (int reg = 0; reg < 4; ++reg) {
        int m = m0 + wr * 64 + mi * 16 + 4 * g + reg;
        out[(size_t)m * 512 + n] = acc[mi][ni][reg] + bv[ni];
      }
    }
  }
}

// ---------------------------------------------------------------------------
// MFMA flash attention, no-max softmax, 8 waves/block (256 q), 32 q/wave.
// 128-key tiles as 2x 64-key sub-buffers: ONE barrier per 128 keys.
// V pre-permuted (single b128 PV fragments), cvt_pk, bf16 partials.
// ---------------------------------------------------------------------------
template <bool SPLIT2>
__global__ __launch_bounds__(512, 2) void attn_mfma(
    const ushort_t* __restrict__ Q, const ushort_t* __restrict__ K,
    const ushort_t* __restrict__ Vt, ushort_t* __restrict__ AO,
    ushort_t* __restrict__ Opart, float* __restrict__ Lpart) {
  // [buf][sub][64 rows x 64 cols]
  __shared__ ushort_t KL[2][2][64 * 64];
  __shared__ ushort_t VL[2][2][64 * 64];

  const int tid = threadIdx.x;
  const int wid = tid >> 6;   // 0..7
  const int lane = tid & 63;
  const int g = lane >> 4;
  const int ql = lane & 15;

  // XCD-aware remap: 512 blocks = 8 XCD x 64 (16 qt x 4 bhsp each).
  int L;
  if (SPLIT2) {
    int orig = blockIdx.x;
    L = (orig & 7) * 64 + (orig >> 3);
  } else {
    L = blockIdx.x;
  }
  const int qt = L & 15;
  const int bhsp = L >> 4;
  const int sp = SPLIT2 ? (bhsp & 1) : 0;
  const int bh = SPLIT2 ? (bhsp >> 1) : bhsp;
  const int NT = SPLIT2 ? 16 : 32;        // 128-key tiles
  const int key0 = SPLIT2 ? sp * 2048 : 0;

  const ushort_t* Qb = Q + (size_t)bh * S_LEN * DK;
  const ushort_t* Kb = K + (size_t)bh * S_LEN * DK;
  const ushort_t* Vb = Vt + (size_t)bh * DK * S_LEN;

  const int qbase = qt * 256 + wid * 32;

  bf16x8 qf[2][2];
#pragma unroll
  for (int c = 0; c < 2; ++c) {
    int q = qbase + c * 16 + ql;
#pragma unroll
    for (int t = 0; t < 2; ++t)
      qf[c][t] = *reinterpret_cast<const bf16x8*>(Qb + (size_t)q * DK + t * 32 + g * 8);
  }

  bf16x8 ones;
#pragma unroll
  for (int j = 0; j < 8; ++j) ones[j] = (short)0x3F80;

  f32x4 ot[4][2];
#pragma unroll
  for (int db = 0; db < 4; ++db)
#pragma unroll
    for (int c = 0; c < 2; ++c) ot[db][c] = (f32x4){0.f, 0.f, 0.f, 0.f};
  f32x4 lacc[2];
  lacc[0] = (f32x4){0.f, 0.f, 0.f, 0.f};
  lacc[1] = (f32x4){0.f, 0.f, 0.f, 0.f};

  // ---- staging: 8 waves x 8 rows per sub-tile ----
  const int srow = lane >> 3;
  const int schk = lane & 7;
  const int r0 = wid * 8 + srow;        // 0..63
  const int ssc = (schk ^ srow) << 4;   // r0&7 == srow

  const char* gk0 = (const char*)Kb + ((size_t)(key0 + r0)) * 128 + ssc;
  const char* gk1 = gk0 + 64 * 128;
  const char* gv0 = (const char*)Vb + (size_t)r0 * (S_LEN * 2) + (size_t)key0 * 2 + ssc;
  const char* gv1 = gv0 + 128;

  char* lkBase = (char*)&KL[0][0][0] + (wid * 8) * 128 + lane * 16;
  char* lvBase = (char*)&VL[0][0][0] + (wid * 8) * 128 + lane * 16;

  int koA[4], koB[4];
#pragma unroll
  for (int kb = 0; kb < 4; ++kb) {
    int r = kb * 16 + ql;
    koA[kb] = r * 128 + (((g) ^ (r & 7)) << 4);
    koB[kb] = r * 128 + (((g + 4) ^ (r & 7)) << 4);
  }
  int voP[2][4];
#pragma unroll
  for (int t = 0; t < 2; ++t)
#pragma unroll
    for (int db = 0; db < 4; ++db) {
      int rd = db * 16 + ql;
      voP[t][db] = rd * 128 + (((t * 4 + g) ^ (rd & 7)) << 4);
    }

  // prologue: stage 128-key tile 0 into buf0
  gll16(gk0, lkBase);           gll16(gk1, lkBase + 8192);
  gll16(gv0, lvBase);           gll16(gv1, lvBase + 8192);
  gk0 += 16384; gk1 += 16384; gv0 += 256; gv1 += 256;
  __syncthreads();

  auto half = [&](const char* KB, const char* VB) {
    f32x4 st[4][2];
    __builtin_amdgcn_s_setprio(1);
#pragma unroll
    for (int kb = 0; kb < 4; ++kb) {
      bf16x8 k0 = *reinterpret_cast<const bf16x8*>(KB + koA[kb]);
      bf16x8 k1 = *reinterpret_cast<const bf16x8*>(KB + koB[kb]);
#pragma unroll
      for (int c = 0; c < 2; ++c) {
        f32x4 z = (f32x4){0.f, 0.f, 0.f, 0.f};
        z = __builtin_amdgcn_mfma_f32_16x16x32_bf16(k0, qf[c][0], z, 0, 0, 0);
        z = __builtin_amdgcn_mfma_f32_16x16x32_bf16(k1, qf[c][1], z, 0, 0, 0);
        st[kb][c] = z;
      }
    }
    __builtin_amdgcn_s_setprio(0);

    unsigned pk[2][4][2];
#pragma unroll
    for (int c = 0; c < 2; ++c)
#pragma unroll
      for (int kb = 0; kb < 4; ++kb)
#pragma unroll
        for (int r2 = 0; r2 < 2; ++r2) {
          float pa = __builtin_amdgcn_exp2f(st[kb][c][2 * r2]);
          float pb_ = __builtin_amdgcn_exp2f(st[kb][c][2 * r2 + 1]);
          pk[c][kb][r2] = packbf(pa, pb_);
        }

    __builtin_amdgcn_s_setprio(1);
#pragma unroll
    for (int t = 0; t < 2; ++t) {
      union { unsigned u[4]; bf16x8 v; } pb0, pb1;
      pb0.u[0] = pk[0][2 * t][0];     pb0.u[1] = pk[0][2 * t][1];
      pb0.u[2] = pk[0][2 * t + 1][0]; pb0.u[3] = pk[0][2 * t + 1][1];
      pb1.u[0] = pk[1][2 * t][0];     pb1.u[1] = pk[1][2 * t][1];
      pb1.u[2] = pk[1][2 * t + 1][0]; pb1.u[3] = pk[1][2 * t + 1][1];
#pragma unroll
      for (int db = 0; db < 4; ++db) {
        bf16x8 af = *reinterpret_cast<const bf16x8*>(VB + voP[t][db]);
        ot[db][0] = __builtin_amdgcn_mfma_f32_16x16x32_bf16(af, pb0.v, ot[db][0], 0, 0, 0);
        ot[db][1] = __builtin_amdgcn_mfma_f32_16x16x32_bf16(af, pb1.v, ot[db][1], 0, 0, 0);
      }
      lacc[0] = __builtin_amdgcn_mfma_f32_16x16x32_bf16(ones, pb0.v, lacc[0], 0, 0, 0);
      lacc[1] = __builtin_amdgcn_mfma_f32_16x16x32_bf16(ones, pb1.v, lacc[1], 0, 0, 0);
    }
    __builtin_amdgcn_s_setprio(0);
  };

  auto body = [&](const char* KB, const char* VB, char* dk, char* dv, bool pref) {
    if (pref) {
      gll16(gk0, dk);           gll16(gk1, dk + 8192);
      gll16(gv0, dv);           gll16(gv1, dv + 8192);
      gk0 += 16384; gk1 += 16384; gv0 += 256; gv1 += 256;
    }
    half(KB, VB);
    half(KB + 8192, VB + 8192);
    __syncthreads();
  };

  const char* KB0 = (const char*)&KL[0][0][0];
  const char* VB0 = (const char*)&VL[0][0][0];
  const char* KB1 = KB0 + 16384;
  const char* VB1 = VB0 + 16384;

  for (int it = 0; it < NT; it += 2) {
    body(KB0, VB0, lkBase + 16384, lvBase + 16384, true);
    body(KB1, VB1, lkBase, lvBase, it + 2 < NT);
  }

  if (SPLIT2) {
    ushort_t* Ob = Opart + (((size_t)sp * 16 + bh) * S_LEN) * 64;
#pragma unroll
    for (int c = 0; c < 2; ++c) {
      const int q = qbase + c * 16 + ql;
#pragma unroll
      for (int db = 0; db < 4; ++db) {
        uint2 o;
        o.x = packbf(ot[db][c][0], ot[db][c][1]);
        o.y = packbf(ot[db][c][2], ot[db][c][3]);
        *reinterpret_cast<uint2*>(Ob + (size_t)q * 64 + db * 16 + 4 * g) = o;
      }
      if (g == 0) Lpart[((size_t)sp * 16 + bh) * S_LEN + q] = lacc[c][0];
    }
  } else {
    const int b = bh >> 3, h = bh & 7;
#pragma unroll
    for (int c = 0; c < 2; ++c) {
      const int q = qbase + c * 16 + ql;
      float inv = 1.f / lacc[c][0];
#pragma unroll
      for (int db = 0; db < 4; ++db) {
        uint2 o;
        o.x = packbf(ot[db][c][0] * inv, ot[db][c][1] * inv);
        o.y = packbf(ot[db][c][2] * inv, ot[db][c][3] * inv);
        *reinterpret_cast<uint2*>(AO + ((size_t)b * S_LEN + q) * DMODEL + h * DK + db * 16 + g * 4) = o;
      }
    }
  }
}

extern "C" void kernel_launch(void* const* d_in, const int* in_sizes, int n_in,
                              void* d_out, int out_size, void* d_ws, size_t ws_size,
                              hipStream_t stream) {
  const float* x  = (const float*)d_in[0];
  const float* Wq = (const float*)d_in[1];
  const float* bq = (const float*)d_in[2];
  const float* Wk = (const float*)d_in[3];
  const float* bk = (const float*)d_in[4];
  const float* Wv = (const float*)d_in[5];
  const float* bv = (const float*)d_in[6];
  const float* Wo = (const float*)d_in[7];
  const float* bo = (const float*)d_in[8];
  float* out = (float*)d_out;

  const float CQ = 0.18033688f;  // 0.125 * log2(e)

  char* ws = (char*)d_ws;
  const size_t NBF = (size_t)MROWS * DMODEL;  // 4 Mi elements
  ushort_t* AObuf = (ushort_t*)ws;            // 8MB (fallback AO)
  ushort_t* Qbf = (ushort_t*)(ws + NBF * 2);
  ushort_t* Kbf = (ushort_t*)(ws + NBF * 4);
  ushort_t* Vtb = (ushort_t*)(ws + NBF * 6);

  const size_t OFF_WT    = NBF * 8;
  const size_t OFF_LPART = OFF_WT + 4 * 512 * 512 * 2;
  const size_t OFF_OPART = OFF_LPART + 512 * 1024;
  const size_t NEED_SPLIT = OFF_OPART + (size_t)2 * 16 * S_LEN * 64 * 2;  // bf16 partials
  const bool use_split = ws_size >= NEED_SPLIT;

  ushort_t* Wcat;
  if (use_split) {
    Wcat = (ushort_t*)(ws + OFF_WT);
  } else {
    Wcat = (ushort_t*)(ws + NBF * 10);
  }
  ushort_t* Wot = Wcat + 3 * 512 * 512;
  float* Lpart = (float*)(ws + OFF_LPART);
  ushort_t* Opart = (ushort_t*)(ws + OFF_OPART);

  prep<<<1024, 256, 0, stream>>>(Wq, Wk, Wv, Wo, Wcat, Wot);

  gemm_qkv<<<768, 256, 0, stream>>>(x, Wcat, bq, bk, bv, Qbf, Kbf, Vtb, CQ);

  if (use_split) {
    attn_mfma<true><<<512, 512, 0, stream>>>(Qbf, Kbf, Vtb, AObuf, Opart, Lpart);
    gemm_wo_fused<<<512, 256, 0, stream>>>(Opart, Lpart, Wot, bo, out);
  } else {
    attn_mfma<false><<<256, 512, 0, stream>>>(Qbf, Kbf, Vtb, AObuf, Opart, Lpart);
    dim3 gg(MROWS / 128, DMODEL / 128);
    gemm_wo<<<gg, 256, 0, stream>>>(AObuf, Wot, bo, out);
  }
}